// Round 1
// baseline (4818.359 us; speedup 1.0000x reference)
//
#include <hip/hip_runtime.h>
#include <cstdint>
#include <cstddef>

typedef unsigned short u16;
typedef __bf16 bf16x8 __attribute__((ext_vector_type(8)));
typedef float f32x4 __attribute__((ext_vector_type(4)));

constexpr int kN  = 4096;
constexpr int kE  = 131072;
constexpr int kET = kE + kN;   // with self loops
constexpr int kIn = 512;
constexpr int kC  = 256;
constexpr int kL  = 3;

__device__ __forceinline__ u16 f2bf(float f) {
    unsigned u = __builtin_bit_cast(unsigned, f);
    u += 0x7fffu + ((u >> 16) & 1u);
    return (u16)(u >> 16);
}
__device__ __forceinline__ float bf2f(u16 s) {
    unsigned u = ((unsigned)s) << 16;
    return __builtin_bit_cast(float, u);
}
__device__ __forceinline__ float gelu_erf(float x) {
    return 0.5f * x * (1.f + erff(x * 0.70710678118654752f));
}

// ---------------- cast fp32 -> bf16 (vector4) ----------------
__global__ void cast_f2b(const float* __restrict__ src, u16* __restrict__ dst, int n4) {
    int i = blockIdx.x * blockDim.x + threadIdx.x;
    if (i >= n4) return;
    float4 v = ((const float4*)src)[i];
    ushort4 o;
    o.x = f2bf(v.x); o.y = f2bf(v.y); o.z = f2bf(v.z); o.w = f2bf(v.w);
    ((ushort4*)dst)[i] = o;
}

// ---------------- CSR build (by dst) ----------------
__global__ void csr_count(const int* __restrict__ ei, int* __restrict__ cnt) {
    int e = blockIdx.x * 256 + threadIdx.x;
    if (e >= kET) return;
    int d = (e < kE) ? ei[kE + e] : (e - kE);
    atomicAdd(cnt + d, 1);
}

__global__ __launch_bounds__(1024) void csr_scan(int* __restrict__ cnt_cur, int* __restrict__ off) {
    __shared__ int lds[1024];
    int t = threadIdx.x;
    int c[4], s = 0;
#pragma unroll
    for (int j = 0; j < 4; ++j) { c[j] = cnt_cur[t * 4 + j]; s += c[j]; }
    lds[t] = s;
    __syncthreads();
    for (int d = 1; d < 1024; d <<= 1) {
        int v = (t >= d) ? lds[t - d] : 0;
        __syncthreads();
        lds[t] += v;
        __syncthreads();
    }
    int excl = lds[t] - s;
#pragma unroll
    for (int j = 0; j < 4; ++j) { off[t * 4 + j] = excl; cnt_cur[t * 4 + j] = excl; excl += c[j]; }
    if (t == 1023) off[4096] = excl;
}

__global__ void csr_scatter(const int* __restrict__ ei, int* __restrict__ cur, int* __restrict__ csrc) {
    int e = blockIdx.x * 256 + threadIdx.x;
    if (e >= kET) return;
    int s, d;
    if (e < kE) { s = ei[e]; d = ei[kE + e]; } else { s = d = e - kE; }
    int pos = atomicAdd(cur + d, 1);
    csrc[pos] = s;
}

// ---------------- bf16 MFMA GEMM: C[M,N] = act(A[M,K] @ W[N,K]^T + bias) ----------------
// block 256 = 4 waves; block tile 64x64; wave tile 32x32 (2x2 of 16x16x32 MFMA)
template <int ACT, int WF32, int WBF16>
__global__ __launch_bounds__(256) void gemm_bt(
    const u16* __restrict__ A, const u16* __restrict__ W,
    const float* __restrict__ bias, float* __restrict__ Cf,
    u16* __restrict__ Cb, int M, int N, int K) {
    int wave = threadIdx.x >> 6, lane = threadIdx.x & 63;
    int bm = blockIdx.y * 64 + (wave >> 1) * 32;
    int bn = blockIdx.x * 64 + (wave & 1) * 32;
    int lr = lane & 15, lk = (lane >> 4) * 8;
    const u16* Ap = A + (size_t)(bm + lr) * K + lk;
    const u16* Wp = W + (size_t)(bn + lr) * K + lk;
    f32x4 acc[2][2] = {};
    for (int k0 = 0; k0 < K; k0 += 32) {
        bf16x8 a0 = *(const bf16x8*)(Ap + k0);
        bf16x8 a1 = *(const bf16x8*)(Ap + (size_t)16 * K + k0);
        bf16x8 b0 = *(const bf16x8*)(Wp + k0);
        bf16x8 b1 = *(const bf16x8*)(Wp + (size_t)16 * K + k0);
        acc[0][0] = __builtin_amdgcn_mfma_f32_16x16x32_bf16(a0, b0, acc[0][0], 0, 0, 0);
        acc[0][1] = __builtin_amdgcn_mfma_f32_16x16x32_bf16(a0, b1, acc[0][1], 0, 0, 0);
        acc[1][0] = __builtin_amdgcn_mfma_f32_16x16x32_bf16(a1, b0, acc[1][0], 0, 0, 0);
        acc[1][1] = __builtin_amdgcn_mfma_f32_16x16x32_bf16(a1, b1, acc[1][1], 0, 0, 0);
    }
    int r0 = bm + (lane >> 4) * 4;
    int c0 = bn + (lane & 15);
#pragma unroll
    for (int i = 0; i < 2; ++i)
#pragma unroll
        for (int j = 0; j < 2; ++j)
#pragma unroll
            for (int r = 0; r < 4; ++r) {
                int row = r0 + i * 16 + r, col = c0 + j * 16;
                float v = acc[i][j][r];
                if (bias) v += bias[col];
                if (ACT == 1) v = gelu_erf(v);
                if (WF32) Cf[(size_t)row * N + col] = v;
                if (WBF16) Cb[(size_t)row * N + col] = f2bf(v);
            }
}

// ---------------- LayerNorm(h + add) -> h (fp32) and h_bf (bf16); wave per row ----------------
__global__ __launch_bounds__(256) void ln_res(
    const float* hin, const float* add,
    const float* __restrict__ g, const float* __restrict__ b,
    float* hout, u16* __restrict__ hbf) {
    int row = blockIdx.x * 4 + (threadIdx.x >> 6);
    int lane = threadIdx.x & 63;
    const float4 x4 = *(const float4*)(hin + (size_t)row * kC + lane * 4);
    const float4 a4 = *(const float4*)(add + (size_t)row * kC + lane * 4);
    float v[4] = {x4.x + a4.x, x4.y + a4.y, x4.z + a4.z, x4.w + a4.w};
    float s = v[0] + v[1] + v[2] + v[3];
    for (int d = 1; d < 64; d <<= 1) s += __shfl_xor(s, d);
    float mu = s * (1.f / kC);
    float q = 0.f;
#pragma unroll
    for (int j = 0; j < 4; ++j) { float d = v[j] - mu; q += d * d; }
    for (int d = 1; d < 64; d <<= 1) q += __shfl_xor(q, d);
    float rstd = rsqrtf(q * (1.f / kC) + 1e-5f);
    const float4 g4 = *(const float4*)(g + lane * 4);
    const float4 b4 = *(const float4*)(b + lane * 4);
    float y0 = (v[0] - mu) * rstd * g4.x + b4.x;
    float y1 = (v[1] - mu) * rstd * g4.y + b4.y;
    float y2 = (v[2] - mu) * rstd * g4.z + b4.z;
    float y3 = (v[3] - mu) * rstd * g4.w + b4.w;
    *(float4*)(hout + (size_t)row * kC + lane * 4) = make_float4(y0, y1, y2, y3);
    ushort4 o; o.x = f2bf(y0); o.y = f2bf(y1); o.z = f2bf(y2); o.w = f2bf(y3);
    *(ushort4*)(hbf + (size_t)row * kC + lane * 4) = o;
}

// ---------------- GATv2: per-node online softmax aggregation; wave = head ----------------
__global__ __launch_bounds__(256) void gat_agg(
    const float* __restrict__ xl, const float* __restrict__ xr,
    const float* __restrict__ att, const float* __restrict__ gb,
    const int* __restrict__ off, const int* __restrict__ srcs,
    float* __restrict__ outloc) {
    int n = blockIdx.x;
    int w = threadIdx.x >> 6, lane = threadIdx.x & 63;
    int base = w * 256 + lane * 4;
    const float4 xrv = *(const float4*)(xr + (size_t)n * 1024 + base);
    const float4 av = *(const float4*)(att + base);
    int i0 = off[n], i1 = off[n + 1];
    float m = -1e30f, lsum = 0.f;
    float ax = 0.f, ay = 0.f, az = 0.f, aw = 0.f;
    for (int i = i0; i < i1; ++i) {
        int s = srcs[i];
        const float4 xv = *(const float4*)(xl + (size_t)s * 1024 + base);
        float e0 = xv.x + xrv.x, e1 = xv.y + xrv.y, e2 = xv.z + xrv.z, e3 = xv.w + xrv.w;
        e0 = e0 > 0.f ? e0 : 0.2f * e0;
        e1 = e1 > 0.f ? e1 : 0.2f * e1;
        e2 = e2 > 0.f ? e2 : 0.2f * e2;
        e3 = e3 > 0.f ? e3 : 0.2f * e3;
        float p = av.x * e0 + av.y * e1 + av.z * e2 + av.w * e3;
        p += __shfl_xor(p, 1); p += __shfl_xor(p, 2); p += __shfl_xor(p, 4);
        p += __shfl_xor(p, 8); p += __shfl_xor(p, 16); p += __shfl_xor(p, 32);
        float mn = fmaxf(m, p);
        float corr = __expf(m - mn);
        float pw = __expf(p - mn);
        lsum = lsum * corr + pw;
        ax = ax * corr + pw * xv.x;
        ay = ay * corr + pw * xv.y;
        az = az * corr + pw * xv.z;
        aw = aw * corr + pw * xv.w;
        m = mn;
    }
    float inv = 1.f / lsum;
    __shared__ float red[4][256];
    red[w][lane * 4 + 0] = ax * inv;
    red[w][lane * 4 + 1] = ay * inv;
    red[w][lane * 4 + 2] = az * inv;
    red[w][lane * 4 + 3] = aw * inv;
    __syncthreads();
    int c = threadIdx.x;
    float vsum = 0.25f * (red[0][c] + red[1][c] + red[2][c] + red[3][c]) + gb[c];
    outloc[(size_t)n * kC + c] = vsum;
}

// ---------------- fp32 flash attention, 2 queries/thread, 64-key tiles ----------------
// grid: (kN/32, 4 heads), block 128 (2 waves). qkv: [4096][768] (q|k|v, head-major 64)
__global__ __launch_bounds__(128) void mha_flash(
    const float* __restrict__ qkv, u16* __restrict__ attn_bf) {
    int head = blockIdx.y;
    int t = threadIdx.x;
    int g = t & 7;
    int qp = t >> 3;               // 0..15
    int lane = t & 63;
    int q0 = blockIdx.x * 32;
    float qreg[2][8];
#pragma unroll
    for (int qq = 0; qq < 2; ++qq) {
        const float* qrow = qkv + (size_t)(q0 + qp * 2 + qq) * 768 + head * 64 + g * 8;
#pragma unroll
        for (int j = 0; j < 8; ++j) qreg[qq][j] = qrow[j] * 0.125f;
    }
    __shared__ float Kt[64][68];
    __shared__ float Vt[64][68];
    float m[2] = {-1e30f, -1e30f}, lsum[2] = {0.f, 0.f};
    float acc[2][8] = {};
    for (int t0 = 0; t0 < kN; t0 += 64) {
        int rr = t >> 1, c0 = (t & 1) * 32;
        const float* kr = qkv + (size_t)(t0 + rr) * 768 + 256 + head * 64 + c0;
        const float* vr = kr + 256;
#pragma unroll
        for (int u = 0; u < 8; ++u) {
            *(float4*)&Kt[rr][c0 + u * 4] = *(const float4*)(kr + u * 4);
            *(float4*)&Vt[rr][c0 + u * 4] = *(const float4*)(vr + u * 4);
        }
        __syncthreads();
        float p8[2][8];
#pragma unroll
        for (int j = 0; j < 64; ++j) {
            float4 ka = *(const float4*)&Kt[j][g * 8];
            float4 kb = *(const float4*)&Kt[j][g * 8 + 4];
#pragma unroll
            for (int qq = 0; qq < 2; ++qq) {
                float s = qreg[qq][0] * ka.x + qreg[qq][1] * ka.y + qreg[qq][2] * ka.z + qreg[qq][3] * ka.w
                        + qreg[qq][4] * kb.x + qreg[qq][5] * kb.y + qreg[qq][6] * kb.z + qreg[qq][7] * kb.w;
                s += __shfl_xor(s, 1); s += __shfl_xor(s, 2); s += __shfl_xor(s, 4);
                if ((j & 7) == g) p8[qq][j >> 3] = s;
            }
        }
#pragma unroll
        for (int qq = 0; qq < 2; ++qq) {
            float tm = p8[qq][0];
#pragma unroll
            for (int i2 = 1; i2 < 8; ++i2) tm = fmaxf(tm, p8[qq][i2]);
            tm = fmaxf(tm, __shfl_xor(tm, 1));
            tm = fmaxf(tm, __shfl_xor(tm, 2));
            tm = fmaxf(tm, __shfl_xor(tm, 4));
            float mn = fmaxf(m[qq], tm);
            float corr = __expf(m[qq] - mn);
            lsum[qq] *= corr;
#pragma unroll
            for (int jj = 0; jj < 8; ++jj) acc[qq][jj] *= corr;
            m[qq] = mn;
            float ps = 0.f;
#pragma unroll
            for (int i2 = 0; i2 < 8; ++i2) { p8[qq][i2] = __expf(p8[qq][i2] - mn); ps += p8[qq][i2]; }
            ps += __shfl_xor(ps, 1); ps += __shfl_xor(ps, 2); ps += __shfl_xor(ps, 4);
            lsum[qq] += ps;
        }
#pragma unroll
        for (int j = 0; j < 64; ++j) {
            float4 va = *(const float4*)&Vt[j][g * 8];
            float4 vb = *(const float4*)&Vt[j][g * 8 + 4];
            int srcl = (lane & 56) | (j & 7);
#pragma unroll
            for (int qq = 0; qq < 2; ++qq) {
                float pj = __shfl(p8[qq][j >> 3], srcl);
                acc[qq][0] += pj * va.x; acc[qq][1] += pj * va.y;
                acc[qq][2] += pj * va.z; acc[qq][3] += pj * va.w;
                acc[qq][4] += pj * vb.x; acc[qq][5] += pj * vb.y;
                acc[qq][6] += pj * vb.z; acc[qq][7] += pj * vb.w;
            }
        }
        __syncthreads();
    }
#pragma unroll
    for (int qq = 0; qq < 2; ++qq) {
        float inv = 1.f / lsum[qq];
        u16* orow = attn_bf + (size_t)(q0 + qp * 2 + qq) * 256 + head * 64 + g * 8;
        ushort4 o;
        o.x = f2bf(acc[qq][0] * inv); o.y = f2bf(acc[qq][1] * inv);
        o.z = f2bf(acc[qq][2] * inv); o.w = f2bf(acc[qq][3] * inv);
        *(ushort4*)orow = o;
        o.x = f2bf(acc[qq][4] * inv); o.y = f2bf(acc[qq][5] * inv);
        o.z = f2bf(acc[qq][6] * inv); o.w = f2bf(acc[qq][7] * inv);
        *(ushort4*)(orow + 4) = o;
    }
}

// ---------------- final: out[4096,2] = t_bf @ out_w2^T + b2; wave per row ----------------
__global__ __launch_bounds__(256) void final_out(
    const u16* __restrict__ tbf, const float* __restrict__ w2,
    const float* __restrict__ b2, float* __restrict__ out) {
    int row = blockIdx.x * 4 + (threadIdx.x >> 6);
    int lane = threadIdx.x & 63;
    const ushort4 tv = *(const ushort4*)(tbf + (size_t)row * 256 + lane * 4);
    float t0 = bf2f(tv.x), t1 = bf2f(tv.y), t2 = bf2f(tv.z), t3 = bf2f(tv.w);
    const float4 w0 = *(const float4*)(w2 + lane * 4);
    const float4 w1 = *(const float4*)(w2 + 256 + lane * 4);
    float d0 = t0 * w0.x + t1 * w0.y + t2 * w0.z + t3 * w0.w;
    float d1 = t0 * w1.x + t1 * w1.y + t2 * w1.z + t3 * w1.w;
    for (int d = 1; d < 64; d <<= 1) { d0 += __shfl_xor(d0, d); d1 += __shfl_xor(d1, d); }
    if (lane == 0) {
        out[(size_t)row * 2 + 0] = d0 + b2[0];
        out[(size_t)row * 2 + 1] = d1 + b2[1];
    }
}

extern "C" void kernel_launch(void* const* d_in, const int* in_sizes, int n_in,
                              void* d_out, int out_size, void* d_ws, size_t ws_size,
                              hipStream_t stream) {
    (void)in_sizes; (void)n_in; (void)out_size;
    const float* x        = (const float*)d_in[0];
    const int*   ei       = (const int*)d_in[1];
    const float* in_w     = (const float*)d_in[2];
    const float* in_b     = (const float*)d_in[3];
    const float* gat_wl   = (const float*)d_in[4];
    const float* gat_wr   = (const float*)d_in[5];
    const float* gat_att  = (const float*)d_in[6];
    const float* gat_b    = (const float*)d_in[7];
    const float* mha_in_w = (const float*)d_in[8];
    const float* mha_in_b = (const float*)d_in[9];
    const float* mha_out_w= (const float*)d_in[10];
    const float* mha_out_b= (const float*)d_in[11];
    const float* ln1_g = (const float*)d_in[12];
    const float* ln1_b = (const float*)d_in[13];
    const float* ln2_g = (const float*)d_in[14];
    const float* ln2_b = (const float*)d_in[15];
    const float* ln3_g = (const float*)d_in[16];
    const float* ln3_b = (const float*)d_in[17];
    const float* ffn_w1 = (const float*)d_in[18];
    const float* ffn_b1 = (const float*)d_in[19];
    const float* ffn_w2 = (const float*)d_in[20];
    const float* ffn_b2 = (const float*)d_in[21];
    const float* out_w1 = (const float*)d_in[22];
    const float* out_b1 = (const float*)d_in[23];
    const float* out_w2 = (const float*)d_in[24];
    const float* out_b2 = (const float*)d_in[25];
    float* out = (float*)d_out;

    char* ws = (char*)d_ws;
    size_t off = 0;
    auto alloc = [&](size_t bytes) -> void* {
        void* p = (void*)(ws + off);
        off += (bytes + 255) & ~(size_t)255;
        return p;
    };
    float* h     = (float*)alloc((size_t)kN * kC * 4);
    u16*   hbf   = (u16*)  alloc((size_t)kN * kC * 2);
    float* xlb   = (float*)alloc((size_t)kN * 1024 * 4);
    float* xrb   = (float*)alloc((size_t)kN * 1024 * 4);
    float* qkv   = (float*)alloc((size_t)kN * 768 * 4);
    float* locb  = (float*)alloc((size_t)kN * kC * 4);
    u16*   attnb = (u16*)  alloc((size_t)kN * kC * 2);
    u16*   midb  = (u16*)  alloc((size_t)kN * 512 * 2);
    u16*   tbf   = (u16*)  alloc((size_t)kN * kC * 2);
    u16*   xbf   = (u16*)  alloc((size_t)kN * kIn * 2);
    u16*   wbf   = (u16*)  alloc((size_t)3342336 * 2);
    int*   coff  = (int*)  alloc((size_t)4097 * 4);
    int*   ccur  = (int*)  alloc((size_t)4096 * 4);
    int*   csrc  = (int*)  alloc((size_t)kET * 4);
    if (ws_size < off) return;  // not enough scratch: bail loudly (output stays poisoned)

    // bf16 weight buffer offsets (elements)
    const size_t OFF_INW  = 0;
    const size_t OFF_GWL  = 131072;
    const size_t OFF_GWR  = 917504;
    const size_t OFF_MIN  = 1703936;
    const size_t OFF_MOUT = 2293760;
    const size_t OFF_F1   = 2490368;
    const size_t OFF_F2   = 2883584;
    const size_t OFF_O1   = 3276800;

    auto cast = [&](const float* s, u16* d, int n) {
        int n4 = n >> 2;
        cast_f2b<<<dim3((n4 + 255) / 256), dim3(256), 0, stream>>>(s, d, n4);
    };
    cast(x, xbf, kN * kIn);
    cast(in_w, wbf + OFF_INW, kC * kIn);
    cast(gat_wl, wbf + OFF_GWL, kL * 1024 * kC);
    cast(gat_wr, wbf + OFF_GWR, kL * 1024 * kC);
    cast(mha_in_w, wbf + OFF_MIN, kL * 768 * kC);
    cast(mha_out_w, wbf + OFF_MOUT, kL * kC * kC);
    cast(ffn_w1, wbf + OFF_F1, kL * 512 * kC);
    cast(ffn_w2, wbf + OFF_F2, kL * kC * 512);
    cast(out_w1, wbf + OFF_O1, kC * kC);

    // CSR build (once per launch; same graph for all layers)
    hipMemsetAsync(ccur, 0, 4096 * 4, stream);
    csr_count<<<dim3((kET + 255) / 256), dim3(256), 0, stream>>>(ei, ccur);
    csr_scan<<<dim3(1), dim3(1024), 0, stream>>>(ccur, coff);
    csr_scatter<<<dim3((kET + 255) / 256), dim3(256), 0, stream>>>(ei, ccur, csrc);

    // input projection: h = x @ in_w^T + in_b  (fp32 + bf16 outputs)
    gemm_bt<0, 1, 1><<<dim3(kC / 64, kN / 64), dim3(256), 0, stream>>>(
        xbf, wbf + OFF_INW, in_b, h, hbf, kN, kC, kIn);

    for (int l = 0; l < kL; ++l) {
        // GATv2 transforms
        gemm_bt<0, 1, 0><<<dim3(1024 / 64, kN / 64), dim3(256), 0, stream>>>(
            hbf, wbf + OFF_GWL + (size_t)l * 1024 * kC, nullptr, xlb, nullptr, kN, 1024, kC);
        gemm_bt<0, 1, 0><<<dim3(1024 / 64, kN / 64), dim3(256), 0, stream>>>(
            hbf, wbf + OFF_GWR + (size_t)l * 1024 * kC, nullptr, xrb, nullptr, kN, 1024, kC);
        gat_agg<<<dim3(kN), dim3(256), 0, stream>>>(
            xlb, xrb, gat_att + (size_t)l * 1024, gat_b + (size_t)l * kC, coff, csrc, locb);
        ln_res<<<dim3(kN / 4), dim3(256), 0, stream>>>(
            h, locb, ln1_g + (size_t)l * kC, ln1_b + (size_t)l * kC, h, hbf);

        // MHA
        gemm_bt<0, 1, 0><<<dim3(768 / 64, kN / 64), dim3(256), 0, stream>>>(
            hbf, wbf + OFF_MIN + (size_t)l * 768 * kC, mha_in_b + (size_t)l * 768, qkv, nullptr, kN, 768, kC);
        mha_flash<<<dim3(kN / 32, 4), dim3(128), 0, stream>>>(qkv, attnb);
        gemm_bt<0, 1, 0><<<dim3(kC / 64, kN / 64), dim3(256), 0, stream>>>(
            attnb, wbf + OFF_MOUT + (size_t)l * kC * kC, mha_out_b + (size_t)l * kC, locb, nullptr, kN, kC, kC);
        ln_res<<<dim3(kN / 4), dim3(256), 0, stream>>>(
            h, locb, ln2_g + (size_t)l * kC, ln2_b + (size_t)l * kC, h, hbf);

        // FFN
        gemm_bt<1, 0, 1><<<dim3(512 / 64, kN / 64), dim3(256), 0, stream>>>(
            hbf, wbf + OFF_F1 + (size_t)l * 512 * kC, ffn_b1 + (size_t)l * 512, nullptr, midb, kN, 512, kC);
        gemm_bt<0, 1, 0><<<dim3(kC / 64, kN / 64), dim3(256), 0, stream>>>(
            midb, wbf + OFF_F2 + (size_t)l * kC * 512, ffn_b2 + (size_t)l * kC, locb, nullptr, kN, kC, 512);
        ln_res<<<dim3(kN / 4), dim3(256), 0, stream>>>(
            h, locb, ln3_g + (size_t)l * kC, ln3_b + (size_t)l * kC, h, hbf);
    }

    // output head
    gemm_bt<1, 0, 1><<<dim3(kC / 64, kN / 64), dim3(256), 0, stream>>>(
        hbf, wbf + OFF_O1, out_b1, nullptr, tbf, kN, kC, kC);
    final_out<<<dim3(kN / 4), dim3(256), 0, stream>>>(tbf, out_w2, out_b2, out);
}

// Round 3
// 1027.572 us; speedup vs baseline: 4.6891x; 4.6891x over previous
//
#include <hip/hip_runtime.h>
#include <cstdint>
#include <cstddef>

typedef unsigned short u16;
typedef __bf16 bf16x8 __attribute__((ext_vector_type(8)));
typedef float f32x4 __attribute__((ext_vector_type(4)));

constexpr int kN  = 4096;
constexpr int kE  = 131072;
constexpr int kET = kE + kN;   // with self loops
constexpr int kIn = 512;
constexpr int kC  = 256;
constexpr int kL  = 3;

__device__ __forceinline__ u16 f2bf(float f) {
    unsigned u = __builtin_bit_cast(unsigned, f);
    u += 0x7fffu + ((u >> 16) & 1u);
    return (u16)(u >> 16);
}
__device__ __forceinline__ float bf2f(u16 s) {
    unsigned u = ((unsigned)s) << 16;
    return __builtin_bit_cast(float, u);
}
__device__ __forceinline__ float gelu_erf(float x) {
    return 0.5f * x * (1.f + erff(x * 0.70710678118654752f));
}

// ---------------- cast fp32 -> bf16 (vector4) ----------------
__global__ void cast_f2b(const float* __restrict__ src, u16* __restrict__ dst, int n4) {
    int i = blockIdx.x * blockDim.x + threadIdx.x;
    if (i >= n4) return;
    float4 v = ((const float4*)src)[i];
    ushort4 o;
    o.x = f2bf(v.x); o.y = f2bf(v.y); o.z = f2bf(v.z); o.w = f2bf(v.w);
    ((ushort4*)dst)[i] = o;
}

// ---------------- CSR build (by dst) ----------------
__global__ void csr_count(const int* __restrict__ ei, int* __restrict__ cnt) {
    int e = blockIdx.x * 256 + threadIdx.x;
    if (e >= kET) return;
    int d = (e < kE) ? ei[kE + e] : (e - kE);
    atomicAdd(cnt + d, 1);
}

__global__ __launch_bounds__(1024) void csr_scan(int* __restrict__ cnt_cur, int* __restrict__ off) {
    __shared__ int lds[1024];
    int t = threadIdx.x;
    int c[4], s = 0;
#pragma unroll
    for (int j = 0; j < 4; ++j) { c[j] = cnt_cur[t * 4 + j]; s += c[j]; }
    lds[t] = s;
    __syncthreads();
    for (int d = 1; d < 1024; d <<= 1) {
        int v = (t >= d) ? lds[t - d] : 0;
        __syncthreads();
        lds[t] += v;
        __syncthreads();
    }
    int excl = lds[t] - s;
#pragma unroll
    for (int j = 0; j < 4; ++j) { off[t * 4 + j] = excl; cnt_cur[t * 4 + j] = excl; excl += c[j]; }
    if (t == 1023) off[4096] = excl;
}

__global__ void csr_scatter(const int* __restrict__ ei, int* __restrict__ cur, int* __restrict__ csrc) {
    int e = blockIdx.x * 256 + threadIdx.x;
    if (e >= kET) return;
    int s, d;
    if (e < kE) { s = ei[e]; d = ei[kE + e]; } else { s = d = e - kE; }
    int pos = atomicAdd(cur + d, 1);
    csrc[pos] = s;
}

// ---------------- bf16 MFMA GEMM: C[M,N] = act(A[M,K] @ W[N,K]^T + bias) ----------------
// block 256 = 4 waves; block tile 64x64; wave tile 32x32 (2x2 of 16x16x32 MFMA)
template <int ACT, int WF32, int WBF16>
__global__ __launch_bounds__(256) void gemm_bt(
    const u16* __restrict__ A, const u16* __restrict__ W,
    const float* __restrict__ bias, float* __restrict__ Cf,
    u16* __restrict__ Cb, int M, int N, int K) {
    int wave = threadIdx.x >> 6, lane = threadIdx.x & 63;
    int bm = blockIdx.y * 64 + (wave >> 1) * 32;
    int bn = blockIdx.x * 64 + (wave & 1) * 32;
    int lr = lane & 15, lk = (lane >> 4) * 8;
    const u16* Ap = A + (size_t)(bm + lr) * K + lk;
    const u16* Wp = W + (size_t)(bn + lr) * K + lk;
    f32x4 acc[2][2] = {};
    for (int k0 = 0; k0 < K; k0 += 32) {
        bf16x8 a0 = *(const bf16x8*)(Ap + k0);
        bf16x8 a1 = *(const bf16x8*)(Ap + (size_t)16 * K + k0);
        bf16x8 b0 = *(const bf16x8*)(Wp + k0);
        bf16x8 b1 = *(const bf16x8*)(Wp + (size_t)16 * K + k0);
        acc[0][0] = __builtin_amdgcn_mfma_f32_16x16x32_bf16(a0, b0, acc[0][0], 0, 0, 0);
        acc[0][1] = __builtin_amdgcn_mfma_f32_16x16x32_bf16(a0, b1, acc[0][1], 0, 0, 0);
        acc[1][0] = __builtin_amdgcn_mfma_f32_16x16x32_bf16(a1, b0, acc[1][0], 0, 0, 0);
        acc[1][1] = __builtin_amdgcn_mfma_f32_16x16x32_bf16(a1, b1, acc[1][1], 0, 0, 0);
    }
    int r0 = bm + (lane >> 4) * 4;
    int c0 = bn + (lane & 15);
#pragma unroll
    for (int i = 0; i < 2; ++i)
#pragma unroll
        for (int j = 0; j < 2; ++j)
#pragma unroll
            for (int r = 0; r < 4; ++r) {
                int row = r0 + i * 16 + r, col = c0 + j * 16;
                float v = acc[i][j][r];
                if (bias) v += bias[col];
                if (ACT == 1) v = gelu_erf(v);
                if (WF32) Cf[(size_t)row * N + col] = v;
                if (WBF16) Cb[(size_t)row * N + col] = f2bf(v);
            }
}

// ---------------- LayerNorm(h + add) -> h (fp32) and h_bf (bf16); wave per row ----------------
__global__ __launch_bounds__(256) void ln_res(
    const float* hin, const float* add,
    const float* __restrict__ g, const float* __restrict__ b,
    float* hout, u16* __restrict__ hbf) {
    int row = blockIdx.x * 4 + (threadIdx.x >> 6);
    int lane = threadIdx.x & 63;
    const float4 x4 = *(const float4*)(hin + (size_t)row * kC + lane * 4);
    const float4 a4 = *(const float4*)(add + (size_t)row * kC + lane * 4);
    float v[4] = {x4.x + a4.x, x4.y + a4.y, x4.z + a4.z, x4.w + a4.w};
    float s = v[0] + v[1] + v[2] + v[3];
    for (int d = 1; d < 64; d <<= 1) s += __shfl_xor(s, d);
    float mu = s * (1.f / kC);
    float q = 0.f;
#pragma unroll
    for (int j = 0; j < 4; ++j) { float d = v[j] - mu; q += d * d; }
    for (int d = 1; d < 64; d <<= 1) q += __shfl_xor(q, d);
    float rstd = rsqrtf(q * (1.f / kC) + 1e-5f);
    const float4 g4 = *(const float4*)(g + lane * 4);
    const float4 b4 = *(const float4*)(b + lane * 4);
    float y0 = (v[0] - mu) * rstd * g4.x + b4.x;
    float y1 = (v[1] - mu) * rstd * g4.y + b4.y;
    float y2 = (v[2] - mu) * rstd * g4.z + b4.z;
    float y3 = (v[3] - mu) * rstd * g4.w + b4.w;
    *(float4*)(hout + (size_t)row * kC + lane * 4) = make_float4(y0, y1, y2, y3);
    ushort4 o; o.x = f2bf(y0); o.y = f2bf(y1); o.z = f2bf(y2); o.w = f2bf(y3);
    *(ushort4*)(hbf + (size_t)row * kC + lane * 4) = o;
}

// ---------------- GATv2: per-node online softmax aggregation; wave = head ----------------
__global__ __launch_bounds__(256) void gat_agg(
    const float* __restrict__ xl, const float* __restrict__ xr,
    const float* __restrict__ att, const float* __restrict__ gb,
    const int* __restrict__ off, const int* __restrict__ srcs,
    float* __restrict__ outloc) {
    int n = blockIdx.x;
    int w = threadIdx.x >> 6, lane = threadIdx.x & 63;
    int base = w * 256 + lane * 4;
    const float4 xrv = *(const float4*)(xr + (size_t)n * 1024 + base);
    const float4 av = *(const float4*)(att + base);
    int i0 = off[n], i1 = off[n + 1];
    float m = -1e30f, lsum = 0.f;
    float ax = 0.f, ay = 0.f, az = 0.f, aw = 0.f;
    for (int i = i0; i < i1; ++i) {
        int s = srcs[i];
        const float4 xv = *(const float4*)(xl + (size_t)s * 1024 + base);
        float e0 = xv.x + xrv.x, e1 = xv.y + xrv.y, e2 = xv.z + xrv.z, e3 = xv.w + xrv.w;
        e0 = e0 > 0.f ? e0 : 0.2f * e0;
        e1 = e1 > 0.f ? e1 : 0.2f * e1;
        e2 = e2 > 0.f ? e2 : 0.2f * e2;
        e3 = e3 > 0.f ? e3 : 0.2f * e3;
        float p = av.x * e0 + av.y * e1 + av.z * e2 + av.w * e3;
        p += __shfl_xor(p, 1); p += __shfl_xor(p, 2); p += __shfl_xor(p, 4);
        p += __shfl_xor(p, 8); p += __shfl_xor(p, 16); p += __shfl_xor(p, 32);
        float mn = fmaxf(m, p);
        float corr = __expf(m - mn);
        float pw = __expf(p - mn);
        lsum = lsum * corr + pw;
        ax = ax * corr + pw * xv.x;
        ay = ay * corr + pw * xv.y;
        az = az * corr + pw * xv.z;
        aw = aw * corr + pw * xv.w;
        m = mn;
    }
    float inv = 1.f / lsum;
    __shared__ float red[4][256];
    red[w][lane * 4 + 0] = ax * inv;
    red[w][lane * 4 + 1] = ay * inv;
    red[w][lane * 4 + 2] = az * inv;
    red[w][lane * 4 + 3] = aw * inv;
    __syncthreads();
    int c = threadIdx.x;
    float vsum = 0.25f * (red[0][c] + red[1][c] + red[2][c] + red[3][c]) + gb[c];
    outloc[(size_t)n * kC + c] = vsum;
}

// ---------------- qkv repack: qkv fp32 [4096][768] -> Qb/Kb [4][4096][64] bf16, VTb [4][64][4096] bf16
// Q scaled by 1/sqrt(64) * log2(e) so attention can use exp2 directly.
__global__ __launch_bounds__(256) void qkv_repack(
    const float* __restrict__ qkv, u16* __restrict__ Qb, u16* __restrict__ Kb,
    u16* __restrict__ VTb) {
    int h = blockIdx.y;
    int n0 = blockIdx.x * 64;
    int t = threadIdx.x;
    int nr = t >> 2, cb = (t & 3) * 16;
    const float* src = qkv + (size_t)(n0 + nr) * 768 + h * 64 + cb;
    u16* qd = Qb + ((size_t)h * kN + n0 + nr) * 64 + cb;
    u16* kd = Kb + ((size_t)h * kN + n0 + nr) * 64 + cb;
    __shared__ float lds[64][65];
    constexpr float QS = 0.125f * 1.4426950408889634f;  // 1/sqrt(DH) * log2(e)
#pragma unroll
    for (int j = 0; j < 16; j += 4) {
        ushort4 qo, ko;
        qo.x = f2bf(src[j + 0] * QS); qo.y = f2bf(src[j + 1] * QS);
        qo.z = f2bf(src[j + 2] * QS); qo.w = f2bf(src[j + 3] * QS);
        ko.x = f2bf(src[256 + j + 0]); ko.y = f2bf(src[256 + j + 1]);
        ko.z = f2bf(src[256 + j + 2]); ko.w = f2bf(src[256 + j + 3]);
        *(ushort4*)(qd + j) = qo;
        *(ushort4*)(kd + j) = ko;
        lds[nr][cb + j + 0] = src[512 + j + 0];
        lds[nr][cb + j + 1] = src[512 + j + 1];
        lds[nr][cb + j + 2] = src[512 + j + 2];
        lds[nr][cb + j + 3] = src[512 + j + 3];
    }
    __syncthreads();
    int d = t >> 2, nb = (t & 3) * 16;
    u16* vd = VTb + ((size_t)h * 64 + d) * kN + n0 + nb;
#pragma unroll
    for (int j = 0; j < 16; j += 4) {
        ushort4 vo;
        vo.x = f2bf(lds[nb + j + 0][d]);
        vo.y = f2bf(lds[nb + j + 1][d]);
        vo.z = f2bf(lds[nb + j + 2][d]);
        vo.w = f2bf(lds[nb + j + 3][d]);
        *(ushort4*)(vd + j) = vo;
    }
}

// ---------------- MFMA flash attention ----------------
// 1 wave per block, 16 q-rows; grid (kN/16, 4 heads). Swapped QK^T: S^T = mfma(K, Q)
// so q is lane-local (lane&15). Online softmax in exp2 domain (log2e folded into Q).
// P redistributed C-layout -> A-layout via per-wave LDS (no barriers needed).
__global__ __launch_bounds__(64) void mha_mfma(
    const u16* __restrict__ Qb, const u16* __restrict__ Kb,
    const u16* __restrict__ VTb, u16* __restrict__ attn_bf) {
    int head = blockIdx.y;
    int q0 = blockIdx.x * 16;
    int lane = threadIdx.x;
    int g = lane >> 4, r = lane & 15;
    const u16* Qh = Qb + ((size_t)head * kN + q0) * 64;
    const u16* Kh = Kb + (size_t)head * kN * 64;
    const u16* VTh = VTb + (size_t)head * 64 * kN;
    __shared__ u16 plds[16 * 80];   // P buffer: 16 q rows x 64 keys, stride 80 (4-way max conflict)
    bf16x8 qf0 = *(const bf16x8*)(Qh + r * 64 + g * 8);
    bf16x8 qf1 = *(const bf16x8*)(Qh + r * 64 + 32 + g * 8);
    f32x4 o[4] = {};
    float m = -3.0e38f, l = 0.f;
    for (int k0 = 0; k0 < kN; k0 += 64) {
        // K fragments: A-operand rows = keys (k0+16t+r), k-dim = head dim
        bf16x8 kf[4][2];
#pragma unroll
        for (int t = 0; t < 4; ++t) {
            const u16* kr = Kh + (size_t)(k0 + 16 * t + r) * 64 + g * 8;
            kf[t][0] = *(const bf16x8*)kr;
            kf[t][1] = *(const bf16x8*)(kr + 32);
        }
        // V fragments: B-operand from VT[d][key] rows (contiguous)
        bf16x8 vf[2][4];
#pragma unroll
        for (int u = 0; u < 2; ++u)
#pragma unroll
            for (int dt = 0; dt < 4; ++dt)
                vf[u][dt] = *(const bf16x8*)(VTh + (size_t)(dt * 16 + r) * kN + k0 + u * 32 + g * 8);
        // S^T tiles: D rows = keys (16t + 4g + reg), cols = q (r)
        f32x4 st[4] = {};
#pragma unroll
        for (int t = 0; t < 4; ++t) {
            st[t] = __builtin_amdgcn_mfma_f32_16x16x32_bf16(kf[t][0], qf0, st[t], 0, 0, 0);
            st[t] = __builtin_amdgcn_mfma_f32_16x16x32_bf16(kf[t][1], qf1, st[t], 0, 0, 0);
        }
        // online softmax (exp2 domain), state per q=r (replicated across g groups)
        float pm = st[0][0];
#pragma unroll
        for (int t = 0; t < 4; ++t)
#pragma unroll
            for (int e = 0; e < 4; ++e) pm = fmaxf(pm, st[t][e]);
        pm = fmaxf(pm, __shfl_xor(pm, 16));
        pm = fmaxf(pm, __shfl_xor(pm, 32));
        float mn = fmaxf(m, pm);
        float corr = __builtin_amdgcn_exp2f(m - mn);
        float ls = 0.f;
        float p[4][4];
#pragma unroll
        for (int t = 0; t < 4; ++t)
#pragma unroll
            for (int e = 0; e < 4; ++e) { p[t][e] = __builtin_amdgcn_exp2f(st[t][e] - mn); ls += p[t][e]; }
        ls += __shfl_xor(ls, 16);
        ls += __shfl_xor(ls, 32);
        l = l * corr + ls;
        m = mn;
        // rescale O: O rows are q = 4g+reg, state lives at q = r -> fetch corr per row
        float corrq[4];
#pragma unroll
        for (int e = 0; e < 4; ++e) corrq[e] = __shfl(corr, g * 4 + e);
#pragma unroll
        for (int dt = 0; dt < 4; ++dt)
#pragma unroll
            for (int e = 0; e < 4; ++e) o[dt][e] *= corrq[e];
        // P: C-layout -> LDS -> A-layout (per-wave private, waitcnt-ordered)
#pragma unroll
        for (int t = 0; t < 4; ++t) {
            ushort4 pk;
            pk.x = f2bf(p[t][0]); pk.y = f2bf(p[t][1]);
            pk.z = f2bf(p[t][2]); pk.w = f2bf(p[t][3]);
            *(ushort4*)(plds + r * 80 + 16 * t + 4 * g) = pk;
        }
        bf16x8 pa0 = *(const bf16x8*)(plds + r * 80 + 8 * g);
        bf16x8 pa1 = *(const bf16x8*)(plds + r * 80 + 32 + 8 * g);
#pragma unroll
        for (int dt = 0; dt < 4; ++dt) {
            o[dt] = __builtin_amdgcn_mfma_f32_16x16x32_bf16(pa0, vf[0][dt], o[dt], 0, 0, 0);
            o[dt] = __builtin_amdgcn_mfma_f32_16x16x32_bf16(pa1, vf[1][dt], o[dt], 0, 0, 0);
        }
    }
    float inv = 1.f / l;
    float invq[4];
#pragma unroll
    for (int e = 0; e < 4; ++e) invq[e] = __shfl(inv, g * 4 + e);
#pragma unroll
    for (int dt = 0; dt < 4; ++dt)
#pragma unroll
        for (int e = 0; e < 4; ++e)
            attn_bf[(size_t)(q0 + g * 4 + e) * kC + head * 64 + dt * 16 + r] = f2bf(o[dt][e] * invq[e]);
}

// ---------------- final: out[4096,2] = t_bf @ out_w2^T + b2; wave per row ----------------
__global__ __launch_bounds__(256) void final_out(
    const u16* __restrict__ tbf, const float* __restrict__ w2,
    const float* __restrict__ b2, float* __restrict__ out) {
    int row = blockIdx.x * 4 + (threadIdx.x >> 6);
    int lane = threadIdx.x & 63;
    const ushort4 tv = *(const ushort4*)(tbf + (size_t)row * 256 + lane * 4);
    float t0 = bf2f(tv.x), t1 = bf2f(tv.y), t2 = bf2f(tv.z), t3 = bf2f(tv.w);
    const float4 w0 = *(const float4*)(w2 + lane * 4);
    const float4 w1 = *(const float4*)(w2 + 256 + lane * 4);
    float d0 = t0 * w0.x + t1 * w0.y + t2 * w0.z + t3 * w0.w;
    float d1 = t0 * w1.x + t1 * w1.y + t2 * w1.z + t3 * w1.w;
    for (int d = 1; d < 64; d <<= 1) { d0 += __shfl_xor(d0, d); d1 += __shfl_xor(d1, d); }
    if (lane == 0) {
        out[(size_t)row * 2 + 0] = d0 + b2[0];
        out[(size_t)row * 2 + 1] = d1 + b2[1];
    }
}

extern "C" void kernel_launch(void* const* d_in, const int* in_sizes, int n_in,
                              void* d_out, int out_size, void* d_ws, size_t ws_size,
                              hipStream_t stream) {
    (void)in_sizes; (void)n_in; (void)out_size;
    const float* x        = (const float*)d_in[0];
    const int*   ei       = (const int*)d_in[1];
    const float* in_w     = (const float*)d_in[2];
    const float* in_b     = (const float*)d_in[3];
    const float* gat_wl   = (const float*)d_in[4];
    const float* gat_wr   = (const float*)d_in[5];
    const float* gat_att  = (const float*)d_in[6];
    const float* gat_b    = (const float*)d_in[7];
    const float* mha_in_w = (const float*)d_in[8];
    const float* mha_in_b = (const float*)d_in[9];
    const float* mha_out_w= (const float*)d_in[10];
    const float* mha_out_b= (const float*)d_in[11];
    const float* ln1_g = (const float*)d_in[12];
    const float* ln1_b = (const float*)d_in[13];
    const float* ln2_g = (const float*)d_in[14];
    const float* ln2_b = (const float*)d_in[15];
    const float* ln3_g = (const float*)d_in[16];
    const float* ln3_b = (const float*)d_in[17];
    const float* ffn_w1 = (const float*)d_in[18];
    const float* ffn_b1 = (const float*)d_in[19];
    const float* ffn_w2 = (const float*)d_in[20];
    const float* ffn_b2 = (const float*)d_in[21];
    const float* out_w1 = (const float*)d_in[22];
    const float* out_b1 = (const float*)d_in[23];
    const float* out_w2 = (const float*)d_in[24];
    const float* out_b2 = (const float*)d_in[25];
    float* out = (float*)d_out;

    char* ws = (char*)d_ws;
    size_t off = 0;
    auto alloc = [&](size_t bytes) -> void* {
        void* p = (void*)(ws + off);
        off += (bytes + 255) & ~(size_t)255;
        return p;
    };
    float* h     = (float*)alloc((size_t)kN * kC * 4);
    u16*   hbf   = (u16*)  alloc((size_t)kN * kC * 2);
    float* xlb   = (float*)alloc((size_t)kN * 1024 * 4);
    float* xrb   = (float*)alloc((size_t)kN * 1024 * 4);
    float* qkv   = (float*)alloc((size_t)kN * 768 * 4);
    float* locb  = (float*)alloc((size_t)kN * kC * 4);
    u16*   attnb = (u16*)  alloc((size_t)kN * kC * 2);
    u16*   midb  = (u16*)  alloc((size_t)kN * 512 * 2);
    u16*   tbf   = (u16*)  alloc((size_t)kN * kC * 2);
    u16*   xbf   = (u16*)  alloc((size_t)kN * kIn * 2);
    u16*   wbf   = (u16*)  alloc((size_t)3342336 * 2);
    int*   coff  = (int*)  alloc((size_t)4097 * 4);
    int*   ccur  = (int*)  alloc((size_t)4096 * 4);
    int*   csrc  = (int*)  alloc((size_t)kET * 4);
    if (ws_size < off) return;  // not enough scratch: bail loudly (output stays poisoned)

    // MHA attention operand buffers: alias into xlb (dead during the MHA phase;
    // fully rewritten by next layer's GAT GEMM before reuse). 6 MB < 16 MB.
    u16* Qb  = (u16*)xlb;                       // [4][4096][64]
    u16* Kb  = Qb + (size_t)4 * kN * 64;        // [4][4096][64]
    u16* VTb = Kb + (size_t)4 * kN * 64;        // [4][64][4096]

    // bf16 weight buffer offsets (elements)
    const size_t OFF_INW  = 0;
    const size_t OFF_GWL  = 131072;
    const size_t OFF_GWR  = 917504;
    const size_t OFF_MIN  = 1703936;
    const size_t OFF_MOUT = 2293760;
    const size_t OFF_F1   = 2490368;
    const size_t OFF_F2   = 2883584;
    const size_t OFF_O1   = 3276800;

    auto cast = [&](const float* s, u16* d, int n) {
        int n4 = n >> 2;
        cast_f2b<<<dim3((n4 + 255) / 256), dim3(256), 0, stream>>>(s, d, n4);
    };
    cast(x, xbf, kN * kIn);
    cast(in_w, wbf + OFF_INW, kC * kIn);
    cast(gat_wl, wbf + OFF_GWL, kL * 1024 * kC);
    cast(gat_wr, wbf + OFF_GWR, kL * 1024 * kC);
    cast(mha_in_w, wbf + OFF_MIN, kL * 768 * kC);
    cast(mha_out_w, wbf + OFF_MOUT, kL * kC * kC);
    cast(ffn_w1, wbf + OFF_F1, kL * 512 * kC);
    cast(ffn_w2, wbf + OFF_F2, kL * kC * 512);
    cast(out_w1, wbf + OFF_O1, kC * kC);

    // CSR build (once per launch; same graph for all layers)
    hipMemsetAsync(ccur, 0, 4096 * 4, stream);
    csr_count<<<dim3((kET + 255) / 256), dim3(256), 0, stream>>>(ei, ccur);
    csr_scan<<<dim3(1), dim3(1024), 0, stream>>>(ccur, coff);
    csr_scatter<<<dim3((kET + 255) / 256), dim3(256), 0, stream>>>(ei, ccur, csrc);

    // input projection: h = x @ in_w^T + in_b  (fp32 + bf16 outputs)
    gemm_bt<0, 1, 1><<<dim3(kC / 64, kN / 64), dim3(256), 0, stream>>>(
        xbf, wbf + OFF_INW, in_b, h, hbf, kN, kC, kIn);

    for (int l = 0; l < kL; ++l) {
        // GATv2 transforms
        gemm_bt<0, 1, 0><<<dim3(1024 / 64, kN / 64), dim3(256), 0, stream>>>(
            hbf, wbf + OFF_GWL + (size_t)l * 1024 * kC, nullptr, xlb, nullptr, kN, 1024, kC);
        gemm_bt<0, 1, 0><<<dim3(1024 / 64, kN / 64), dim3(256), 0, stream>>>(
            hbf, wbf + OFF_GWR + (size_t)l * 1024 * kC, nullptr, xrb, nullptr, kN, 1024, kC);
        gat_agg<<<dim3(kN), dim3(256), 0, stream>>>(
            xlb, xrb, gat_att + (size_t)l * 1024, gat_b + (size_t)l * kC, coff, csrc, locb);
        ln_res<<<dim3(kN / 4), dim3(256), 0, stream>>>(
            h, locb, ln1_g + (size_t)l * kC, ln1_b + (size_t)l * kC, h, hbf);

        // MHA
        gemm_bt<0, 1, 0><<<dim3(768 / 64, kN / 64), dim3(256), 0, stream>>>(
            hbf, wbf + OFF_MIN + (size_t)l * 768 * kC, mha_in_b + (size_t)l * 768, qkv, nullptr, kN, 768, kC);
        qkv_repack<<<dim3(kN / 64, 4), dim3(256), 0, stream>>>(qkv, Qb, Kb, VTb);
        mha_mfma<<<dim3(kN / 16, 4), dim3(64), 0, stream>>>(Qb, Kb, VTb, attnb);
        gemm_bt<0, 1, 0><<<dim3(kC / 64, kN / 64), dim3(256), 0, stream>>>(
            attnb, wbf + OFF_MOUT + (size_t)l * kC * kC, mha_out_b + (size_t)l * kC, locb, nullptr, kN, kC, kC);
        ln_res<<<dim3(kN / 4), dim3(256), 0, stream>>>(
            h, locb, ln2_g + (size_t)l * kC, ln2_b + (size_t)l * kC, h, hbf);

        // FFN
        gemm_bt<1, 0, 1><<<dim3(512 / 64, kN / 64), dim3(256), 0, stream>>>(
            hbf, wbf + OFF_F1 + (size_t)l * 512 * kC, ffn_b1 + (size_t)l * 512, nullptr, midb, kN, 512, kC);
        gemm_bt<0, 1, 0><<<dim3(kC / 64, kN / 64), dim3(256), 0, stream>>>(
            midb, wbf + OFF_F2 + (size_t)l * kC * 512, ffn_b2 + (size_t)l * kC, locb, nullptr, kN, kC, 512);
        ln_res<<<dim3(kN / 4), dim3(256), 0, stream>>>(
            h, locb, ln3_g + (size_t)l * kC, ln3_b + (size_t)l * kC, h, hbf);
    }

    // output head
    gemm_bt<1, 0, 1><<<dim3(kC / 64, kN / 64), dim3(256), 0, stream>>>(
        hbf, wbf + OFF_O1, out_b1, nullptr, tbf, kN, kC, kC);
    final_out<<<dim3(kN / 4), dim3(256), 0, stream>>>(tbf, out_w2, out_b2, out);
}

// Round 4
// 809.426 us; speedup vs baseline: 5.9528x; 1.2695x over previous
//
#include <hip/hip_runtime.h>
#include <cstdint>
#include <cstddef>

typedef unsigned short u16;
typedef __bf16 bf16x8 __attribute__((ext_vector_type(8)));
typedef float f32x4 __attribute__((ext_vector_type(4)));

constexpr int kN  = 4096;
constexpr int kE  = 131072;
constexpr int kET = kE + kN;   // with self loops
constexpr int kIn = 512;
constexpr int kC  = 256;
constexpr int kL  = 3;

constexpr int NSPLIT = 4;
constexpr int KSPAN  = kN / NSPLIT;  // 1024 keys per split
constexpr int NSTEP  = KSPAN / 64;   // 16 steps of 64 keys

__device__ __forceinline__ u16 f2bf(float f) {
    unsigned u = __builtin_bit_cast(unsigned, f);
    u += 0x7fffu + ((u >> 16) & 1u);
    return (u16)(u >> 16);
}
__device__ __forceinline__ float bf2f(u16 s) {
    unsigned u = ((unsigned)s) << 16;
    return __builtin_bit_cast(float, u);
}
__device__ __forceinline__ float gelu_erf(float x) {
    return 0.5f * x * (1.f + erff(x * 0.70710678118654752f));
}
// async global->LDS, 16B per lane; ldst must be wave-uniform base (HW adds lane*16)
__device__ __forceinline__ void gload_lds16(const u16* gsrc, u16* ldst) {
    __builtin_amdgcn_global_load_lds(
        (const __attribute__((address_space(1))) unsigned int*)gsrc,
        (__attribute__((address_space(3))) unsigned int*)ldst, 16, 0, 0);
}

// ---------------- cast fp32 -> bf16 (vector4) ----------------
__global__ void cast_f2b(const float* __restrict__ src, u16* __restrict__ dst, int n4) {
    int i = blockIdx.x * blockDim.x + threadIdx.x;
    if (i >= n4) return;
    float4 v = ((const float4*)src)[i];
    ushort4 o;
    o.x = f2bf(v.x); o.y = f2bf(v.y); o.z = f2bf(v.z); o.w = f2bf(v.w);
    ((ushort4*)dst)[i] = o;
}

// ---------------- CSR build (by dst) ----------------
__global__ void csr_count(const int* __restrict__ ei, int* __restrict__ cnt) {
    int e = blockIdx.x * 256 + threadIdx.x;
    if (e >= kET) return;
    int d = (e < kE) ? ei[kE + e] : (e - kE);
    atomicAdd(cnt + d, 1);
}

__global__ __launch_bounds__(1024) void csr_scan(int* __restrict__ cnt_cur, int* __restrict__ off) {
    __shared__ int lds[1024];
    int t = threadIdx.x;
    int c[4], s = 0;
#pragma unroll
    for (int j = 0; j < 4; ++j) { c[j] = cnt_cur[t * 4 + j]; s += c[j]; }
    lds[t] = s;
    __syncthreads();
    for (int d = 1; d < 1024; d <<= 1) {
        int v = (t >= d) ? lds[t - d] : 0;
        __syncthreads();
        lds[t] += v;
        __syncthreads();
    }
    int excl = lds[t] - s;
#pragma unroll
    for (int j = 0; j < 4; ++j) { off[t * 4 + j] = excl; cnt_cur[t * 4 + j] = excl; excl += c[j]; }
    if (t == 1023) off[4096] = excl;
}

__global__ void csr_scatter(const int* __restrict__ ei, int* __restrict__ cur, int* __restrict__ csrc) {
    int e = blockIdx.x * 256 + threadIdx.x;
    if (e >= kET) return;
    int s, d;
    if (e < kE) { s = ei[e]; d = ei[kE + e]; } else { s = d = e - kE; }
    int pos = atomicAdd(cur + d, 1);
    csrc[pos] = s;
}

// ---------------- bf16 MFMA GEMM: C[M,N] = act(A[M,K] @ W[N,K]^T + bias) ----------------
// block 256 = 4 waves; block tile 64x64; wave tile 32x32 (2x2 of 16x16x32 MFMA)
template <int ACT, int WF32, int WBF16>
__global__ __launch_bounds__(256) void gemm_bt(
    const u16* __restrict__ A, const u16* __restrict__ W,
    const float* __restrict__ bias, float* __restrict__ Cf,
    u16* __restrict__ Cb, int M, int N, int K) {
    int wave = threadIdx.x >> 6, lane = threadIdx.x & 63;
    int bm = blockIdx.y * 64 + (wave >> 1) * 32;
    int bn = blockIdx.x * 64 + (wave & 1) * 32;
    int lr = lane & 15, lk = (lane >> 4) * 8;
    const u16* Ap = A + (size_t)(bm + lr) * K + lk;
    const u16* Wp = W + (size_t)(bn + lr) * K + lk;
    f32x4 acc[2][2] = {};
    for (int k0 = 0; k0 < K; k0 += 32) {
        bf16x8 a0 = *(const bf16x8*)(Ap + k0);
        bf16x8 a1 = *(const bf16x8*)(Ap + (size_t)16 * K + k0);
        bf16x8 b0 = *(const bf16x8*)(Wp + k0);
        bf16x8 b1 = *(const bf16x8*)(Wp + (size_t)16 * K + k0);
        acc[0][0] = __builtin_amdgcn_mfma_f32_16x16x32_bf16(a0, b0, acc[0][0], 0, 0, 0);
        acc[0][1] = __builtin_amdgcn_mfma_f32_16x16x32_bf16(a0, b1, acc[0][1], 0, 0, 0);
        acc[1][0] = __builtin_amdgcn_mfma_f32_16x16x32_bf16(a1, b0, acc[1][0], 0, 0, 0);
        acc[1][1] = __builtin_amdgcn_mfma_f32_16x16x32_bf16(a1, b1, acc[1][1], 0, 0, 0);
    }
    int r0 = bm + (lane >> 4) * 4;
    int c0 = bn + (lane & 15);
#pragma unroll
    for (int i = 0; i < 2; ++i)
#pragma unroll
        for (int j = 0; j < 2; ++j)
#pragma unroll
            for (int r = 0; r < 4; ++r) {
                int row = r0 + i * 16 + r, col = c0 + j * 16;
                float v = acc[i][j][r];
                if (bias) v += bias[col];
                if (ACT == 1) v = gelu_erf(v);
                if (WF32) Cf[(size_t)row * N + col] = v;
                if (WBF16) Cb[(size_t)row * N + col] = f2bf(v);
            }
}

// ---------------- LayerNorm(h + add) -> h (fp32) and h_bf (bf16); wave per row ----------------
__global__ __launch_bounds__(256) void ln_res(
    const float* hin, const float* add,
    const float* __restrict__ g, const float* __restrict__ b,
    float* hout, u16* __restrict__ hbf) {
    int row = blockIdx.x * 4 + (threadIdx.x >> 6);
    int lane = threadIdx.x & 63;
    const float4 x4 = *(const float4*)(hin + (size_t)row * kC + lane * 4);
    const float4 a4 = *(const float4*)(add + (size_t)row * kC + lane * 4);
    float v[4] = {x4.x + a4.x, x4.y + a4.y, x4.z + a4.z, x4.w + a4.w};
    float s = v[0] + v[1] + v[2] + v[3];
    for (int d = 1; d < 64; d <<= 1) s += __shfl_xor(s, d);
    float mu = s * (1.f / kC);
    float q = 0.f;
#pragma unroll
    for (int j = 0; j < 4; ++j) { float d = v[j] - mu; q += d * d; }
    for (int d = 1; d < 64; d <<= 1) q += __shfl_xor(q, d);
    float rstd = rsqrtf(q * (1.f / kC) + 1e-5f);
    const float4 g4 = *(const float4*)(g + lane * 4);
    const float4 b4 = *(const float4*)(b + lane * 4);
    float y0 = (v[0] - mu) * rstd * g4.x + b4.x;
    float y1 = (v[1] - mu) * rstd * g4.y + b4.y;
    float y2 = (v[2] - mu) * rstd * g4.z + b4.z;
    float y3 = (v[3] - mu) * rstd * g4.w + b4.w;
    *(float4*)(hout + (size_t)row * kC + lane * 4) = make_float4(y0, y1, y2, y3);
    ushort4 o; o.x = f2bf(y0); o.y = f2bf(y1); o.z = f2bf(y2); o.w = f2bf(y3);
    *(ushort4*)(hbf + (size_t)row * kC + lane * 4) = o;
}

// ---------------- GATv2: per-node online softmax aggregation; wave = head ----------------
__global__ __launch_bounds__(256) void gat_agg(
    const float* __restrict__ xl, const float* __restrict__ xr,
    const float* __restrict__ att, const float* __restrict__ gb,
    const int* __restrict__ off, const int* __restrict__ srcs,
    float* __restrict__ outloc) {
    int n = blockIdx.x;
    int w = threadIdx.x >> 6, lane = threadIdx.x & 63;
    int base = w * 256 + lane * 4;
    const float4 xrv = *(const float4*)(xr + (size_t)n * 1024 + base);
    const float4 av = *(const float4*)(att + base);
    int i0 = off[n], i1 = off[n + 1];
    float m = -1e30f, lsum = 0.f;
    float ax = 0.f, ay = 0.f, az = 0.f, aw = 0.f;
    for (int i = i0; i < i1; ++i) {
        int s = srcs[i];
        const float4 xv = *(const float4*)(xl + (size_t)s * 1024 + base);
        float e0 = xv.x + xrv.x, e1 = xv.y + xrv.y, e2 = xv.z + xrv.z, e3 = xv.w + xrv.w;
        e0 = e0 > 0.f ? e0 : 0.2f * e0;
        e1 = e1 > 0.f ? e1 : 0.2f * e1;
        e2 = e2 > 0.f ? e2 : 0.2f * e2;
        e3 = e3 > 0.f ? e3 : 0.2f * e3;
        float p = av.x * e0 + av.y * e1 + av.z * e2 + av.w * e3;
        p += __shfl_xor(p, 1); p += __shfl_xor(p, 2); p += __shfl_xor(p, 4);
        p += __shfl_xor(p, 8); p += __shfl_xor(p, 16); p += __shfl_xor(p, 32);
        float mn = fmaxf(m, p);
        float corr = __expf(m - mn);
        float pw = __expf(p - mn);
        lsum = lsum * corr + pw;
        ax = ax * corr + pw * xv.x;
        ay = ay * corr + pw * xv.y;
        az = az * corr + pw * xv.z;
        aw = aw * corr + pw * xv.w;
        m = mn;
    }
    float inv = 1.f / lsum;
    __shared__ float red[4][256];
    red[w][lane * 4 + 0] = ax * inv;
    red[w][lane * 4 + 1] = ay * inv;
    red[w][lane * 4 + 2] = az * inv;
    red[w][lane * 4 + 3] = aw * inv;
    __syncthreads();
    int c = threadIdx.x;
    float vsum = 0.25f * (red[0][c] + red[1][c] + red[2][c] + red[3][c]) + gb[c];
    outloc[(size_t)n * kC + c] = vsum;
}

// ---------------- qkv repack: qkv fp32 [4096][768] -> Qb/Kb [4][4096][64] bf16, VTb [4][64][4096] bf16
// Q scaled by 1/sqrt(64) * log2(e) so attention can use exp2 directly.
__global__ __launch_bounds__(256) void qkv_repack(
    const float* __restrict__ qkv, u16* __restrict__ Qb, u16* __restrict__ Kb,
    u16* __restrict__ VTb) {
    int h = blockIdx.y;
    int n0 = blockIdx.x * 64;
    int t = threadIdx.x;
    int nr = t >> 2, cb = (t & 3) * 16;
    const float* src = qkv + (size_t)(n0 + nr) * 768 + h * 64 + cb;
    u16* qd = Qb + ((size_t)h * kN + n0 + nr) * 64 + cb;
    u16* kd = Kb + ((size_t)h * kN + n0 + nr) * 64 + cb;
    __shared__ float lds[64][65];
    constexpr float QS = 0.125f * 1.4426950408889634f;  // 1/sqrt(DH) * log2(e)
#pragma unroll
    for (int j = 0; j < 16; j += 4) {
        ushort4 qo, ko;
        qo.x = f2bf(src[j + 0] * QS); qo.y = f2bf(src[j + 1] * QS);
        qo.z = f2bf(src[j + 2] * QS); qo.w = f2bf(src[j + 3] * QS);
        ko.x = f2bf(src[256 + j + 0]); ko.y = f2bf(src[256 + j + 1]);
        ko.z = f2bf(src[256 + j + 2]); ko.w = f2bf(src[256 + j + 3]);
        *(ushort4*)(qd + j) = qo;
        *(ushort4*)(kd + j) = ko;
        lds[nr][cb + j + 0] = src[512 + j + 0];
        lds[nr][cb + j + 1] = src[512 + j + 1];
        lds[nr][cb + j + 2] = src[512 + j + 2];
        lds[nr][cb + j + 3] = src[512 + j + 3];
    }
    __syncthreads();
    int d = t >> 2, nb = (t & 3) * 16;
    u16* vd = VTb + ((size_t)h * 64 + d) * kN + n0 + nb;
#pragma unroll
    for (int j = 0; j < 16; j += 4) {
        ushort4 vo;
        vo.x = f2bf(lds[nb + j + 0][d]);
        vo.y = f2bf(lds[nb + j + 1][d]);
        vo.z = f2bf(lds[nb + j + 2][d]);
        vo.w = f2bf(lds[nb + j + 3][d]);
        *(ushort4*)(vd + j) = vo;
    }
}

// ---------------- MFMA flash attention, LDS-shared K/V, split-K ----------------
// Block = 4 waves, 64 q rows (16/wave). Grid (kN/64, heads, NSPLIT).
// K and VT 64x64 tiles double-buffered in LDS via global_load_lds with XOR-swizzled
// source (chunk ^= row&7) so fragment ds_read_b128 spreads over all bank groups.
// Writes unnormalized partial O + (m,l) per split; mha_merge recombines (LSE merge).
__global__ __launch_bounds__(256, 4) void mha_mfma2(
    const u16* __restrict__ Qb, const u16* __restrict__ Kb,
    const u16* __restrict__ VTb, float* __restrict__ opart, float* __restrict__ mlpart) {
    int qt = blockIdx.x, head = blockIdx.y, sp = blockIdx.z;
    int tid = threadIdx.x;
    int w = tid >> 6, lane = tid & 63;
    int g = lane >> 4, r = lane & 15;
    int q0 = qt * 64;
    const u16* Qh = Qb + ((size_t)head * kN + q0 + w * 16) * 64;
    const u16* Kh = Kb + (size_t)head * kN * 64;
    const u16* VTh = VTb + (size_t)head * 64 * kN;
    __shared__ u16 Kt[2][64 * 64];
    __shared__ u16 Vt[2][64 * 64];
    __shared__ u16 plds[4][16 * 64];
    // staging geometry: instr i in {0,1}; lane covers (row = i*32 + w*8 + (lane>>3), chunk = lane&7)
    // of the 64x64 tile; global chunk is XOR-swizzled by row&7 (= (lane>>3)&7).
    int srow = w * 8 + (lane >> 3);
    int schunk = ((lane & 7) ^ ((lane >> 3) & 7)) * 8;   // element offset within row
    int kbase = sp * KSPAN;

    bf16x8 qf0 = *(const bf16x8*)(Qh + r * 64 + g * 8);
    bf16x8 qf1 = *(const bf16x8*)(Qh + r * 64 + 32 + g * 8);

    auto stage = [&](int buf, int k0) {
#pragma unroll
        for (int i = 0; i < 2; ++i) {
            int row = i * 32 + srow;
            gload_lds16(Kh + (size_t)(k0 + row) * 64 + schunk, &Kt[buf][(i * 32 + w * 8) * 64]);
            gload_lds16(VTh + (size_t)row * kN + k0 + schunk, &Vt[buf][(i * 32 + w * 8) * 64]);
        }
    };

    f32x4 o[4] = {};
    float m = -3.0e38f, l = 0.f;

    stage(0, kbase);
    __syncthreads();   // vmcnt(0) drain + barrier: buffer 0 ready

    for (int st = 0; st < NSTEP; ++st) {
        int cur = st & 1;
        if (st + 1 < NSTEP) stage(cur ^ 1, kbase + (st + 1) * 64);
        const u16* Kl = &Kt[cur][0];
        const u16* Vl = &Vt[cur][0];
        int rx = r & 7;
        // S^T tiles: rows = keys (16t + 4g + reg), cols = q (r)
        f32x4 stt[4] = {};
#pragma unroll
        for (int t = 0; t < 4; ++t) {
            bf16x8 kf0 = *(const bf16x8*)(Kl + (16 * t + r) * 64 + ((0 + g) ^ rx) * 8);
            bf16x8 kf1 = *(const bf16x8*)(Kl + (16 * t + r) * 64 + ((4 + g) ^ rx) * 8);
            stt[t] = __builtin_amdgcn_mfma_f32_16x16x32_bf16(kf0, qf0, stt[t], 0, 0, 0);
            stt[t] = __builtin_amdgcn_mfma_f32_16x16x32_bf16(kf1, qf1, stt[t], 0, 0, 0);
        }
        // online softmax (exp2 domain), state per q=r (replicated across g groups)
        float pm = stt[0][0];
#pragma unroll
        for (int t = 0; t < 4; ++t)
#pragma unroll
            for (int e = 0; e < 4; ++e) pm = fmaxf(pm, stt[t][e]);
        pm = fmaxf(pm, __shfl_xor(pm, 16));
        pm = fmaxf(pm, __shfl_xor(pm, 32));
        float mn = fmaxf(m, pm);
        float corr = __builtin_amdgcn_exp2f(m - mn);
        float ls = 0.f;
        float p[4][4];
#pragma unroll
        for (int t = 0; t < 4; ++t)
#pragma unroll
            for (int e = 0; e < 4; ++e) { p[t][e] = __builtin_amdgcn_exp2f(stt[t][e] - mn); ls += p[t][e]; }
        ls += __shfl_xor(ls, 16);
        ls += __shfl_xor(ls, 32);
        l = l * corr + ls;
        m = mn;
        // rescale O: O rows are q = 4g+reg, state lives at q = r -> fetch corr per row
        float corrq[4];
#pragma unroll
        for (int e = 0; e < 4; ++e) corrq[e] = __shfl(corr, g * 4 + e);
#pragma unroll
        for (int dt = 0; dt < 4; ++dt)
#pragma unroll
            for (int e = 0; e < 4; ++e) o[dt][e] *= corrq[e];
        // P: C-layout -> LDS -> A-layout (per-wave private, waitcnt-ordered)
#pragma unroll
        for (int t = 0; t < 4; ++t) {
            ushort4 pk;
            pk.x = f2bf(p[t][0]); pk.y = f2bf(p[t][1]);
            pk.z = f2bf(p[t][2]); pk.w = f2bf(p[t][3]);
            *(ushort4*)(&plds[w][r * 64 + 16 * t + 4 * g]) = pk;
        }
        bf16x8 pa0 = *(const bf16x8*)(&plds[w][r * 64 + 8 * g]);
        bf16x8 pa1 = *(const bf16x8*)(&plds[w][r * 64 + 32 + 8 * g]);
#pragma unroll
        for (int dt = 0; dt < 4; ++dt) {
            bf16x8 vf0 = *(const bf16x8*)(Vl + (dt * 16 + r) * 64 + ((0 + g) ^ rx) * 8);
            bf16x8 vf1 = *(const bf16x8*)(Vl + (dt * 16 + r) * 64 + ((4 + g) ^ rx) * 8);
            o[dt] = __builtin_amdgcn_mfma_f32_16x16x32_bf16(pa0, vf0, o[dt], 0, 0, 0);
            o[dt] = __builtin_amdgcn_mfma_f32_16x16x32_bf16(pa1, vf1, o[dt], 0, 0, 0);
        }
        __syncthreads();   // vmcnt(0): next buffer staged; lgkmcnt: all reads of cur done
    }

    // store unnormalized partials
    size_t slot = (size_t)(head * 64 + qt) * NSPLIT + sp;
    float* ob = opart + slot * 4096;
#pragma unroll
    for (int dt = 0; dt < 4; ++dt)
#pragma unroll
        for (int e = 0; e < 4; ++e)
            ob[(w * 16 + g * 4 + e) * 64 + dt * 16 + r] = o[dt][e];
    float* mlb = mlpart + slot * 128;
    if (g == 0) { mlb[w * 16 + r] = m; mlb[64 + w * 16 + r] = l; }
}

// ---------------- merge split-K attention partials -> attnb (bf16) ----------------
// grid (kN/4, heads), block 256: wave w = one q row, lane = d (0..63)
__global__ __launch_bounds__(256) void mha_merge(
    const float* __restrict__ opart, const float* __restrict__ mlpart,
    u16* __restrict__ attnb) {
    int head = blockIdx.y;
    int q = blockIdx.x * 4 + (threadIdx.x >> 6);
    int d = threadIdx.x & 63;
    int qt = q >> 6, ql = q & 63;
    size_t sb = (size_t)(head * 64 + qt) * NSPLIT;
    float ms[NSPLIT], lsv[NSPLIT];
    float mstar = -3.0e38f;
#pragma unroll
    for (int s = 0; s < NSPLIT; ++s) {
        ms[s] = mlpart[(sb + s) * 128 + ql];
        lsv[s] = mlpart[(sb + s) * 128 + 64 + ql];
        mstar = fmaxf(mstar, ms[s]);
    }
    float acc = 0.f, lsum = 0.f;
#pragma unroll
    for (int s = 0; s < NSPLIT; ++s) {
        float wgt = __builtin_amdgcn_exp2f(ms[s] - mstar);
        lsum += lsv[s] * wgt;
        acc += opart[(sb + s) * 4096 + ql * 64 + d] * wgt;
    }
    attnb[(size_t)q * kC + head * 64 + d] = f2bf(acc / lsum);
}

// ---------------- final: out[4096,2] = t_bf @ out_w2^T + b2; wave per row ----------------
__global__ __launch_bounds__(256) void final_out(
    const u16* __restrict__ tbf, const float* __restrict__ w2,
    const float* __restrict__ b2, float* __restrict__ out) {
    int row = blockIdx.x * 4 + (threadIdx.x >> 6);
    int lane = threadIdx.x & 63;
    const ushort4 tv = *(const ushort4*)(tbf + (size_t)row * 256 + lane * 4);
    float t0 = bf2f(tv.x), t1 = bf2f(tv.y), t2 = bf2f(tv.z), t3 = bf2f(tv.w);
    const float4 w0 = *(const float4*)(w2 + lane * 4);
    const float4 w1 = *(const float4*)(w2 + 256 + lane * 4);
    float d0 = t0 * w0.x + t1 * w0.y + t2 * w0.z + t3 * w0.w;
    float d1 = t0 * w1.x + t1 * w1.y + t2 * w1.z + t3 * w1.w;
    for (int d = 1; d < 64; d <<= 1) { d0 += __shfl_xor(d0, d); d1 += __shfl_xor(d1, d); }
    if (lane == 0) {
        out[(size_t)row * 2 + 0] = d0 + b2[0];
        out[(size_t)row * 2 + 1] = d1 + b2[1];
    }
}

extern "C" void kernel_launch(void* const* d_in, const int* in_sizes, int n_in,
                              void* d_out, int out_size, void* d_ws, size_t ws_size,
                              hipStream_t stream) {
    (void)in_sizes; (void)n_in; (void)out_size;
    const float* x        = (const float*)d_in[0];
    const int*   ei       = (const int*)d_in[1];
    const float* in_w     = (const float*)d_in[2];
    const float* in_b     = (const float*)d_in[3];
    const float* gat_wl   = (const float*)d_in[4];
    const float* gat_wr   = (const float*)d_in[5];
    const float* gat_att  = (const float*)d_in[6];
    const float* gat_b    = (const float*)d_in[7];
    const float* mha_in_w = (const float*)d_in[8];
    const float* mha_in_b = (const float*)d_in[9];
    const float* mha_out_w= (const float*)d_in[10];
    const float* mha_out_b= (const float*)d_in[11];
    const float* ln1_g = (const float*)d_in[12];
    const float* ln1_b = (const float*)d_in[13];
    const float* ln2_g = (const float*)d_in[14];
    const float* ln2_b = (const float*)d_in[15];
    const float* ln3_g = (const float*)d_in[16];
    const float* ln3_b = (const float*)d_in[17];
    const float* ffn_w1 = (const float*)d_in[18];
    const float* ffn_b1 = (const float*)d_in[19];
    const float* ffn_w2 = (const float*)d_in[20];
    const float* ffn_b2 = (const float*)d_in[21];
    const float* out_w1 = (const float*)d_in[22];
    const float* out_b1 = (const float*)d_in[23];
    const float* out_w2 = (const float*)d_in[24];
    const float* out_b2 = (const float*)d_in[25];
    float* out = (float*)d_out;

    char* ws = (char*)d_ws;
    size_t off = 0;
    auto alloc = [&](size_t bytes) -> void* {
        void* p = (void*)(ws + off);
        off += (bytes + 255) & ~(size_t)255;
        return p;
    };
    float* h     = (float*)alloc((size_t)kN * kC * 4);
    u16*   hbf   = (u16*)  alloc((size_t)kN * kC * 2);
    float* xlb   = (float*)alloc((size_t)kN * 1024 * 4);
    float* xrb   = (float*)alloc((size_t)kN * 1024 * 4);
    float* qkv   = (float*)alloc((size_t)kN * 768 * 4);
    float* locb  = (float*)alloc((size_t)kN * kC * 4);
    u16*   attnb = (u16*)  alloc((size_t)kN * kC * 2);
    u16*   midb  = (u16*)  alloc((size_t)kN * 512 * 2);
    u16*   tbf   = (u16*)  alloc((size_t)kN * kC * 2);
    u16*   xbf   = (u16*)  alloc((size_t)kN * kIn * 2);
    u16*   wbf   = (u16*)  alloc((size_t)3342336 * 2);
    int*   coff  = (int*)  alloc((size_t)4097 * 4);
    int*   ccur  = (int*)  alloc((size_t)4096 * 4);
    int*   csrc  = (int*)  alloc((size_t)kET * 4);
    if (ws_size < off) return;  // not enough scratch: bail loudly (output stays poisoned)

    // MHA attention operand buffers: alias into xlb (dead during the MHA phase;
    // fully rewritten by next layer's GAT GEMM before reuse). 6 MB < 16 MB.
    u16* Qb  = (u16*)xlb;                       // [4][4096][64]
    u16* Kb  = Qb + (size_t)4 * kN * 64;        // [4][4096][64]
    u16* VTb = Kb + (size_t)4 * kN * 64;        // [4][64][4096]
    // split-K partials: opart aliases xrb (exact fit: 1024 slots x 4096 f32 = 16 MB);
    // mlpart aliases locb (1024 x 128 f32 = 512 KB). Both dead during the MHA phase.
    float* opart  = xrb;
    float* mlpart = locb;

    // bf16 weight buffer offsets (elements)
    const size_t OFF_INW  = 0;
    const size_t OFF_GWL  = 131072;
    const size_t OFF_GWR  = 917504;
    const size_t OFF_MIN  = 1703936;
    const size_t OFF_MOUT = 2293760;
    const size_t OFF_F1   = 2490368;
    const size_t OFF_F2   = 2883584;
    const size_t OFF_O1   = 3276800;

    auto cast = [&](const float* s, u16* d, int n) {
        int n4 = n >> 2;
        cast_f2b<<<dim3((n4 + 255) / 256), dim3(256), 0, stream>>>(s, d, n4);
    };
    cast(x, xbf, kN * kIn);
    cast(in_w, wbf + OFF_INW, kC * kIn);
    cast(gat_wl, wbf + OFF_GWL, kL * 1024 * kC);
    cast(gat_wr, wbf + OFF_GWR, kL * 1024 * kC);
    cast(mha_in_w, wbf + OFF_MIN, kL * 768 * kC);
    cast(mha_out_w, wbf + OFF_MOUT, kL * kC * kC);
    cast(ffn_w1, wbf + OFF_F1, kL * 512 * kC);
    cast(ffn_w2, wbf + OFF_F2, kL * kC * 512);
    cast(out_w1, wbf + OFF_O1, kC * kC);

    // CSR build (once per launch; same graph for all layers)
    hipMemsetAsync(ccur, 0, 4096 * 4, stream);
    csr_count<<<dim3((kET + 255) / 256), dim3(256), 0, stream>>>(ei, ccur);
    csr_scan<<<dim3(1), dim3(1024), 0, stream>>>(ccur, coff);
    csr_scatter<<<dim3((kET + 255) / 256), dim3(256), 0, stream>>>(ei, ccur, csrc);

    // input projection: h = x @ in_w^T + in_b  (fp32 + bf16 outputs)
    gemm_bt<0, 1, 1><<<dim3(kC / 64, kN / 64), dim3(256), 0, stream>>>(
        xbf, wbf + OFF_INW, in_b, h, hbf, kN, kC, kIn);

    for (int l = 0; l < kL; ++l) {
        // GATv2 transforms
        gemm_bt<0, 1, 0><<<dim3(1024 / 64, kN / 64), dim3(256), 0, stream>>>(
            hbf, wbf + OFF_GWL + (size_t)l * 1024 * kC, nullptr, xlb, nullptr, kN, 1024, kC);
        gemm_bt<0, 1, 0><<<dim3(1024 / 64, kN / 64), dim3(256), 0, stream>>>(
            hbf, wbf + OFF_GWR + (size_t)l * 1024 * kC, nullptr, xrb, nullptr, kN, 1024, kC);
        gat_agg<<<dim3(kN), dim3(256), 0, stream>>>(
            xlb, xrb, gat_att + (size_t)l * 1024, gat_b + (size_t)l * kC, coff, csrc, locb);
        ln_res<<<dim3(kN / 4), dim3(256), 0, stream>>>(
            h, locb, ln1_g + (size_t)l * kC, ln1_b + (size_t)l * kC, h, hbf);

        // MHA
        gemm_bt<0, 1, 0><<<dim3(768 / 64, kN / 64), dim3(256), 0, stream>>>(
            hbf, wbf + OFF_MIN + (size_t)l * 768 * kC, mha_in_b + (size_t)l * 768, qkv, nullptr, kN, 768, kC);
        qkv_repack<<<dim3(kN / 64, 4), dim3(256), 0, stream>>>(qkv, Qb, Kb, VTb);
        mha_mfma2<<<dim3(kN / 64, 4, NSPLIT), dim3(256), 0, stream>>>(Qb, Kb, VTb, opart, mlpart);
        mha_merge<<<dim3(kN / 4, 4), dim3(256), 0, stream>>>(opart, mlpart, attnb);
        gemm_bt<0, 1, 0><<<dim3(kC / 64, kN / 64), dim3(256), 0, stream>>>(
            attnb, wbf + OFF_MOUT + (size_t)l * kC * kC, mha_out_b + (size_t)l * kC, locb, nullptr, kN, kC, kC);
        ln_res<<<dim3(kN / 4), dim3(256), 0, stream>>>(
            h, locb, ln2_g + (size_t)l * kC, ln2_b + (size_t)l * kC, h, hbf);

        // FFN
        gemm_bt<1, 0, 1><<<dim3(512 / 64, kN / 64), dim3(256), 0, stream>>>(
            hbf, wbf + OFF_F1 + (size_t)l * 512 * kC, ffn_b1 + (size_t)l * 512, nullptr, midb, kN, 512, kC);
        gemm_bt<0, 1, 0><<<dim3(kC / 64, kN / 64), dim3(256), 0, stream>>>(
            midb, wbf + OFF_F2 + (size_t)l * kC * 512, ffn_b2 + (size_t)l * kC, locb, nullptr, kN, kC, 512);
        ln_res<<<dim3(kN / 4), dim3(256), 0, stream>>>(
            h, locb, ln3_g + (size_t)l * kC, ln3_b + (size_t)l * kC, h, hbf);
    }

    // output head
    gemm_bt<1, 0, 1><<<dim3(kC / 64, kN / 64), dim3(256), 0, stream>>>(
        hbf, wbf + OFF_O1, out_b1, nullptr, tbf, kN, kC, kC);
    final_out<<<dim3(kN / 4), dim3(256), 0, stream>>>(tbf, out_w2, out_b2, out);
}

// Round 5
// 776.646 us; speedup vs baseline: 6.2041x; 1.0422x over previous
//
#include <hip/hip_runtime.h>
#include <cstdint>
#include <cstddef>

typedef unsigned short u16;
typedef __bf16 bf16x8 __attribute__((ext_vector_type(8)));
typedef float f32x4 __attribute__((ext_vector_type(4)));

constexpr int kN  = 4096;
constexpr int kE  = 131072;
constexpr int kET = kE + kN;   // with self loops
constexpr int kIn = 512;
constexpr int kC  = 256;
constexpr int kL  = 3;

constexpr int NSPLIT = 4;
constexpr int KSPAN  = kN / NSPLIT;  // 1024 keys per split
constexpr int NSTEP  = KSPAN / 64;   // 16 steps of 64 keys

__device__ __forceinline__ u16 f2bf(float f) {
    unsigned u = __builtin_bit_cast(unsigned, f);
    u += 0x7fffu + ((u >> 16) & 1u);
    return (u16)(u >> 16);
}
__device__ __forceinline__ float bf2f(u16 s) {
    unsigned u = ((unsigned)s) << 16;
    return __builtin_bit_cast(float, u);
}
__device__ __forceinline__ float gelu_erf(float x) {
    return 0.5f * x * (1.f + erff(x * 0.70710678118654752f));
}
// async global->LDS, 16B per lane; ldst must be wave-uniform base (HW adds lane*16)
__device__ __forceinline__ void gload_lds16(const u16* gsrc, u16* ldst) {
    __builtin_amdgcn_global_load_lds(
        (const __attribute__((address_space(1))) unsigned int*)gsrc,
        (__attribute__((address_space(3))) unsigned int*)ldst, 16, 0, 0);
}

// ---------------- cast fp32 -> bf16 (vector4) ----------------
__global__ void cast_f2b(const float* __restrict__ src, u16* __restrict__ dst, int n4) {
    int i = blockIdx.x * blockDim.x + threadIdx.x;
    if (i >= n4) return;
    float4 v = ((const float4*)src)[i];
    ushort4 o;
    o.x = f2bf(v.x); o.y = f2bf(v.y); o.z = f2bf(v.z); o.w = f2bf(v.w);
    ((ushort4*)dst)[i] = o;
}

// ---------------- CSR build (by dst) ----------------
__global__ void csr_count(const int* __restrict__ ei, int* __restrict__ cnt) {
    int e = blockIdx.x * 256 + threadIdx.x;
    if (e >= kET) return;
    int d = (e < kE) ? ei[kE + e] : (e - kE);
    atomicAdd(cnt + d, 1);
}

__global__ __launch_bounds__(1024) void csr_scan(int* __restrict__ cnt_cur, int* __restrict__ off) {
    __shared__ int lds[1024];
    int t = threadIdx.x;
    int c[4], s = 0;
#pragma unroll
    for (int j = 0; j < 4; ++j) { c[j] = cnt_cur[t * 4 + j]; s += c[j]; }
    lds[t] = s;
    __syncthreads();
    for (int d = 1; d < 1024; d <<= 1) {
        int v = (t >= d) ? lds[t - d] : 0;
        __syncthreads();
        lds[t] += v;
        __syncthreads();
    }
    int excl = lds[t] - s;
#pragma unroll
    for (int j = 0; j < 4; ++j) { off[t * 4 + j] = excl; cnt_cur[t * 4 + j] = excl; excl += c[j]; }
    if (t == 1023) off[4096] = excl;
}

__global__ void csr_scatter(const int* __restrict__ ei, int* __restrict__ cur, int* __restrict__ csrc) {
    int e = blockIdx.x * 256 + threadIdx.x;
    if (e >= kET) return;
    int s, d;
    if (e < kE) { s = ei[e]; d = ei[kE + e]; } else { s = d = e - kE; }
    int pos = atomicAdd(cur + d, 1);
    csrc[pos] = s;
}

// ---------------- bf16 MFMA GEMM: C[M,N] = act(A[M,K] @ W[N,K]^T + bias) ----------------
// block 256 = 4 waves; block tile 64x64; wave tile 32x32 (2x2 of 16x16x32 MFMA)
template <int ACT, int WF32, int WBF16>
__global__ __launch_bounds__(256) void gemm_bt(
    const u16* __restrict__ A, const u16* __restrict__ W,
    const float* __restrict__ bias, float* __restrict__ Cf,
    u16* __restrict__ Cb, int M, int N, int K) {
    int wave = threadIdx.x >> 6, lane = threadIdx.x & 63;
    int bm = blockIdx.y * 64 + (wave >> 1) * 32;
    int bn = blockIdx.x * 64 + (wave & 1) * 32;
    int lr = lane & 15, lk = (lane >> 4) * 8;
    const u16* Ap = A + (size_t)(bm + lr) * K + lk;
    const u16* Wp = W + (size_t)(bn + lr) * K + lk;
    f32x4 acc[2][2] = {};
    for (int k0 = 0; k0 < K; k0 += 32) {
        bf16x8 a0 = *(const bf16x8*)(Ap + k0);
        bf16x8 a1 = *(const bf16x8*)(Ap + (size_t)16 * K + k0);
        bf16x8 b0 = *(const bf16x8*)(Wp + k0);
        bf16x8 b1 = *(const bf16x8*)(Wp + (size_t)16 * K + k0);
        acc[0][0] = __builtin_amdgcn_mfma_f32_16x16x32_bf16(a0, b0, acc[0][0], 0, 0, 0);
        acc[0][1] = __builtin_amdgcn_mfma_f32_16x16x32_bf16(a0, b1, acc[0][1], 0, 0, 0);
        acc[1][0] = __builtin_amdgcn_mfma_f32_16x16x32_bf16(a1, b0, acc[1][0], 0, 0, 0);
        acc[1][1] = __builtin_amdgcn_mfma_f32_16x16x32_bf16(a1, b1, acc[1][1], 0, 0, 0);
    }
    int r0 = bm + (lane >> 4) * 4;
    int c0 = bn + (lane & 15);
#pragma unroll
    for (int i = 0; i < 2; ++i)
#pragma unroll
        for (int j = 0; j < 2; ++j)
#pragma unroll
            for (int r = 0; r < 4; ++r) {
                int row = r0 + i * 16 + r, col = c0 + j * 16;
                float v = acc[i][j][r];
                if (bias) v += bias[col];
                if (ACT == 1) v = gelu_erf(v);
                if (WF32) Cf[(size_t)row * N + col] = v;
                if (WBF16) Cb[(size_t)row * N + col] = f2bf(v);
            }
}

// ---------------- LayerNorm(h + add) -> h (fp32) and h_bf (bf16); wave per row ----------------
__global__ __launch_bounds__(256) void ln_res(
    const float* hin, const float* add,
    const float* __restrict__ g, const float* __restrict__ b,
    float* hout, u16* __restrict__ hbf) {
    int row = blockIdx.x * 4 + (threadIdx.x >> 6);
    int lane = threadIdx.x & 63;
    const float4 x4 = *(const float4*)(hin + (size_t)row * kC + lane * 4);
    const float4 a4 = *(const float4*)(add + (size_t)row * kC + lane * 4);
    float v[4] = {x4.x + a4.x, x4.y + a4.y, x4.z + a4.z, x4.w + a4.w};
    float s = v[0] + v[1] + v[2] + v[3];
    for (int d = 1; d < 64; d <<= 1) s += __shfl_xor(s, d);
    float mu = s * (1.f / kC);
    float q = 0.f;
#pragma unroll
    for (int j = 0; j < 4; ++j) { float d = v[j] - mu; q += d * d; }
    for (int d = 1; d < 64; d <<= 1) q += __shfl_xor(q, d);
    float rstd = rsqrtf(q * (1.f / kC) + 1e-5f);
    const float4 g4 = *(const float4*)(g + lane * 4);
    const float4 b4 = *(const float4*)(b + lane * 4);
    float y0 = (v[0] - mu) * rstd * g4.x + b4.x;
    float y1 = (v[1] - mu) * rstd * g4.y + b4.y;
    float y2 = (v[2] - mu) * rstd * g4.z + b4.z;
    float y3 = (v[3] - mu) * rstd * g4.w + b4.w;
    *(float4*)(hout + (size_t)row * kC + lane * 4) = make_float4(y0, y1, y2, y3);
    ushort4 o; o.x = f2bf(y0); o.y = f2bf(y1); o.z = f2bf(y2); o.w = f2bf(y3);
    *(ushort4*)(hbf + (size_t)row * kC + lane * 4) = o;
}

// ---------------- GATv2: per-node online softmax aggregation; wave = head ----------------
// bf16 xl/xr (halved gather bytes). Branch-form online softmax (p>m rescale is a
// rare wave-uniform branch); 2 interleaved independent states for MLP; exact merge.
__global__ __launch_bounds__(256) void gat_agg(
    const u16* __restrict__ xl, const u16* __restrict__ xr,
    const float* __restrict__ att, const float* __restrict__ gb,
    const int* __restrict__ off, const int* __restrict__ srcs,
    float* __restrict__ outloc) {
    int n = blockIdx.x;
    int w = threadIdx.x >> 6, lane = threadIdx.x & 63;
    int base = w * 256 + lane * 4;
    ushort4 xr4 = *(const ushort4*)(xr + (size_t)n * 1024 + base);
    float xr0 = bf2f(xr4.x), xr1 = bf2f(xr4.y), xr2 = bf2f(xr4.z), xr3 = bf2f(xr4.w);
    const float4 av = *(const float4*)(att + base);
    int i0 = off[n], i1 = off[n + 1];

    float mA = -1e30f, lsA = 0.f, a0A = 0.f, a1A = 0.f, a2A = 0.f, a3A = 0.f;
    float mB = -1e30f, lsB = 0.f, a0B = 0.f, a1B = 0.f, a2B = 0.f, a3B = 0.f;

    auto edge = [&](int s, float& m, float& ls, float& a0, float& a1, float& a2, float& a3) {
        ushort4 x4 = *(const ushort4*)(xl + (size_t)s * 1024 + base);
        float x0 = bf2f(x4.x), x1 = bf2f(x4.y), x2 = bf2f(x4.z), x3 = bf2f(x4.w);
        float e0 = x0 + xr0; e0 = e0 > 0.f ? e0 : 0.2f * e0;
        float e1 = x1 + xr1; e1 = e1 > 0.f ? e1 : 0.2f * e1;
        float e2 = x2 + xr2; e2 = e2 > 0.f ? e2 : 0.2f * e2;
        float e3 = x3 + xr3; e3 = e3 > 0.f ? e3 : 0.2f * e3;
        float p = av.x * e0 + av.y * e1 + av.z * e2 + av.w * e3;
        p += __shfl_xor(p, 1); p += __shfl_xor(p, 2); p += __shfl_xor(p, 4);
        p += __shfl_xor(p, 8); p += __shfl_xor(p, 16); p += __shfl_xor(p, 32);
        if (p > m) {  // wave-uniform (p identical across lanes post-reduce)
            float c = __expf(m - p);
            ls = ls * c + 1.f;
            a0 = a0 * c + x0; a1 = a1 * c + x1; a2 = a2 * c + x2; a3 = a3 * c + x3;
            m = p;
        } else {
            float pw = __expf(p - m);
            ls += pw;
            a0 += pw * x0; a1 += pw * x1; a2 += pw * x2; a3 += pw * x3;
        }
    };
    int i = i0;
    for (; i + 1 < i1; i += 2) {
        edge(srcs[i],     mA, lsA, a0A, a1A, a2A, a3A);
        edge(srcs[i + 1], mB, lsB, a0B, a1B, a2B, a3B);
    }
    if (i < i1) edge(srcs[i], mA, lsA, a0A, a1A, a2A, a3A);
    // exact merge of the two partial softmax states
    float mm = fmaxf(mA, mB);
    float cA = __expf(mA - mm), cB = __expf(mB - mm);
    float lsum = lsA * cA + lsB * cB;
    float inv = 1.f / lsum;
    float r0 = (a0A * cA + a0B * cB) * inv;
    float r1 = (a1A * cA + a1B * cB) * inv;
    float r2 = (a2A * cA + a2B * cB) * inv;
    float r3 = (a3A * cA + a3B * cB) * inv;

    __shared__ float red[4][256];
    red[w][lane * 4 + 0] = r0;
    red[w][lane * 4 + 1] = r1;
    red[w][lane * 4 + 2] = r2;
    red[w][lane * 4 + 3] = r3;
    __syncthreads();
    int c = threadIdx.x;
    float vsum = 0.25f * (red[0][c] + red[1][c] + red[2][c] + red[3][c]) + gb[c];
    outloc[(size_t)n * kC + c] = vsum;
}

// ---------------- qkv repack: qkvb bf16 [4096][768] -> Qb/Kb [4][4096][64], VTb [4][64][4096]
// Q scaled by 1/sqrt(64) * log2(e) so attention can use exp2 directly.
__global__ __launch_bounds__(256) void qkv_repack(
    const u16* __restrict__ qkvb, u16* __restrict__ Qb, u16* __restrict__ Kb,
    u16* __restrict__ VTb) {
    int h = blockIdx.y;
    int n0 = blockIdx.x * 64;
    int t = threadIdx.x;
    int nr = t >> 2, cb = (t & 3) * 16;
    const u16* src = qkvb + (size_t)(n0 + nr) * 768 + h * 64 + cb;
    u16* qd = Qb + ((size_t)h * kN + n0 + nr) * 64 + cb;
    u16* kd = Kb + ((size_t)h * kN + n0 + nr) * 64 + cb;
    __shared__ u16 lds[64][72];
    constexpr float QS = 0.125f * 1.4426950408889634f;  // 1/sqrt(DH) * log2(e)
#pragma unroll
    for (int j = 0; j < 16; j += 4) {
        ushort4 q4 = *(const ushort4*)(src + j);
        ushort4 k4 = *(const ushort4*)(src + 256 + j);
        ushort4 v4 = *(const ushort4*)(src + 512 + j);
        ushort4 qo;
        qo.x = f2bf(bf2f(q4.x) * QS); qo.y = f2bf(bf2f(q4.y) * QS);
        qo.z = f2bf(bf2f(q4.z) * QS); qo.w = f2bf(bf2f(q4.w) * QS);
        *(ushort4*)(qd + j) = qo;
        *(ushort4*)(kd + j) = k4;
        *(ushort4*)(&lds[nr][cb + j]) = v4;
    }
    __syncthreads();
    int d = t >> 2, nb = (t & 3) * 16;
    u16* vd = VTb + ((size_t)h * 64 + d) * kN + n0 + nb;
#pragma unroll
    for (int j = 0; j < 16; j += 4) {
        ushort4 vo;
        vo.x = lds[nb + j + 0][d];
        vo.y = lds[nb + j + 1][d];
        vo.z = lds[nb + j + 2][d];
        vo.w = lds[nb + j + 3][d];
        *(ushort4*)(vd + j) = vo;
    }
}

// ---------------- MFMA flash attention, LDS-shared K/V, split-K ----------------
// Block = 4 waves, 64 q rows (16/wave). Grid (kN/64, heads, NSPLIT).
// K and VT 64x64 tiles double-buffered in LDS via global_load_lds with XOR-swizzled
// source (chunk ^= row&7) so fragment ds_read_b128 spreads over all bank groups.
// Writes unnormalized partial O + (m,l) per split; mha_merge recombines (LSE merge).
__global__ __launch_bounds__(256, 4) void mha_mfma2(
    const u16* __restrict__ Qb, const u16* __restrict__ Kb,
    const u16* __restrict__ VTb, float* __restrict__ opart, float* __restrict__ mlpart) {
    int qt = blockIdx.x, head = blockIdx.y, sp = blockIdx.z;
    int tid = threadIdx.x;
    int w = tid >> 6, lane = tid & 63;
    int g = lane >> 4, r = lane & 15;
    int q0 = qt * 64;
    const u16* Qh = Qb + ((size_t)head * kN + q0 + w * 16) * 64;
    const u16* Kh = Kb + (size_t)head * kN * 64;
    const u16* VTh = VTb + (size_t)head * 64 * kN;
    __shared__ u16 Kt[2][64 * 64];
    __shared__ u16 Vt[2][64 * 64];
    __shared__ u16 plds[4][16 * 64];
    // staging geometry: instr i in {0,1}; lane covers (row = i*32 + w*8 + (lane>>3), chunk = lane&7)
    // of the 64x64 tile; global chunk is XOR-swizzled by row&7 (= (lane>>3)&7).
    int srow = w * 8 + (lane >> 3);
    int schunk = ((lane & 7) ^ ((lane >> 3) & 7)) * 8;   // element offset within row
    int kbase = sp * KSPAN;

    bf16x8 qf0 = *(const bf16x8*)(Qh + r * 64 + g * 8);
    bf16x8 qf1 = *(const bf16x8*)(Qh + r * 64 + 32 + g * 8);

    auto stage = [&](int buf, int k0) {
#pragma unroll
        for (int i = 0; i < 2; ++i) {
            int row = i * 32 + srow;
            gload_lds16(Kh + (size_t)(k0 + row) * 64 + schunk, &Kt[buf][(i * 32 + w * 8) * 64]);
            gload_lds16(VTh + (size_t)row * kN + k0 + schunk, &Vt[buf][(i * 32 + w * 8) * 64]);
        }
    };

    f32x4 o[4] = {};
    float m = -3.0e38f, l = 0.f;

    stage(0, kbase);
    __syncthreads();   // vmcnt(0) drain + barrier: buffer 0 ready

    for (int st = 0; st < NSTEP; ++st) {
        int cur = st & 1;
        if (st + 1 < NSTEP) stage(cur ^ 1, kbase + (st + 1) * 64);
        const u16* Kl = &Kt[cur][0];
        const u16* Vl = &Vt[cur][0];
        int rx = r & 7;
        // S^T tiles: rows = keys (16t + 4g + reg), cols = q (r)
        f32x4 stt[4] = {};
#pragma unroll
        for (int t = 0; t < 4; ++t) {
            bf16x8 kf0 = *(const bf16x8*)(Kl + (16 * t + r) * 64 + ((0 + g) ^ rx) * 8);
            bf16x8 kf1 = *(const bf16x8*)(Kl + (16 * t + r) * 64 + ((4 + g) ^ rx) * 8);
            stt[t] = __builtin_amdgcn_mfma_f32_16x16x32_bf16(kf0, qf0, stt[t], 0, 0, 0);
            stt[t] = __builtin_amdgcn_mfma_f32_16x16x32_bf16(kf1, qf1, stt[t], 0, 0, 0);
        }
        // online softmax (exp2 domain), state per q=r (replicated across g groups)
        float pm = stt[0][0];
#pragma unroll
        for (int t = 0; t < 4; ++t)
#pragma unroll
            for (int e = 0; e < 4; ++e) pm = fmaxf(pm, stt[t][e]);
        pm = fmaxf(pm, __shfl_xor(pm, 16));
        pm = fmaxf(pm, __shfl_xor(pm, 32));
        float mn = fmaxf(m, pm);
        float corr = __builtin_amdgcn_exp2f(m - mn);
        float ls = 0.f;
        float p[4][4];
#pragma unroll
        for (int t = 0; t < 4; ++t)
#pragma unroll
            for (int e = 0; e < 4; ++e) { p[t][e] = __builtin_amdgcn_exp2f(stt[t][e] - mn); ls += p[t][e]; }
        ls += __shfl_xor(ls, 16);
        ls += __shfl_xor(ls, 32);
        l = l * corr + ls;
        m = mn;
        // rescale O: O rows are q = 4g+reg, state lives at q = r -> fetch corr per row
        float corrq[4];
#pragma unroll
        for (int e = 0; e < 4; ++e) corrq[e] = __shfl(corr, g * 4 + e);
#pragma unroll
        for (int dt = 0; dt < 4; ++dt)
#pragma unroll
            for (int e = 0; e < 4; ++e) o[dt][e] *= corrq[e];
        // P: C-layout -> LDS -> A-layout (per-wave private, waitcnt-ordered)
#pragma unroll
        for (int t = 0; t < 4; ++t) {
            ushort4 pk;
            pk.x = f2bf(p[t][0]); pk.y = f2bf(p[t][1]);
            pk.z = f2bf(p[t][2]); pk.w = f2bf(p[t][3]);
            *(ushort4*)(&plds[w][r * 64 + 16 * t + 4 * g]) = pk;
        }
        bf16x8 pa0 = *(const bf16x8*)(&plds[w][r * 64 + 8 * g]);
        bf16x8 pa1 = *(const bf16x8*)(&plds[w][r * 64 + 32 + 8 * g]);
#pragma unroll
        for (int dt = 0; dt < 4; ++dt) {
            bf16x8 vf0 = *(const bf16x8*)(Vl + (dt * 16 + r) * 64 + ((0 + g) ^ rx) * 8);
            bf16x8 vf1 = *(const bf16x8*)(Vl + (dt * 16 + r) * 64 + ((4 + g) ^ rx) * 8);
            o[dt] = __builtin_amdgcn_mfma_f32_16x16x32_bf16(pa0, vf0, o[dt], 0, 0, 0);
            o[dt] = __builtin_amdgcn_mfma_f32_16x16x32_bf16(pa1, vf1, o[dt], 0, 0, 0);
        }
        __syncthreads();   // vmcnt(0): next buffer staged; lgkmcnt: all reads of cur done
    }

    // store unnormalized partials
    size_t slot = (size_t)(head * 64 + qt) * NSPLIT + sp;
    float* ob = opart + slot * 4096;
#pragma unroll
    for (int dt = 0; dt < 4; ++dt)
#pragma unroll
        for (int e = 0; e < 4; ++e)
            ob[(w * 16 + g * 4 + e) * 64 + dt * 16 + r] = o[dt][e];
    float* mlb = mlpart + slot * 128;
    if (g == 0) { mlb[w * 16 + r] = m; mlb[64 + w * 16 + r] = l; }
}

// ---------------- merge split-K attention partials -> attnb (bf16) ----------------
// grid (kN/4, heads), block 256: wave w = one q row, lane = d (0..63)
__global__ __launch_bounds__(256) void mha_merge(
    const float* __restrict__ opart, const float* __restrict__ mlpart,
    u16* __restrict__ attnb) {
    int head = blockIdx.y;
    int q = blockIdx.x * 4 + (threadIdx.x >> 6);
    int d = threadIdx.x & 63;
    int qt = q >> 6, ql = q & 63;
    size_t sb = (size_t)(head * 64 + qt) * NSPLIT;
    float ms[NSPLIT], lsv[NSPLIT];
    float mstar = -3.0e38f;
#pragma unroll
    for (int s = 0; s < NSPLIT; ++s) {
        ms[s] = mlpart[(sb + s) * 128 + ql];
        lsv[s] = mlpart[(sb + s) * 128 + 64 + ql];
        mstar = fmaxf(mstar, ms[s]);
    }
    float acc = 0.f, lsum = 0.f;
#pragma unroll
    for (int s = 0; s < NSPLIT; ++s) {
        float wgt = __builtin_amdgcn_exp2f(ms[s] - mstar);
        lsum += lsv[s] * wgt;
        acc += opart[(sb + s) * 4096 + ql * 64 + d] * wgt;
    }
    attnb[(size_t)q * kC + head * 64 + d] = f2bf(acc / lsum);
}

// ---------------- final: out[4096,2] = t_bf @ out_w2^T + b2; wave per row ----------------
__global__ __launch_bounds__(256) void final_out(
    const u16* __restrict__ tbf, const float* __restrict__ w2,
    const float* __restrict__ b2, float* __restrict__ out) {
    int row = blockIdx.x * 4 + (threadIdx.x >> 6);
    int lane = threadIdx.x & 63;
    const ushort4 tv = *(const ushort4*)(tbf + (size_t)row * 256 + lane * 4);
    float t0 = bf2f(tv.x), t1 = bf2f(tv.y), t2 = bf2f(tv.z), t3 = bf2f(tv.w);
    const float4 w0 = *(const float4*)(w2 + lane * 4);
    const float4 w1 = *(const float4*)(w2 + 256 + lane * 4);
    float d0 = t0 * w0.x + t1 * w0.y + t2 * w0.z + t3 * w0.w;
    float d1 = t0 * w1.x + t1 * w1.y + t2 * w1.z + t3 * w1.w;
    for (int d = 1; d < 64; d <<= 1) { d0 += __shfl_xor(d0, d); d1 += __shfl_xor(d1, d); }
    if (lane == 0) {
        out[(size_t)row * 2 + 0] = d0 + b2[0];
        out[(size_t)row * 2 + 1] = d1 + b2[1];
    }
}

extern "C" void kernel_launch(void* const* d_in, const int* in_sizes, int n_in,
                              void* d_out, int out_size, void* d_ws, size_t ws_size,
                              hipStream_t stream) {
    (void)in_sizes; (void)n_in; (void)out_size;
    const float* x        = (const float*)d_in[0];
    const int*   ei       = (const int*)d_in[1];
    const float* in_w     = (const float*)d_in[2];
    const float* in_b     = (const float*)d_in[3];
    const float* gat_wl   = (const float*)d_in[4];
    const float* gat_wr   = (const float*)d_in[5];
    const float* gat_att  = (const float*)d_in[6];
    const float* gat_b    = (const float*)d_in[7];
    const float* mha_in_w = (const float*)d_in[8];
    const float* mha_in_b = (const float*)d_in[9];
    const float* mha_out_w= (const float*)d_in[10];
    const float* mha_out_b= (const float*)d_in[11];
    const float* ln1_g = (const float*)d_in[12];
    const float* ln1_b = (const float*)d_in[13];
    const float* ln2_g = (const float*)d_in[14];
    const float* ln2_b = (const float*)d_in[15];
    const float* ln3_g = (const float*)d_in[16];
    const float* ln3_b = (const float*)d_in[17];
    const float* ffn_w1 = (const float*)d_in[18];
    const float* ffn_b1 = (const float*)d_in[19];
    const float* ffn_w2 = (const float*)d_in[20];
    const float* ffn_b2 = (const float*)d_in[21];
    const float* out_w1 = (const float*)d_in[22];
    const float* out_b1 = (const float*)d_in[23];
    const float* out_w2 = (const float*)d_in[24];
    const float* out_b2 = (const float*)d_in[25];
    float* out = (float*)d_out;

    char* ws = (char*)d_ws;
    size_t off = 0;
    auto alloc = [&](size_t bytes) -> void* {
        void* p = (void*)(ws + off);
        off += (bytes + 255) & ~(size_t)255;
        return p;
    };
    float* h     = (float*)alloc((size_t)kN * kC * 4);
    u16*   hbf   = (u16*)  alloc((size_t)kN * kC * 2);
    float* xlb   = (float*)alloc((size_t)kN * 1024 * 4);   // slot reused: xlbf+xrbf / Qb+Kb+VTb
    float* xrb   = (float*)alloc((size_t)kN * 1024 * 4);   // slot reused: opart
    float* qkv   = (float*)alloc((size_t)kN * 768 * 4);    // slot reused: qkvb (bf16)
    float* locb  = (float*)alloc((size_t)kN * kC * 4);
    u16*   attnb = (u16*)  alloc((size_t)kN * kC * 2);
    u16*   midb  = (u16*)  alloc((size_t)kN * 512 * 2);
    u16*   tbf   = (u16*)  alloc((size_t)kN * kC * 2);
    u16*   xbf   = (u16*)  alloc((size_t)kN * kIn * 2);
    u16*   wbf   = (u16*)  alloc((size_t)3342336 * 2);
    int*   coff  = (int*)  alloc((size_t)4097 * 4);
    int*   ccur  = (int*)  alloc((size_t)4096 * 4);
    int*   csrc  = (int*)  alloc((size_t)kET * 4);
    if (ws_size < off) return;  // not enough scratch: bail loudly (output stays poisoned)

    // GAT transforms in bf16, carved from the xlb slot (8 MB + 8 MB = 16 MB slot).
    u16* xlbf = (u16*)xlb;                      // [4096][1024] bf16
    u16* xrbf = xlbf + (size_t)kN * 1024;       // [4096][1024] bf16
    // MHA attention operands: alias the same slot (xlbf/xrbf dead after gat_agg/ln1).
    u16* Qb  = (u16*)xlb;                       // [4][4096][64]
    u16* Kb  = Qb + (size_t)4 * kN * 64;        // [4][4096][64]
    u16* VTb = Kb + (size_t)4 * kN * 64;        // [4][64][4096]
    // qkv in bf16, carved from the qkv slot.
    u16* qkvb = (u16*)qkv;                      // [4096][768] bf16
    // split-K partials: opart = xrb slot (1024 slots x 4096 f32 = 16 MB exact);
    // mlpart = locb slot (dead between ln1 and the mout GEMM).
    float* opart  = xrb;
    float* mlpart = locb;

    // bf16 weight buffer offsets (elements)
    const size_t OFF_INW  = 0;
    const size_t OFF_GWL  = 131072;
    const size_t OFF_GWR  = 917504;
    const size_t OFF_MIN  = 1703936;
    const size_t OFF_MOUT = 2293760;
    const size_t OFF_F1   = 2490368;
    const size_t OFF_F2   = 2883584;
    const size_t OFF_O1   = 3276800;

    auto cast = [&](const float* s, u16* d, int n) {
        int n4 = n >> 2;
        cast_f2b<<<dim3((n4 + 255) / 256), dim3(256), 0, stream>>>(s, d, n4);
    };
    cast(x, xbf, kN * kIn);
    cast(in_w, wbf + OFF_INW, kC * kIn);
    cast(gat_wl, wbf + OFF_GWL, kL * 1024 * kC);
    cast(gat_wr, wbf + OFF_GWR, kL * 1024 * kC);
    cast(mha_in_w, wbf + OFF_MIN, kL * 768 * kC);
    cast(mha_out_w, wbf + OFF_MOUT, kL * kC * kC);
    cast(ffn_w1, wbf + OFF_F1, kL * 512 * kC);
    cast(ffn_w2, wbf + OFF_F2, kL * kC * 512);
    cast(out_w1, wbf + OFF_O1, kC * kC);

    // CSR build (once per launch; same graph for all layers)
    hipMemsetAsync(ccur, 0, 4096 * 4, stream);
    csr_count<<<dim3((kET + 255) / 256), dim3(256), 0, stream>>>(ei, ccur);
    csr_scan<<<dim3(1), dim3(1024), 0, stream>>>(ccur, coff);
    csr_scatter<<<dim3((kET + 255) / 256), dim3(256), 0, stream>>>(ei, ccur, csrc);

    // input projection: h = x @ in_w^T + in_b  (fp32 + bf16 outputs)
    gemm_bt<0, 1, 1><<<dim3(kC / 64, kN / 64), dim3(256), 0, stream>>>(
        xbf, wbf + OFF_INW, in_b, h, hbf, kN, kC, kIn);

    for (int l = 0; l < kL; ++l) {
        // GATv2 transforms (bf16 outputs)
        gemm_bt<0, 0, 1><<<dim3(1024 / 64, kN / 64), dim3(256), 0, stream>>>(
            hbf, wbf + OFF_GWL + (size_t)l * 1024 * kC, nullptr, nullptr, xlbf, kN, 1024, kC);
        gemm_bt<0, 0, 1><<<dim3(1024 / 64, kN / 64), dim3(256), 0, stream>>>(
            hbf, wbf + OFF_GWR + (size_t)l * 1024 * kC, nullptr, nullptr, xrbf, kN, 1024, kC);
        gat_agg<<<dim3(kN), dim3(256), 0, stream>>>(
            xlbf, xrbf, gat_att + (size_t)l * 1024, gat_b + (size_t)l * kC, coff, csrc, locb);
        ln_res<<<dim3(kN / 4), dim3(256), 0, stream>>>(
            h, locb, ln1_g + (size_t)l * kC, ln1_b + (size_t)l * kC, h, hbf);

        // MHA
        gemm_bt<0, 0, 1><<<dim3(768 / 64, kN / 64), dim3(256), 0, stream>>>(
            hbf, wbf + OFF_MIN + (size_t)l * 768 * kC, mha_in_b + (size_t)l * 768, nullptr, qkvb, kN, 768, kC);
        qkv_repack<<<dim3(kN / 64, 4), dim3(256), 0, stream>>>(qkvb, Qb, Kb, VTb);
        mha_mfma2<<<dim3(kN / 64, 4, NSPLIT), dim3(256), 0, stream>>>(Qb, Kb, VTb, opart, mlpart);
        mha_merge<<<dim3(kN / 4, 4), dim3(256), 0, stream>>>(opart, mlpart, attnb);
        gemm_bt<0, 1, 0><<<dim3(kC / 64, kN / 64), dim3(256), 0, stream>>>(
            attnb, wbf + OFF_MOUT + (size_t)l * kC * kC, mha_out_b + (size_t)l * kC, locb, nullptr, kN, kC, kC);
        ln_res<<<dim3(kN / 4), dim3(256), 0, stream>>>(
            h, locb, ln2_g + (size_t)l * kC, ln2_b + (size_t)l * kC, h, hbf);

        // FFN
        gemm_bt<1, 0, 1><<<dim3(512 / 64, kN / 64), dim3(256), 0, stream>>>(
            hbf, wbf + OFF_F1 + (size_t)l * 512 * kC, ffn_b1 + (size_t)l * 512, nullptr, midb, kN, 512, kC);
        gemm_bt<0, 1, 0><<<dim3(kC / 64, kN / 64), dim3(256), 0, stream>>>(
            midb, wbf + OFF_F2 + (size_t)l * kC * 512, ffn_b2 + (size_t)l * kC, locb, nullptr, kN, kC, 512);
        ln_res<<<dim3(kN / 4), dim3(256), 0, stream>>>(
            h, locb, ln3_g + (size_t)l * kC, ln3_b + (size_t)l * kC, h, hbf);
    }

    // output head
    gemm_bt<1, 0, 1><<<dim3(kC / 64, kN / 64), dim3(256), 0, stream>>>(
        hbf, wbf + OFF_O1, out_b1, nullptr, tbf, kN, kC, kC);
    final_out<<<dim3(kN / 4), dim3(256), 0, stream>>>(tbf, out_w2, out_b2, out);
}

// Round 6
// 697.579 us; speedup vs baseline: 6.9073x; 1.1133x over previous
//
#include <hip/hip_runtime.h>
#include <cstdint>
#include <cstddef>

typedef unsigned short u16;
typedef __bf16 bf16x8 __attribute__((ext_vector_type(8)));
typedef float f32x4 __attribute__((ext_vector_type(4)));

constexpr int kN  = 4096;
constexpr int kE  = 131072;
constexpr int kET = kE + kN;   // with self loops
constexpr int kIn = 512;
constexpr int kC  = 256;
constexpr int kL  = 3;

constexpr int NSPLIT = 4;
constexpr int KSPAN  = kN / NSPLIT;  // 1024 keys per split
constexpr int NSTEP  = KSPAN / 64;   // 16 steps of 64 keys

__device__ __forceinline__ u16 f2bf(float f) {
    unsigned u = __builtin_bit_cast(unsigned, f);
    u += 0x7fffu + ((u >> 16) & 1u);
    return (u16)(u >> 16);
}
__device__ __forceinline__ float bf2f(u16 s) {
    unsigned u = ((unsigned)s) << 16;
    return __builtin_bit_cast(float, u);
}
__device__ __forceinline__ float gelu_erf(float x) {
    return 0.5f * x * (1.f + erff(x * 0.70710678118654752f));
}
// async global->LDS, 16B per lane; ldst must be wave-uniform base (HW adds lane*16)
__device__ __forceinline__ void gload_lds16(const u16* gsrc, u16* ldst) {
    __builtin_amdgcn_global_load_lds(
        (const __attribute__((address_space(1))) unsigned int*)gsrc,
        (__attribute__((address_space(3))) unsigned int*)ldst, 16, 0, 0);
}
// sum over each row of 16 lanes via DPP row_ror adds (full-rate VALU, no LDS pipe)
__device__ __forceinline__ float dpp_ror_add16(float x) {
    int t;
    t = __builtin_amdgcn_update_dpp(0, __builtin_bit_cast(int, x), 0x121, 0xf, 0xf, true);
    x += __builtin_bit_cast(float, t);
    t = __builtin_amdgcn_update_dpp(0, __builtin_bit_cast(int, x), 0x122, 0xf, 0xf, true);
    x += __builtin_bit_cast(float, t);
    t = __builtin_amdgcn_update_dpp(0, __builtin_bit_cast(int, x), 0x124, 0xf, 0xf, true);
    x += __builtin_bit_cast(float, t);
    t = __builtin_amdgcn_update_dpp(0, __builtin_bit_cast(int, x), 0x128, 0xf, 0xf, true);
    x += __builtin_bit_cast(float, t);
    return x;
}
// unpack 8 bf16 (uint4) -> 8 f32
__device__ __forceinline__ void unpack8(uint4 u, float* x) {
    x[0] = __builtin_bit_cast(float, u.x << 16);
    x[1] = __builtin_bit_cast(float, u.x & 0xffff0000u);
    x[2] = __builtin_bit_cast(float, u.y << 16);
    x[3] = __builtin_bit_cast(float, u.y & 0xffff0000u);
    x[4] = __builtin_bit_cast(float, u.z << 16);
    x[5] = __builtin_bit_cast(float, u.z & 0xffff0000u);
    x[6] = __builtin_bit_cast(float, u.w << 16);
    x[7] = __builtin_bit_cast(float, u.w & 0xffff0000u);
}

// ---------------- cast fp32 -> bf16 (vector4) ----------------
__global__ void cast_f2b(const float* __restrict__ src, u16* __restrict__ dst, int n4) {
    int i = blockIdx.x * blockDim.x + threadIdx.x;
    if (i >= n4) return;
    float4 v = ((const float4*)src)[i];
    ushort4 o;
    o.x = f2bf(v.x); o.y = f2bf(v.y); o.z = f2bf(v.z); o.w = f2bf(v.w);
    ((ushort4*)dst)[i] = o;
}

// ---------------- CSR build (by dst) ----------------
__global__ void csr_count(const int* __restrict__ ei, int* __restrict__ cnt) {
    int e = blockIdx.x * 256 + threadIdx.x;
    if (e >= kET) return;
    int d = (e < kE) ? ei[kE + e] : (e - kE);
    atomicAdd(cnt + d, 1);
}

__global__ __launch_bounds__(1024) void csr_scan(int* __restrict__ cnt_cur, int* __restrict__ off) {
    __shared__ int lds[1024];
    int t = threadIdx.x;
    int c[4], s = 0;
#pragma unroll
    for (int j = 0; j < 4; ++j) { c[j] = cnt_cur[t * 4 + j]; s += c[j]; }
    lds[t] = s;
    __syncthreads();
    for (int d = 1; d < 1024; d <<= 1) {
        int v = (t >= d) ? lds[t - d] : 0;
        __syncthreads();
        lds[t] += v;
        __syncthreads();
    }
    int excl = lds[t] - s;
#pragma unroll
    for (int j = 0; j < 4; ++j) { off[t * 4 + j] = excl; cnt_cur[t * 4 + j] = excl; excl += c[j]; }
    if (t == 1023) off[4096] = excl;
}

__global__ void csr_scatter(const int* __restrict__ ei, int* __restrict__ cur, int* __restrict__ csrc) {
    int e = blockIdx.x * 256 + threadIdx.x;
    if (e >= kET) return;
    int s, d;
    if (e < kE) { s = ei[e]; d = ei[kE + e]; } else { s = d = e - kE; }
    int pos = atomicAdd(cur + d, 1);
    csrc[pos] = s;
}

// ---------------- bf16 MFMA GEMM: C[M,N] = act(A[M,K] @ W[N,K]^T + bias) ----------------
// block 256 = 4 waves; block tile 64x64; wave tile 32x32 (2x2 of 16x16x32 MFMA)
template <int ACT, int WF32, int WBF16>
__global__ __launch_bounds__(256) void gemm_bt(
    const u16* __restrict__ A, const u16* __restrict__ W,
    const float* __restrict__ bias, float* __restrict__ Cf,
    u16* __restrict__ Cb, int M, int N, int K) {
    int wave = threadIdx.x >> 6, lane = threadIdx.x & 63;
    int bm = blockIdx.y * 64 + (wave >> 1) * 32;
    int bn = blockIdx.x * 64 + (wave & 1) * 32;
    int lr = lane & 15, lk = (lane >> 4) * 8;
    const u16* Ap = A + (size_t)(bm + lr) * K + lk;
    const u16* Wp = W + (size_t)(bn + lr) * K + lk;
    f32x4 acc[2][2] = {};
    for (int k0 = 0; k0 < K; k0 += 32) {
        bf16x8 a0 = *(const bf16x8*)(Ap + k0);
        bf16x8 a1 = *(const bf16x8*)(Ap + (size_t)16 * K + k0);
        bf16x8 b0 = *(const bf16x8*)(Wp + k0);
        bf16x8 b1 = *(const bf16x8*)(Wp + (size_t)16 * K + k0);
        acc[0][0] = __builtin_amdgcn_mfma_f32_16x16x32_bf16(a0, b0, acc[0][0], 0, 0, 0);
        acc[0][1] = __builtin_amdgcn_mfma_f32_16x16x32_bf16(a0, b1, acc[0][1], 0, 0, 0);
        acc[1][0] = __builtin_amdgcn_mfma_f32_16x16x32_bf16(a1, b0, acc[1][0], 0, 0, 0);
        acc[1][1] = __builtin_amdgcn_mfma_f32_16x16x32_bf16(a1, b1, acc[1][1], 0, 0, 0);
    }
    int r0 = bm + (lane >> 4) * 4;
    int c0 = bn + (lane & 15);
#pragma unroll
    for (int i = 0; i < 2; ++i)
#pragma unroll
        for (int j = 0; j < 2; ++j)
#pragma unroll
            for (int r = 0; r < 4; ++r) {
                int row = r0 + i * 16 + r, col = c0 + j * 16;
                float v = acc[i][j][r];
                if (bias) v += bias[col];
                if (ACT == 1) v = gelu_erf(v);
                if (WF32) Cf[(size_t)row * N + col] = v;
                if (WBF16) Cb[(size_t)row * N + col] = f2bf(v);
            }
}

// ---------------- LayerNorm(h + add) -> h (fp32) and h_bf (bf16); wave per row ----------------
__global__ __launch_bounds__(256) void ln_res(
    const float* hin, const float* add,
    const float* __restrict__ g, const float* __restrict__ b,
    float* hout, u16* __restrict__ hbf) {
    int row = blockIdx.x * 4 + (threadIdx.x >> 6);
    int lane = threadIdx.x & 63;
    const float4 x4 = *(const float4*)(hin + (size_t)row * kC + lane * 4);
    const float4 a4 = *(const float4*)(add + (size_t)row * kC + lane * 4);
    float v[4] = {x4.x + a4.x, x4.y + a4.y, x4.z + a4.z, x4.w + a4.w};
    float s = v[0] + v[1] + v[2] + v[3];
    for (int d = 1; d < 64; d <<= 1) s += __shfl_xor(s, d);
    float mu = s * (1.f / kC);
    float q = 0.f;
#pragma unroll
    for (int j = 0; j < 4; ++j) { float d = v[j] - mu; q += d * d; }
    for (int d = 1; d < 64; d <<= 1) q += __shfl_xor(q, d);
    float rstd = rsqrtf(q * (1.f / kC) + 1e-5f);
    const float4 g4 = *(const float4*)(g + lane * 4);
    const float4 b4 = *(const float4*)(b + lane * 4);
    float y0 = (v[0] - mu) * rstd * g4.x + b4.x;
    float y1 = (v[1] - mu) * rstd * g4.y + b4.y;
    float y2 = (v[2] - mu) * rstd * g4.z + b4.z;
    float y3 = (v[3] - mu) * rstd * g4.w + b4.w;
    *(float4*)(hout + (size_t)row * kC + lane * 4) = make_float4(y0, y1, y2, y3);
    ushort4 o; o.x = f2bf(y0); o.y = f2bf(y1); o.z = f2bf(y2); o.w = f2bf(y3);
    *(ushort4*)(hbf + (size_t)row * kC + lane * 4) = o;
}

// ---------------- GATv2: per-node online softmax aggregation ----------------
// Block = node, wave = head. Within a wave: 4 quarters (16 lanes) each process
// their own edge in lockstep (16 channels/lane), so 4 edges advance per wave-inst.
// Score reduce = 4 DPP row_ror adds (pure VALU). Per-quarter online-softmax state,
// exact 4-way LSE merge at the end. 1-edge software prefetch per quarter.
__global__ __launch_bounds__(256) void gat_agg(
    const u16* __restrict__ xl, const u16* __restrict__ xr,
    const float* __restrict__ att, const float* __restrict__ gb,
    const int* __restrict__ off, const int* __restrict__ srcs,
    float* __restrict__ outloc) {
    int n = blockIdx.x;
    int w = threadIdx.x >> 6, lane = threadIdx.x & 63;
    int q = lane >> 4, t = lane & 15;
    int cb = w * 256 + t * 16;   // channel slice [cb, cb+16) of 1024

    uint4 xru0 = *(const uint4*)(xr + (size_t)n * 1024 + cb);
    uint4 xru1 = *(const uint4*)(xr + (size_t)n * 1024 + cb + 8);
    float xrv[16];
    unpack8(xru0, xrv); unpack8(xru1, xrv + 8);
    float attv[16], att2[16];
#pragma unroll
    for (int j = 0; j < 16; j += 4) {
        float4 a4 = *(const float4*)(att + cb + j);
        attv[j] = a4.x; attv[j + 1] = a4.y; attv[j + 2] = a4.z; attv[j + 3] = a4.w;
    }
#pragma unroll
    for (int j = 0; j < 16; ++j) att2[j] = 0.2f * attv[j];

    int i0 = off[n], i1 = off[n + 1];
    float m = -1e30f, ls = 0.f;
    float acc[16] = {};
    int i = i0 + q;
    uint4 p0, p1;
    if (i < i1) {
        int s = srcs[i];
        p0 = *(const uint4*)(xl + (size_t)s * 1024 + cb);
        p1 = *(const uint4*)(xl + (size_t)s * 1024 + cb + 8);
    }
    while (i < i1) {
        uint4 c0 = p0, c1 = p1;
        int inext = i + 4;
        if (inext < i1) {
            int s2 = srcs[inext];
            p0 = *(const uint4*)(xl + (size_t)s2 * 1024 + cb);
            p1 = *(const uint4*)(xl + (size_t)s2 * 1024 + cb + 8);
        }
        float x[16];
        unpack8(c0, x); unpack8(c1, x + 8);
        float p = 0.f;
#pragma unroll
        for (int j = 0; j < 16; ++j) {
            float e = x[j] + xrv[j];
            p = fmaf(attv[j], fmaxf(e, 0.f), p);
            p = fmaf(att2[j], fminf(e, 0.f), p);
        }
        p = dpp_ror_add16(p);   // all 16 lanes of the quarter now hold the score
        if (p > m) {            // quarter-uniform; divergence between quarters is rare
            float c = __expf(m - p);
            ls = ls * c + 1.f;
#pragma unroll
            for (int j = 0; j < 16; ++j) acc[j] = acc[j] * c + x[j];
            m = p;
        } else {
            float pw = __expf(p - m);
            ls += pw;
#pragma unroll
            for (int j = 0; j < 16; ++j) acc[j] = fmaf(pw, x[j], acc[j]);
        }
        i = inext;
    }
    // exact LSE merge of the 4 quarter states (quarter index = lane bits 4..5)
    float mm = fmaxf(m, __shfl_xor(m, 16));
    mm = fmaxf(mm, __shfl_xor(mm, 32));
    float c = __expf(m - mm);   // 0 for empty quarters (m = -1e30)
    ls *= c;
    ls += __shfl_xor(ls, 16);
    ls += __shfl_xor(ls, 32);
    float inv;
#pragma unroll
    for (int j = 0; j < 16; ++j) {
        float a = acc[j] * c;
        a += __shfl_xor(a, 16);
        a += __shfl_xor(a, 32);
        acc[j] = a;
    }
    inv = 1.f / ls;
    __shared__ float red[4][256];
    if (q == 0) {
#pragma unroll
        for (int j = 0; j < 16; ++j) red[w][t * 16 + j] = acc[j] * inv;
    }
    __syncthreads();
    int cc = threadIdx.x;
    float vsum = 0.25f * (red[0][cc] + red[1][cc] + red[2][cc] + red[3][cc]) + gb[cc];
    outloc[(size_t)n * kC + cc] = vsum;
}

// ---------------- qkv repack: qkvb bf16 [4096][768] -> Qb/Kb [4][4096][64], VTb [4][64][4096]
// Q scaled by 1/sqrt(64) * log2(e) so attention can use exp2 directly.
__global__ __launch_bounds__(256) void qkv_repack(
    const u16* __restrict__ qkvb, u16* __restrict__ Qb, u16* __restrict__ Kb,
    u16* __restrict__ VTb) {
    int h = blockIdx.y;
    int n0 = blockIdx.x * 64;
    int t = threadIdx.x;
    int nr = t >> 2, cb = (t & 3) * 16;
    const u16* src = qkvb + (size_t)(n0 + nr) * 768 + h * 64 + cb;
    u16* qd = Qb + ((size_t)h * kN + n0 + nr) * 64 + cb;
    u16* kd = Kb + ((size_t)h * kN + n0 + nr) * 64 + cb;
    __shared__ u16 lds[64][72];
    constexpr float QS = 0.125f * 1.4426950408889634f;  // 1/sqrt(DH) * log2(e)
#pragma unroll
    for (int j = 0; j < 16; j += 4) {
        ushort4 q4 = *(const ushort4*)(src + j);
        ushort4 k4 = *(const ushort4*)(src + 256 + j);
        ushort4 v4 = *(const ushort4*)(src + 512 + j);
        ushort4 qo;
        qo.x = f2bf(bf2f(q4.x) * QS); qo.y = f2bf(bf2f(q4.y) * QS);
        qo.z = f2bf(bf2f(q4.z) * QS); qo.w = f2bf(bf2f(q4.w) * QS);
        *(ushort4*)(qd + j) = qo;
        *(ushort4*)(kd + j) = k4;
        *(ushort4*)(&lds[nr][cb + j]) = v4;
    }
    __syncthreads();
    int d = t >> 2, nb = (t & 3) * 16;
    u16* vd = VTb + ((size_t)h * 64 + d) * kN + n0 + nb;
#pragma unroll
    for (int j = 0; j < 16; j += 4) {
        ushort4 vo;
        vo.x = lds[nb + j + 0][d];
        vo.y = lds[nb + j + 1][d];
        vo.z = lds[nb + j + 2][d];
        vo.w = lds[nb + j + 3][d];
        *(ushort4*)(vd + j) = vo;
    }
}

// ---------------- MFMA flash attention, LDS-shared K/V, split-K ----------------
// Block = 4 waves, 64 q rows (16/wave). Grid (kN/64, heads, NSPLIT).
// K and VT 64x64 tiles double-buffered in LDS via global_load_lds with XOR-swizzled
// source (chunk ^= row&7) so fragment ds_read_b128 spreads over all bank groups.
// Writes unnormalized partial O + (m,l) per split; mha_merge recombines (LSE merge).
__global__ __launch_bounds__(256, 4) void mha_mfma2(
    const u16* __restrict__ Qb, const u16* __restrict__ Kb,
    const u16* __restrict__ VTb, float* __restrict__ opart, float* __restrict__ mlpart) {
    int qt = blockIdx.x, head = blockIdx.y, sp = blockIdx.z;
    int tid = threadIdx.x;
    int w = tid >> 6, lane = tid & 63;
    int g = lane >> 4, r = lane & 15;
    int q0 = qt * 64;
    const u16* Qh = Qb + ((size_t)head * kN + q0 + w * 16) * 64;
    const u16* Kh = Kb + (size_t)head * kN * 64;
    const u16* VTh = VTb + (size_t)head * 64 * kN;
    __shared__ u16 Kt[2][64 * 64];
    __shared__ u16 Vt[2][64 * 64];
    __shared__ u16 plds[4][16 * 64];
    // staging geometry: instr i in {0,1}; lane covers (row = i*32 + w*8 + (lane>>3), chunk = lane&7)
    // of the 64x64 tile; global chunk is XOR-swizzled by row&7 (= (lane>>3)&7).
    int srow = w * 8 + (lane >> 3);
    int schunk = ((lane & 7) ^ ((lane >> 3) & 7)) * 8;   // element offset within row
    int kbase = sp * KSPAN;

    bf16x8 qf0 = *(const bf16x8*)(Qh + r * 64 + g * 8);
    bf16x8 qf1 = *(const bf16x8*)(Qh + r * 64 + 32 + g * 8);

    auto stage = [&](int buf, int k0) {
#pragma unroll
        for (int i = 0; i < 2; ++i) {
            int row = i * 32 + srow;
            gload_lds16(Kh + (size_t)(k0 + row) * 64 + schunk, &Kt[buf][(i * 32 + w * 8) * 64]);
            gload_lds16(VTh + (size_t)row * kN + k0 + schunk, &Vt[buf][(i * 32 + w * 8) * 64]);
        }
    };

    f32x4 o[4] = {};
    float m = -3.0e38f, l = 0.f;

    stage(0, kbase);
    __syncthreads();   // vmcnt(0) drain + barrier: buffer 0 ready

    for (int st = 0; st < NSTEP; ++st) {
        int cur = st & 1;
        if (st + 1 < NSTEP) stage(cur ^ 1, kbase + (st + 1) * 64);
        const u16* Kl = &Kt[cur][0];
        const u16* Vl = &Vt[cur][0];
        int rx = r & 7;
        // S^T tiles: rows = keys (16t + 4g + reg), cols = q (r)
        f32x4 stt[4] = {};
#pragma unroll
        for (int t = 0; t < 4; ++t) {
            bf16x8 kf0 = *(const bf16x8*)(Kl + (16 * t + r) * 64 + ((0 + g) ^ rx) * 8);
            bf16x8 kf1 = *(const bf16x8*)(Kl + (16 * t + r) * 64 + ((4 + g) ^ rx) * 8);
            stt[t] = __builtin_amdgcn_mfma_f32_16x16x32_bf16(kf0, qf0, stt[t], 0, 0, 0);
            stt[t] = __builtin_amdgcn_mfma_f32_16x16x32_bf16(kf1, qf1, stt[t], 0, 0, 0);
        }
        // online softmax (exp2 domain), state per q=r (replicated across g groups)
        float pm = stt[0][0];
#pragma unroll
        for (int t = 0; t < 4; ++t)
#pragma unroll
            for (int e = 0; e < 4; ++e) pm = fmaxf(pm, stt[t][e]);
        pm = fmaxf(pm, __shfl_xor(pm, 16));
        pm = fmaxf(pm, __shfl_xor(pm, 32));
        float mn = fmaxf(m, pm);
        float corr = __builtin_amdgcn_exp2f(m - mn);
        float ls = 0.f;
        float p[4][4];
#pragma unroll
        for (int t = 0; t < 4; ++t)
#pragma unroll
            for (int e = 0; e < 4; ++e) { p[t][e] = __builtin_amdgcn_exp2f(stt[t][e] - mn); ls += p[t][e]; }
        ls += __shfl_xor(ls, 16);
        ls += __shfl_xor(ls, 32);
        l = l * corr + ls;
        m = mn;
        // rescale O: O rows are q = 4g+reg, state lives at q = r -> fetch corr per row
        float corrq[4];
#pragma unroll
        for (int e = 0; e < 4; ++e) corrq[e] = __shfl(corr, g * 4 + e);
#pragma unroll
        for (int dt = 0; dt < 4; ++dt)
#pragma unroll
            for (int e = 0; e < 4; ++e) o[dt][e] *= corrq[e];
        // P: C-layout -> LDS -> A-layout (per-wave private, waitcnt-ordered)
#pragma unroll
        for (int t = 0; t < 4; ++t) {
            ushort4 pk;
            pk.x = f2bf(p[t][0]); pk.y = f2bf(p[t][1]);
            pk.z = f2bf(p[t][2]); pk.w = f2bf(p[t][3]);
            *(ushort4*)(&plds[w][r * 64 + 16 * t + 4 * g]) = pk;
        }
        bf16x8 pa0 = *(const bf16x8*)(&plds[w][r * 64 + 8 * g]);
        bf16x8 pa1 = *(const bf16x8*)(&plds[w][r * 64 + 32 + 8 * g]);
#pragma unroll
        for (int dt = 0; dt < 4; ++dt) {
            bf16x8 vf0 = *(const bf16x8*)(Vl + (dt * 16 + r) * 64 + ((0 + g) ^ rx) * 8);
            bf16x8 vf1 = *(const bf16x8*)(Vl + (dt * 16 + r) * 64 + ((4 + g) ^ rx) * 8);
            o[dt] = __builtin_amdgcn_mfma_f32_16x16x32_bf16(pa0, vf0, o[dt], 0, 0, 0);
            o[dt] = __builtin_amdgcn_mfma_f32_16x16x32_bf16(pa1, vf1, o[dt], 0, 0, 0);
        }
        __syncthreads();   // vmcnt(0): next buffer staged; lgkmcnt: all reads of cur done
    }

    // store unnormalized partials
    size_t slot = (size_t)(head * 64 + qt) * NSPLIT + sp;
    float* ob = opart + slot * 4096;
#pragma unroll
    for (int dt = 0; dt < 4; ++dt)
#pragma unroll
        for (int e = 0; e < 4; ++e)
            ob[(w * 16 + g * 4 + e) * 64 + dt * 16 + r] = o[dt][e];
    float* mlb = mlpart + slot * 128;
    if (g == 0) { mlb[w * 16 + r] = m; mlb[64 + w * 16 + r] = l; }
}

// ---------------- merge split-K attention partials -> attnb (bf16) ----------------
// grid (kN/4, heads), block 256: wave w = one q row, lane = d (0..63)
__global__ __launch_bounds__(256) void mha_merge(
    const float* __restrict__ opart, const float* __restrict__ mlpart,
    u16* __restrict__ attnb) {
    int head = blockIdx.y;
    int q = blockIdx.x * 4 + (threadIdx.x >> 6);
    int d = threadIdx.x & 63;
    int qt = q >> 6, ql = q & 63;
    size_t sb = (size_t)(head * 64 + qt) * NSPLIT;
    float ms[NSPLIT], lsv[NSPLIT];
    float mstar = -3.0e38f;
#pragma unroll
    for (int s = 0; s < NSPLIT; ++s) {
        ms[s] = mlpart[(sb + s) * 128 + ql];
        lsv[s] = mlpart[(sb + s) * 128 + 64 + ql];
        mstar = fmaxf(mstar, ms[s]);
    }
    float acc = 0.f, lsum = 0.f;
#pragma unroll
    for (int s = 0; s < NSPLIT; ++s) {
        float wgt = __builtin_amdgcn_exp2f(ms[s] - mstar);
        lsum += lsv[s] * wgt;
        acc += opart[(sb + s) * 4096 + ql * 64 + d] * wgt;
    }
    attnb[(size_t)q * kC + head * 64 + d] = f2bf(acc / lsum);
}

// ---------------- final: out[4096,2] = t_bf @ out_w2^T + b2; wave per row ----------------
__global__ __launch_bounds__(256) void final_out(
    const u16* __restrict__ tbf, const float* __restrict__ w2,
    const float* __restrict__ b2, float* __restrict__ out) {
    int row = blockIdx.x * 4 + (threadIdx.x >> 6);
    int lane = threadIdx.x & 63;
    const ushort4 tv = *(const ushort4*)(tbf + (size_t)row * 256 + lane * 4);
    float t0 = bf2f(tv.x), t1 = bf2f(tv.y), t2 = bf2f(tv.z), t3 = bf2f(tv.w);
    const float4 w0 = *(const float4*)(w2 + lane * 4);
    const float4 w1 = *(const float4*)(w2 + 256 + lane * 4);
    float d0 = t0 * w0.x + t1 * w0.y + t2 * w0.z + t3 * w0.w;
    float d1 = t0 * w1.x + t1 * w1.y + t2 * w1.z + t3 * w1.w;
    for (int d = 1; d < 64; d <<= 1) { d0 += __shfl_xor(d0, d); d1 += __shfl_xor(d1, d); }
    if (lane == 0) {
        out[(size_t)row * 2 + 0] = d0 + b2[0];
        out[(size_t)row * 2 + 1] = d1 + b2[1];
    }
}

extern "C" void kernel_launch(void* const* d_in, const int* in_sizes, int n_in,
                              void* d_out, int out_size, void* d_ws, size_t ws_size,
                              hipStream_t stream) {
    (void)in_sizes; (void)n_in; (void)out_size;
    const float* x        = (const float*)d_in[0];
    const int*   ei       = (const int*)d_in[1];
    const float* in_w     = (const float*)d_in[2];
    const float* in_b     = (const float*)d_in[3];
    const float* gat_wl   = (const float*)d_in[4];
    const float* gat_wr   = (const float*)d_in[5];
    const float* gat_att  = (const float*)d_in[6];
    const float* gat_b    = (const float*)d_in[7];
    const float* mha_in_w = (const float*)d_in[8];
    const float* mha_in_b = (const float*)d_in[9];
    const float* mha_out_w= (const float*)d_in[10];
    const float* mha_out_b= (const float*)d_in[11];
    const float* ln1_g = (const float*)d_in[12];
    const float* ln1_b = (const float*)d_in[13];
    const float* ln2_g = (const float*)d_in[14];
    const float* ln2_b = (const float*)d_in[15];
    const float* ln3_g = (const float*)d_in[16];
    const float* ln3_b = (const float*)d_in[17];
    const float* ffn_w1 = (const float*)d_in[18];
    const float* ffn_b1 = (const float*)d_in[19];
    const float* ffn_w2 = (const float*)d_in[20];
    const float* ffn_b2 = (const float*)d_in[21];
    const float* out_w1 = (const float*)d_in[22];
    const float* out_b1 = (const float*)d_in[23];
    const float* out_w2 = (const float*)d_in[24];
    const float* out_b2 = (const float*)d_in[25];
    float* out = (float*)d_out;

    char* ws = (char*)d_ws;
    size_t off = 0;
    auto alloc = [&](size_t bytes) -> void* {
        void* p = (void*)(ws + off);
        off += (bytes + 255) & ~(size_t)255;
        return p;
    };
    float* h     = (float*)alloc((size_t)kN * kC * 4);
    u16*   hbf   = (u16*)  alloc((size_t)kN * kC * 2);
    float* xlb   = (float*)alloc((size_t)kN * 1024 * 4);   // slot reused: xlbf+xrbf / Qb+Kb+VTb
    float* xrb   = (float*)alloc((size_t)kN * 1024 * 4);   // slot reused: opart
    float* qkv   = (float*)alloc((size_t)kN * 768 * 4);    // slot reused: qkvb (bf16)
    float* locb  = (float*)alloc((size_t)kN * kC * 4);
    u16*   attnb = (u16*)  alloc((size_t)kN * kC * 2);
    u16*   midb  = (u16*)  alloc((size_t)kN * 512 * 2);
    u16*   tbf   = (u16*)  alloc((size_t)kN * kC * 2);
    u16*   xbf   = (u16*)  alloc((size_t)kN * kIn * 2);
    u16*   wbf   = (u16*)  alloc((size_t)3342336 * 2);
    int*   coff  = (int*)  alloc((size_t)4097 * 4);
    int*   ccur  = (int*)  alloc((size_t)4096 * 4);
    int*   csrc  = (int*)  alloc((size_t)kET * 4);
    if (ws_size < off) return;  // not enough scratch: bail loudly (output stays poisoned)

    // GAT transforms in bf16, carved from the xlb slot (8 MB + 8 MB = 16 MB slot).
    u16* xlbf = (u16*)xlb;                      // [4096][1024] bf16
    u16* xrbf = xlbf + (size_t)kN * 1024;       // [4096][1024] bf16
    // MHA attention operands: alias the same slot (xlbf/xrbf dead after gat_agg/ln1).
    u16* Qb  = (u16*)xlb;                       // [4][4096][64]
    u16* Kb  = Qb + (size_t)4 * kN * 64;        // [4][4096][64]
    u16* VTb = Kb + (size_t)4 * kN * 64;        // [4][64][4096]
    // qkv in bf16, carved from the qkv slot.
    u16* qkvb = (u16*)qkv;                      // [4096][768] bf16
    // split-K partials: opart = xrb slot (1024 slots x 4096 f32 = 16 MB exact);
    // mlpart = locb slot (dead between ln1 and the mout GEMM).
    float* opart  = xrb;
    float* mlpart = locb;

    // bf16 weight buffer offsets (elements)
    const size_t OFF_INW  = 0;
    const size_t OFF_GWL  = 131072;
    const size_t OFF_GWR  = 917504;
    const size_t OFF_MIN  = 1703936;
    const size_t OFF_MOUT = 2293760;
    const size_t OFF_F1   = 2490368;
    const size_t OFF_F2   = 2883584;
    const size_t OFF_O1   = 3276800;

    auto cast = [&](const float* s, u16* d, int n) {
        int n4 = n >> 2;
        cast_f2b<<<dim3((n4 + 255) / 256), dim3(256), 0, stream>>>(s, d, n4);
    };
    cast(x, xbf, kN * kIn);
    cast(in_w, wbf + OFF_INW, kC * kIn);
    cast(gat_wl, wbf + OFF_GWL, kL * 1024 * kC);
    cast(gat_wr, wbf + OFF_GWR, kL * 1024 * kC);
    cast(mha_in_w, wbf + OFF_MIN, kL * 768 * kC);
    cast(mha_out_w, wbf + OFF_MOUT, kL * kC * kC);
    cast(ffn_w1, wbf + OFF_F1, kL * 512 * kC);
    cast(ffn_w2, wbf + OFF_F2, kL * kC * 512);
    cast(out_w1, wbf + OFF_O1, kC * kC);

    // CSR build (once per launch; same graph for all layers)
    hipMemsetAsync(ccur, 0, 4096 * 4, stream);
    csr_count<<<dim3((kET + 255) / 256), dim3(256), 0, stream>>>(ei, ccur);
    csr_scan<<<dim3(1), dim3(1024), 0, stream>>>(ccur, coff);
    csr_scatter<<<dim3((kET + 255) / 256), dim3(256), 0, stream>>>(ei, ccur, csrc);

    // input projection: h = x @ in_w^T + in_b  (fp32 + bf16 outputs)
    gemm_bt<0, 1, 1><<<dim3(kC / 64, kN / 64), dim3(256), 0, stream>>>(
        xbf, wbf + OFF_INW, in_b, h, hbf, kN, kC, kIn);

    for (int l = 0; l < kL; ++l) {
        // GATv2 transforms (bf16 outputs)
        gemm_bt<0, 0, 1><<<dim3(1024 / 64, kN / 64), dim3(256), 0, stream>>>(
            hbf, wbf + OFF_GWL + (size_t)l * 1024 * kC, nullptr, nullptr, xlbf, kN, 1024, kC);
        gemm_bt<0, 0, 1><<<dim3(1024 / 64, kN / 64), dim3(256), 0, stream>>>(
            hbf, wbf + OFF_GWR + (size_t)l * 1024 * kC, nullptr, nullptr, xrbf, kN, 1024, kC);
        gat_agg<<<dim3(kN), dim3(256), 0, stream>>>(
            xlbf, xrbf, gat_att + (size_t)l * 1024, gat_b + (size_t)l * kC, coff, csrc, locb);
        ln_res<<<dim3(kN / 4), dim3(256), 0, stream>>>(
            h, locb, ln1_g + (size_t)l * kC, ln1_b + (size_t)l * kC, h, hbf);

        // MHA
        gemm_bt<0, 0, 1><<<dim3(768 / 64, kN / 64), dim3(256), 0, stream>>>(
            hbf, wbf + OFF_MIN + (size_t)l * 768 * kC, mha_in_b + (size_t)l * 768, nullptr, qkvb, kN, 768, kC);
        qkv_repack<<<dim3(kN / 64, 4), dim3(256), 0, stream>>>(qkvb, Qb, Kb, VTb);
        mha_mfma2<<<dim3(kN / 64, 4, NSPLIT), dim3(256), 0, stream>>>(Qb, Kb, VTb, opart, mlpart);
        mha_merge<<<dim3(kN / 4, 4), dim3(256), 0, stream>>>(opart, mlpart, attnb);
        gemm_bt<0, 1, 0><<<dim3(kC / 64, kN / 64), dim3(256), 0, stream>>>(
            attnb, wbf + OFF_MOUT + (size_t)l * kC * kC, mha_out_b + (size_t)l * kC, locb, nullptr, kN, kC, kC);
        ln_res<<<dim3(kN / 4), dim3(256), 0, stream>>>(
            h, locb, ln2_g + (size_t)l * kC, ln2_b + (size_t)l * kC, h, hbf);

        // FFN
        gemm_bt<1, 0, 1><<<dim3(512 / 64, kN / 64), dim3(256), 0, stream>>>(
            hbf, wbf + OFF_F1 + (size_t)l * 512 * kC, ffn_b1 + (size_t)l * 512, nullptr, midb, kN, 512, kC);
        gemm_bt<0, 1, 0><<<dim3(kC / 64, kN / 64), dim3(256), 0, stream>>>(
            midb, wbf + OFF_F2 + (size_t)l * kC * 512, ffn_b2 + (size_t)l * kC, locb, nullptr, kN, kC, 512);
        ln_res<<<dim3(kN / 4), dim3(256), 0, stream>>>(
            h, locb, ln3_g + (size_t)l * kC, ln3_b + (size_t)l * kC, h, hbf);
    }

    // output head
    gemm_bt<1, 0, 1><<<dim3(kC / 64, kN / 64), dim3(256), 0, stream>>>(
        hbf, wbf + OFF_O1, out_b1, nullptr, tbf, kN, kC, kC);
    final_out<<<dim3(kN / 4), dim3(256), 0, stream>>>(tbf, out_w2, out_b2, out);
}

// Round 8
// 619.801 us; speedup vs baseline: 7.7740x; 1.1255x over previous
//
#include <hip/hip_runtime.h>
#include <cstdint>
#include <cstddef>

typedef unsigned short u16;
typedef __bf16 bf16x8 __attribute__((ext_vector_type(8)));
typedef float f32x4 __attribute__((ext_vector_type(4)));

constexpr int kN  = 4096;
constexpr int kE  = 131072;
constexpr int kET = kE + kN;   // with self loops
constexpr int kIn = 512;
constexpr int kC  = 256;
constexpr int kL  = 3;

constexpr int NSPLIT = 4;
constexpr int KSPAN  = kN / NSPLIT;  // 1024 keys per split
constexpr int NSTEP  = KSPAN / 64;   // 16 steps of 64 keys

__device__ __forceinline__ u16 f2bf(float f) {
    unsigned u = __builtin_bit_cast(unsigned, f);
    u += 0x7fffu + ((u >> 16) & 1u);
    return (u16)(u >> 16);
}
__device__ __forceinline__ float bf2f(u16 s) {
    unsigned u = ((unsigned)s) << 16;
    return __builtin_bit_cast(float, u);
}
__device__ __forceinline__ float gelu_erf(float x) {
    return 0.5f * x * (1.f + erff(x * 0.70710678118654752f));
}
// async global->LDS, 16B per lane; ldst must be wave-uniform base (HW adds lane*16)
__device__ __forceinline__ void gload_lds16(const u16* gsrc, u16* ldst) {
    __builtin_amdgcn_global_load_lds(
        (const __attribute__((address_space(1))) unsigned int*)gsrc,
        (__attribute__((address_space(3))) unsigned int*)ldst, 16, 0, 0);
}
// sum over each row of 16 lanes via DPP row_ror adds (full-rate VALU, no LDS pipe)
__device__ __forceinline__ float dpp_ror_add16(float x) {
    int t;
    t = __builtin_amdgcn_update_dpp(0, __builtin_bit_cast(int, x), 0x121, 0xf, 0xf, true);
    x += __builtin_bit_cast(float, t);
    t = __builtin_amdgcn_update_dpp(0, __builtin_bit_cast(int, x), 0x122, 0xf, 0xf, true);
    x += __builtin_bit_cast(float, t);
    t = __builtin_amdgcn_update_dpp(0, __builtin_bit_cast(int, x), 0x124, 0xf, 0xf, true);
    x += __builtin_bit_cast(float, t);
    t = __builtin_amdgcn_update_dpp(0, __builtin_bit_cast(int, x), 0x128, 0xf, 0xf, true);
    x += __builtin_bit_cast(float, t);
    return x;
}
// unpack 8 bf16 (uint4) -> 8 f32
__device__ __forceinline__ void unpack8(uint4 u, float* x) {
    x[0] = __builtin_bit_cast(float, u.x << 16);
    x[1] = __builtin_bit_cast(float, u.x & 0xffff0000u);
    x[2] = __builtin_bit_cast(float, u.y << 16);
    x[3] = __builtin_bit_cast(float, u.y & 0xffff0000u);
    x[4] = __builtin_bit_cast(float, u.z << 16);
    x[5] = __builtin_bit_cast(float, u.z & 0xffff0000u);
    x[6] = __builtin_bit_cast(float, u.w << 16);
    x[7] = __builtin_bit_cast(float, u.w & 0xffff0000u);
}

// ---------------- cast fp32 -> bf16 (vector4) ----------------
__global__ void cast_f2b(const float* __restrict__ src, u16* __restrict__ dst, int n4) {
    int i = blockIdx.x * blockDim.x + threadIdx.x;
    if (i >= n4) return;
    float4 v = ((const float4*)src)[i];
    ushort4 o;
    o.x = f2bf(v.x); o.y = f2bf(v.y); o.z = f2bf(v.z); o.w = f2bf(v.w);
    ((ushort4*)dst)[i] = o;
}

// ---------------- CSR build (by dst) ----------------
__global__ void csr_count(const int* __restrict__ ei, int* __restrict__ cnt) {
    int e = blockIdx.x * 256 + threadIdx.x;
    if (e >= kET) return;
    int d = (e < kE) ? ei[kE + e] : (e - kE);
    atomicAdd(cnt + d, 1);
}

__global__ __launch_bounds__(1024) void csr_scan(int* __restrict__ cnt_cur, int* __restrict__ off) {
    __shared__ int lds[1024];
    int t = threadIdx.x;
    int c[4], s = 0;
#pragma unroll
    for (int j = 0; j < 4; ++j) { c[j] = cnt_cur[t * 4 + j]; s += c[j]; }
    lds[t] = s;
    __syncthreads();
    for (int d = 1; d < 1024; d <<= 1) {
        int v = (t >= d) ? lds[t - d] : 0;
        __syncthreads();
        lds[t] += v;
        __syncthreads();
    }
    int excl = lds[t] - s;
#pragma unroll
    for (int j = 0; j < 4; ++j) { off[t * 4 + j] = excl; cnt_cur[t * 4 + j] = excl; excl += c[j]; }
    if (t == 1023) off[4096] = excl;
}

__global__ void csr_scatter(const int* __restrict__ ei, int* __restrict__ cur, int* __restrict__ csrc) {
    int e = blockIdx.x * 256 + threadIdx.x;
    if (e >= kET) return;
    int s, d;
    if (e < kE) { s = ei[e]; d = ei[kE + e]; } else { s = d = e - kE; }
    int pos = atomicAdd(cur + d, 1);
    csrc[pos] = s;
}

// ---------------- bf16 MFMA GEMM: C[M,N] = act(A[M,K] @ W[N,K]^T + bias) ----------------
// block 256 = 4 waves; block tile 64x64; wave tile 32x32 (2x2 of 16x16x32 MFMA)
template <int ACT, int WF32, int WBF16>
__global__ __launch_bounds__(256) void gemm_bt(
    const u16* __restrict__ A, const u16* __restrict__ W,
    const float* __restrict__ bias, float* __restrict__ Cf,
    u16* __restrict__ Cb, int M, int N, int K) {
    int wave = threadIdx.x >> 6, lane = threadIdx.x & 63;
    int bm = blockIdx.y * 64 + (wave >> 1) * 32;
    int bn = blockIdx.x * 64 + (wave & 1) * 32;
    int lr = lane & 15, lk = (lane >> 4) * 8;
    const u16* Ap = A + (size_t)(bm + lr) * K + lk;
    const u16* Wp = W + (size_t)(bn + lr) * K + lk;
    f32x4 acc[2][2] = {};
    for (int k0 = 0; k0 < K; k0 += 32) {
        bf16x8 a0 = *(const bf16x8*)(Ap + k0);
        bf16x8 a1 = *(const bf16x8*)(Ap + (size_t)16 * K + k0);
        bf16x8 b0 = *(const bf16x8*)(Wp + k0);
        bf16x8 b1 = *(const bf16x8*)(Wp + (size_t)16 * K + k0);
        acc[0][0] = __builtin_amdgcn_mfma_f32_16x16x32_bf16(a0, b0, acc[0][0], 0, 0, 0);
        acc[0][1] = __builtin_amdgcn_mfma_f32_16x16x32_bf16(a0, b1, acc[0][1], 0, 0, 0);
        acc[1][0] = __builtin_amdgcn_mfma_f32_16x16x32_bf16(a1, b0, acc[1][0], 0, 0, 0);
        acc[1][1] = __builtin_amdgcn_mfma_f32_16x16x32_bf16(a1, b1, acc[1][1], 0, 0, 0);
    }
    int r0 = bm + (lane >> 4) * 4;
    int c0 = bn + (lane & 15);
#pragma unroll
    for (int i = 0; i < 2; ++i)
#pragma unroll
        for (int j = 0; j < 2; ++j)
#pragma unroll
            for (int r = 0; r < 4; ++r) {
                int row = r0 + i * 16 + r, col = c0 + j * 16;
                float v = acc[i][j][r];
                if (bias) v += bias[col];
                if (ACT == 1) v = gelu_erf(v);
                if (WF32) Cf[(size_t)row * N + col] = v;
                if (WBF16) Cb[(size_t)row * N + col] = f2bf(v);
            }
}

// ---------------- LayerNorm(h + add) -> h (fp32) and h_bf (bf16); wave per row ----------------
__global__ __launch_bounds__(256) void ln_res(
    const float* hin, const float* add,
    const float* __restrict__ g, const float* __restrict__ b,
    float* hout, u16* __restrict__ hbf) {
    int row = blockIdx.x * 4 + (threadIdx.x >> 6);
    int lane = threadIdx.x & 63;
    const float4 x4 = *(const float4*)(hin + (size_t)row * kC + lane * 4);
    const float4 a4 = *(const float4*)(add + (size_t)row * kC + lane * 4);
    float v[4] = {x4.x + a4.x, x4.y + a4.y, x4.z + a4.z, x4.w + a4.w};
    float s = v[0] + v[1] + v[2] + v[3];
    for (int d = 1; d < 64; d <<= 1) s += __shfl_xor(s, d);
    float mu = s * (1.f / kC);
    float q = 0.f;
#pragma unroll
    for (int j = 0; j < 4; ++j) { float d = v[j] - mu; q += d * d; }
    for (int d = 1; d < 64; d <<= 1) q += __shfl_xor(q, d);
    float rstd = rsqrtf(q * (1.f / kC) + 1e-5f);
    const float4 g4 = *(const float4*)(g + lane * 4);
    const float4 b4 = *(const float4*)(b + lane * 4);
    float y0 = (v[0] - mu) * rstd * g4.x + b4.x;
    float y1 = (v[1] - mu) * rstd * g4.y + b4.y;
    float y2 = (v[2] - mu) * rstd * g4.z + b4.z;
    float y3 = (v[3] - mu) * rstd * g4.w + b4.w;
    *(float4*)(hout + (size_t)row * kC + lane * 4) = make_float4(y0, y1, y2, y3);
    ushort4 o; o.x = f2bf(y0); o.y = f2bf(y1); o.z = f2bf(y2); o.w = f2bf(y3);
    *(ushort4*)(hbf + (size_t)row * kC + lane * 4) = o;
}

// ---------------- GATv2: per-node online softmax aggregation ----------------
// Block = node, wave = head. Within a wave: 4 quarters (16 lanes) each process
// their own edge in lockstep (16 channels/lane), so 4 edges advance per wave-inst.
// Score reduce = 4 DPP row_ror adds (pure VALU). Per-quarter online-softmax state,
// exact 4-way LSE merge at the end. 1-edge software prefetch per quarter.
__global__ __launch_bounds__(256) void gat_agg(
    const u16* __restrict__ xl, const u16* __restrict__ xr,
    const float* __restrict__ att, const float* __restrict__ gb,
    const int* __restrict__ off, const int* __restrict__ srcs,
    float* __restrict__ outloc) {
    int n = blockIdx.x;
    int w = threadIdx.x >> 6, lane = threadIdx.x & 63;
    int q = lane >> 4, t = lane & 15;
    int cb = w * 256 + t * 16;   // channel slice [cb, cb+16) of 1024

    uint4 xru0 = *(const uint4*)(xr + (size_t)n * 1024 + cb);
    uint4 xru1 = *(const uint4*)(xr + (size_t)n * 1024 + cb + 8);
    float xrv[16];
    unpack8(xru0, xrv); unpack8(xru1, xrv + 8);
    float attv[16], att2[16];
#pragma unroll
    for (int j = 0; j < 16; j += 4) {
        float4 a4 = *(const float4*)(att + cb + j);
        attv[j] = a4.x; attv[j + 1] = a4.y; attv[j + 2] = a4.z; attv[j + 3] = a4.w;
    }
#pragma unroll
    for (int j = 0; j < 16; ++j) att2[j] = 0.2f * attv[j];

    int i0 = off[n], i1 = off[n + 1];
    float m = -1e30f, ls = 0.f;
    float acc[16] = {};
    int i = i0 + q;
    uint4 p0, p1;
    if (i < i1) {
        int s = srcs[i];
        p0 = *(const uint4*)(xl + (size_t)s * 1024 + cb);
        p1 = *(const uint4*)(xl + (size_t)s * 1024 + cb + 8);
    }
    while (i < i1) {
        uint4 c0 = p0, c1 = p1;
        int inext = i + 4;
        if (inext < i1) {
            int s2 = srcs[inext];
            p0 = *(const uint4*)(xl + (size_t)s2 * 1024 + cb);
            p1 = *(const uint4*)(xl + (size_t)s2 * 1024 + cb + 8);
        }
        float x[16];
        unpack8(c0, x); unpack8(c1, x + 8);
        float p = 0.f;
#pragma unroll
        for (int j = 0; j < 16; ++j) {
            float e = x[j] + xrv[j];
            p = fmaf(attv[j], fmaxf(e, 0.f), p);
            p = fmaf(att2[j], fminf(e, 0.f), p);
        }
        p = dpp_ror_add16(p);   // all 16 lanes of the quarter now hold the score
        if (p > m) {            // quarter-uniform; divergence between quarters is rare
            float c = __expf(m - p);
            ls = ls * c + 1.f;
#pragma unroll
            for (int j = 0; j < 16; ++j) acc[j] = acc[j] * c + x[j];
            m = p;
        } else {
            float pw = __expf(p - m);
            ls += pw;
#pragma unroll
            for (int j = 0; j < 16; ++j) acc[j] = fmaf(pw, x[j], acc[j]);
        }
        i = inext;
    }
    // exact LSE merge of the 4 quarter states (quarter index = lane bits 4..5)
    float mm = fmaxf(m, __shfl_xor(m, 16));
    mm = fmaxf(mm, __shfl_xor(mm, 32));
    float c = __expf(m - mm);   // 0 for empty quarters (m = -1e30)
    ls *= c;
    ls += __shfl_xor(ls, 16);
    ls += __shfl_xor(ls, 32);
    float inv;
#pragma unroll
    for (int j = 0; j < 16; ++j) {
        float a = acc[j] * c;
        a += __shfl_xor(a, 16);
        a += __shfl_xor(a, 32);
        acc[j] = a;
    }
    inv = 1.f / ls;
    __shared__ float red[4][256];
    if (q == 0) {
#pragma unroll
        for (int j = 0; j < 16; ++j) red[w][t * 16 + j] = acc[j] * inv;
    }
    __syncthreads();
    int cc = threadIdx.x;
    float vsum = 0.25f * (red[0][cc] + red[1][cc] + red[2][cc] + red[3][cc]) + gb[cc];
    outloc[(size_t)n * kC + cc] = vsum;
}

// ---------------- qkv repack: qkvb bf16 [4096][768] -> Qb/Kb [4][4096][64], VTb [4][64][4096]
// Q scaled by 1/sqrt(64) * log2(e) so attention can use exp2 directly.
__global__ __launch_bounds__(256) void qkv_repack(
    const u16* __restrict__ qkvb, u16* __restrict__ Qb, u16* __restrict__ Kb,
    u16* __restrict__ VTb) {
    int h = blockIdx.y;
    int n0 = blockIdx.x * 64;
    int t = threadIdx.x;
    int nr = t >> 2, cb = (t & 3) * 16;
    const u16* src = qkvb + (size_t)(n0 + nr) * 768 + h * 64 + cb;
    u16* qd = Qb + ((size_t)h * kN + n0 + nr) * 64 + cb;
    u16* kd = Kb + ((size_t)h * kN + n0 + nr) * 64 + cb;
    __shared__ u16 lds[64][72];
    constexpr float QS = 0.125f * 1.4426950408889634f;  // 1/sqrt(DH) * log2(e)
#pragma unroll
    for (int j = 0; j < 16; j += 4) {
        ushort4 q4 = *(const ushort4*)(src + j);
        ushort4 k4 = *(const ushort4*)(src + 256 + j);
        ushort4 v4 = *(const ushort4*)(src + 512 + j);
        ushort4 qo;
        qo.x = f2bf(bf2f(q4.x) * QS); qo.y = f2bf(bf2f(q4.y) * QS);
        qo.z = f2bf(bf2f(q4.z) * QS); qo.w = f2bf(bf2f(q4.w) * QS);
        *(ushort4*)(qd + j) = qo;
        *(ushort4*)(kd + j) = k4;
        *(ushort4*)(&lds[nr][cb + j]) = v4;
    }
    __syncthreads();
    int d = t >> 2, nb = (t & 3) * 16;
    u16* vd = VTb + ((size_t)h * 64 + d) * kN + n0 + nb;
#pragma unroll
    for (int j = 0; j < 16; j += 4) {
        ushort4 vo;
        vo.x = lds[nb + j + 0][d];
        vo.y = lds[nb + j + 1][d];
        vo.z = lds[nb + j + 2][d];
        vo.w = lds[nb + j + 3][d];
        *(ushort4*)(vd + j) = vo;
    }
}

// ---------------- MFMA flash attention, LDS-shared K/V, split-K ----------------
// Block = 4 waves, 64 q rows (16/wave). Grid (kN/64, heads, NSPLIT).
// K and VT 64x64 tiles double-buffered in LDS via global_load_lds with XOR-swizzled
// source (chunk ^= row&7); plds uses the SAME chunk swizzle (c ^= r&7) so the
// P C->A roundtrip is bank-conflict-free (was 16-way on writes, 8-way on reads).
// Writes unnormalized partial O + (m,l) per split; mha_merge recombines (LSE merge).
__global__ __launch_bounds__(256, 4) void mha_mfma2(
    const u16* __restrict__ Qb, const u16* __restrict__ Kb,
    const u16* __restrict__ VTb, float* __restrict__ opart, float* __restrict__ mlpart) {
    int qt = blockIdx.x, head = blockIdx.y, sp = blockIdx.z;
    int tid = threadIdx.x;
    int w = tid >> 6, lane = tid & 63;
    int g = lane >> 4, r = lane & 15;
    int q0 = qt * 64;
    const u16* Qh = Qb + ((size_t)head * kN + q0 + w * 16) * 64;
    const u16* Kh = Kb + (size_t)head * kN * 64;
    const u16* VTh = VTb + (size_t)head * 64 * kN;
    __shared__ u16 Kt[2][64 * 64];
    __shared__ u16 Vt[2][64 * 64];
    __shared__ u16 plds[4][16 * 64];
    // staging geometry: instr i in {0,1}; lane covers (row = i*32 + w*8 + (lane>>3), chunk = lane&7)
    // of the 64x64 tile; global chunk is XOR-swizzled by row&7 (= (lane>>3)&7).
    int srow = w * 8 + (lane >> 3);
    int schunk = ((lane & 7) ^ ((lane >> 3) & 7)) * 8;   // element offset within row
    int kbase = sp * KSPAN;

    bf16x8 qf0 = *(const bf16x8*)(Qh + r * 64 + g * 8);
    bf16x8 qf1 = *(const bf16x8*)(Qh + r * 64 + 32 + g * 8);

    auto stage = [&](int buf, int k0) {
#pragma unroll
        for (int i = 0; i < 2; ++i) {
            int row = i * 32 + srow;
            gload_lds16(Kh + (size_t)(k0 + row) * 64 + schunk, &Kt[buf][(i * 32 + w * 8) * 64]);
            gload_lds16(VTh + (size_t)row * kN + k0 + schunk, &Vt[buf][(i * 32 + w * 8) * 64]);
        }
    };

    f32x4 o[4] = {};
    float m = -3.0e38f, l = 0.f;

    stage(0, kbase);
    __syncthreads();   // vmcnt(0) drain + barrier: buffer 0 ready

    int rx = r & 7;
    for (int st = 0; st < NSTEP; ++st) {
        int cur = st & 1;
        if (st + 1 < NSTEP) stage(cur ^ 1, kbase + (st + 1) * 64);
        const u16* Kl = &Kt[cur][0];
        const u16* Vl = &Vt[cur][0];
        // S^T tiles: rows = keys (16t + 4g + reg), cols = q (r)
        f32x4 stt[4] = {};
#pragma unroll
        for (int t = 0; t < 4; ++t) {
            bf16x8 kf0 = *(const bf16x8*)(Kl + (16 * t + r) * 64 + ((0 + g) ^ rx) * 8);
            bf16x8 kf1 = *(const bf16x8*)(Kl + (16 * t + r) * 64 + ((4 + g) ^ rx) * 8);
            stt[t] = __builtin_amdgcn_mfma_f32_16x16x32_bf16(kf0, qf0, stt[t], 0, 0, 0);
            stt[t] = __builtin_amdgcn_mfma_f32_16x16x32_bf16(kf1, qf1, stt[t], 0, 0, 0);
        }
        // online softmax (exp2 domain), state per q=r (replicated across g groups)
        float pm = stt[0][0];
#pragma unroll
        for (int t = 0; t < 4; ++t)
#pragma unroll
            for (int e = 0; e < 4; ++e) pm = fmaxf(pm, stt[t][e]);
        pm = fmaxf(pm, __shfl_xor(pm, 16));
        pm = fmaxf(pm, __shfl_xor(pm, 32));
        float mn = fmaxf(m, pm);
        float corr = __builtin_amdgcn_exp2f(m - mn);
        float ls = 0.f;
        float p[4][4];
#pragma unroll
        for (int t = 0; t < 4; ++t)
#pragma unroll
            for (int e = 0; e < 4; ++e) { p[t][e] = __builtin_amdgcn_exp2f(stt[t][e] - mn); ls += p[t][e]; }
        ls += __shfl_xor(ls, 16);
        ls += __shfl_xor(ls, 32);
        l = l * corr + ls;
        m = mn;
        // rescale O: O rows are q = 4g+reg, state lives at q = r -> fetch corr per row
        float corrq[4];
#pragma unroll
        for (int e = 0; e < 4; ++e) corrq[e] = __shfl(corr, g * 4 + e);
#pragma unroll
        for (int dt = 0; dt < 4; ++dt)
#pragma unroll
            for (int e = 0; e < 4; ++e) o[dt][e] *= corrq[e];
        // P: C-layout -> LDS -> A-layout. plds chunk-swizzled by q-row (c ^= r&7):
        // write: keys 16t+4g+0..3 = logical chunk 2t+(g>>1), half g&1
        // read:  logical chunks g and 4+g
#pragma unroll
        for (int t = 0; t < 4; ++t) {
            ushort4 pk;
            pk.x = f2bf(p[t][0]); pk.y = f2bf(p[t][1]);
            pk.z = f2bf(p[t][2]); pk.w = f2bf(p[t][3]);
            int lc = (2 * t + (g >> 1)) ^ rx;
            *(ushort4*)(&plds[w][r * 64 + lc * 8 + (g & 1) * 4]) = pk;
        }
        bf16x8 pa0 = *(const bf16x8*)(&plds[w][r * 64 + (g ^ rx) * 8]);
        bf16x8 pa1 = *(const bf16x8*)(&plds[w][r * 64 + ((4 + g) ^ rx) * 8]);
#pragma unroll
        for (int dt = 0; dt < 4; ++dt) {
            bf16x8 vf0 = *(const bf16x8*)(Vl + (dt * 16 + r) * 64 + ((0 + g) ^ rx) * 8);
            bf16x8 vf1 = *(const bf16x8*)(Vl + (dt * 16 + r) * 64 + ((4 + g) ^ rx) * 8);
            o[dt] = __builtin_amdgcn_mfma_f32_16x16x32_bf16(pa0, vf0, o[dt], 0, 0, 0);
            o[dt] = __builtin_amdgcn_mfma_f32_16x16x32_bf16(pa1, vf1, o[dt], 0, 0, 0);
        }
        __syncthreads();   // vmcnt(0): next buffer staged; lgkmcnt: all reads of cur done
    }

    // store unnormalized partials
    size_t slot = (size_t)(head * 64 + qt) * NSPLIT + sp;
    float* ob = opart + slot * 4096;
#pragma unroll
    for (int dt = 0; dt < 4; ++dt)
#pragma unroll
        for (int e = 0; e < 4; ++e)
            ob[(w * 16 + g * 4 + e) * 64 + dt * 16 + r] = o[dt][e];
    float* mlb = mlpart + slot * 128;
    if (g == 0) { mlb[w * 16 + r] = m; mlb[64 + w * 16 + r] = l; }
}

// ---------------- merge split-K attention partials -> attnb (bf16) ----------------
// grid (kN/4, heads), block 256: wave w = one q row, lane = d (0..63)
__global__ __launch_bounds__(256) void mha_merge(
    const float* __restrict__ opart, const float* __restrict__ mlpart,
    u16* __restrict__ attnb) {
    int head = blockIdx.y;
    int q = blockIdx.x * 4 + (threadIdx.x >> 6);
    int d = threadIdx.x & 63;
    int qt = q >> 6, ql = q & 63;
    size_t sb = (size_t)(head * 64 + qt) * NSPLIT;
    float ms[NSPLIT], lsv[NSPLIT];
    float mstar = -3.0e38f;
#pragma unroll
    for (int s = 0; s < NSPLIT; ++s) {
        ms[s] = mlpart[(sb + s) * 128 + ql];
        lsv[s] = mlpart[(sb + s) * 128 + 64 + ql];
        mstar = fmaxf(mstar, ms[s]);
    }
    float acc = 0.f, lsum = 0.f;
#pragma unroll
    for (int s = 0; s < NSPLIT; ++s) {
        float wgt = __builtin_amdgcn_exp2f(ms[s] - mstar);
        lsum += lsv[s] * wgt;
        acc += opart[(sb + s) * 4096 + ql * 64 + d] * wgt;
    }
    attnb[(size_t)q * kC + head * 64 + d] = f2bf(acc / lsum);
}

// ---------------- final: out[4096,2] = t_bf @ out_w2^T + b2; wave per row ----------------
__global__ __launch_bounds__(256) void final_out(
    const u16* __restrict__ tbf, const float* __restrict__ w2,
    const float* __restrict__ b2, float* __restrict__ out) {
    int row = blockIdx.x * 4 + (threadIdx.x >> 6);
    int lane = threadIdx.x & 63;
    const ushort4 tv = *(const ushort4*)(tbf + (size_t)row * 256 + lane * 4);
    float t0 = bf2f(tv.x), t1 = bf2f(tv.y), t2 = bf2f(tv.z), t3 = bf2f(tv.w);
    const float4 w0 = *(const float4*)(w2 + lane * 4);
    const float4 w1 = *(const float4*)(w2 + 256 + lane * 4);
    float d0 = t0 * w0.x + t1 * w0.y + t2 * w0.z + t3 * w0.w;
    float d1 = t0 * w1.x + t1 * w1.y + t2 * w1.z + t3 * w1.w;
    for (int d = 1; d < 64; d <<= 1) { d0 += __shfl_xor(d0, d); d1 += __shfl_xor(d1, d); }
    if (lane == 0) {
        out[(size_t)row * 2 + 0] = d0 + b2[0];
        out[(size_t)row * 2 + 1] = d1 + b2[1];
    }
}

extern "C" void kernel_launch(void* const* d_in, const int* in_sizes, int n_in,
                              void* d_out, int out_size, void* d_ws, size_t ws_size,
                              hipStream_t stream) {
    (void)in_sizes; (void)n_in; (void)out_size;
    const float* x        = (const float*)d_in[0];
    const int*   ei       = (const int*)d_in[1];
    const float* in_w     = (const float*)d_in[2];
    const float* in_b     = (const float*)d_in[3];
    const float* gat_wl   = (const float*)d_in[4];
    const float* gat_wr   = (const float*)d_in[5];
    const float* gat_att  = (const float*)d_in[6];
    const float* gat_b    = (const float*)d_in[7];
    const float* mha_in_w = (const float*)d_in[8];
    const float* mha_in_b = (const float*)d_in[9];
    const float* mha_out_w= (const float*)d_in[10];
    const float* mha_out_b= (const float*)d_in[11];
    const float* ln1_g = (const float*)d_in[12];
    const float* ln1_b = (const float*)d_in[13];
    const float* ln2_g = (const float*)d_in[14];
    const float* ln2_b = (const float*)d_in[15];
    const float* ln3_g = (const float*)d_in[16];
    const float* ln3_b = (const float*)d_in[17];
    const float* ffn_w1 = (const float*)d_in[18];
    const float* ffn_b1 = (const float*)d_in[19];
    const float* ffn_w2 = (const float*)d_in[20];
    const float* ffn_b2 = (const float*)d_in[21];
    const float* out_w1 = (const float*)d_in[22];
    const float* out_b1 = (const float*)d_in[23];
    const float* out_w2 = (const float*)d_in[24];
    const float* out_b2 = (const float*)d_in[25];
    float* out = (float*)d_out;

    char* ws = (char*)d_ws;
    size_t off = 0;
    auto alloc = [&](size_t bytes) -> void* {
        void* p = (void*)(ws + off);
        off += (bytes + 255) & ~(size_t)255;
        return p;
    };
    float* h     = (float*)alloc((size_t)kN * kC * 4);
    u16*   hbf   = (u16*)  alloc((size_t)kN * kC * 2);
    float* xlb   = (float*)alloc((size_t)kN * 1024 * 4);   // slot reused: xlbf+xrbf / Qb+Kb+VTb
    float* xrb   = (float*)alloc((size_t)kN * 1024 * 4);   // slot reused: opart
    float* qkv   = (float*)alloc((size_t)kN * 768 * 4);    // slot reused: qkvb (bf16)
    float* locb  = (float*)alloc((size_t)kN * kC * 4);
    u16*   attnb = (u16*)  alloc((size_t)kN * kC * 2);
    u16*   midb  = (u16*)  alloc((size_t)kN * 512 * 2);
    u16*   tbf   = (u16*)  alloc((size_t)kN * kC * 2);
    u16*   xbf   = (u16*)  alloc((size_t)kN * kIn * 2);
    u16*   wbf   = (u16*)  alloc((size_t)3342336 * 2);
    int*   coff  = (int*)  alloc((size_t)4097 * 4);
    int*   ccur  = (int*)  alloc((size_t)4096 * 4);
    int*   csrc  = (int*)  alloc((size_t)kET * 4);
    if (ws_size < off) return;  // not enough scratch: bail loudly (output stays poisoned)

    // GAT transforms in bf16, carved from the xlb slot (8 MB + 8 MB = 16 MB slot).
    u16* xlbf = (u16*)xlb;                      // [4096][1024] bf16
    u16* xrbf = xlbf + (size_t)kN * 1024;       // [4096][1024] bf16
    // MHA attention operands: alias the same slot (xlbf/xrbf dead after gat_agg/ln1).
    u16* Qb  = (u16*)xlb;                       // [4][4096][64]
    u16* Kb  = Qb + (size_t)4 * kN * 64;        // [4][4096][64]
    u16* VTb = Kb + (size_t)4 * kN * 64;        // [4][64][4096]
    // qkv in bf16, carved from the qkv slot.
    u16* qkvb = (u16*)qkv;                      // [4096][768] bf16
    // split-K partials: opart = xrb slot (1024 slots x 4096 f32 = 16 MB exact);
    // mlpart = locb slot (dead between ln1 and the mout GEMM).
    float* opart  = xrb;
    float* mlpart = locb;

    // bf16 weight buffer offsets (elements)
    const size_t OFF_INW  = 0;
    const size_t OFF_GWL  = 131072;
    const size_t OFF_GWR  = 917504;
    const size_t OFF_MIN  = 1703936;
    const size_t OFF_MOUT = 2293760;
    const size_t OFF_F1   = 2490368;
    const size_t OFF_F2   = 2883584;
    const size_t OFF_O1   = 3276800;

    auto cast = [&](const float* s, u16* d, int n) {
        int n4 = n >> 2;
        cast_f2b<<<dim3((n4 + 255) / 256), dim3(256), 0, stream>>>(s, d, n4);
    };
    cast(x, xbf, kN * kIn);
    cast(in_w, wbf + OFF_INW, kC * kIn);
    cast(gat_wl, wbf + OFF_GWL, kL * 1024 * kC);
    cast(gat_wr, wbf + OFF_GWR, kL * 1024 * kC);
    cast(mha_in_w, wbf + OFF_MIN, kL * 768 * kC);
    cast(mha_out_w, wbf + OFF_MOUT, kL * kC * kC);
    cast(ffn_w1, wbf + OFF_F1, kL * 512 * kC);
    cast(ffn_w2, wbf + OFF_F2, kL * kC * 512);
    cast(out_w1, wbf + OFF_O1, kC * kC);

    // CSR build (once per launch; same graph for all layers)
    hipMemsetAsync(ccur, 0, 4096 * 4, stream);
    csr_count<<<dim3((kET + 255) / 256), dim3(256), 0, stream>>>(ei, ccur);
    csr_scan<<<dim3(1), dim3(1024), 0, stream>>>(ccur, coff);
    csr_scatter<<<dim3((kET + 255) / 256), dim3(256), 0, stream>>>(ei, ccur, csrc);

    // input projection: h = x @ in_w^T + in_b  (fp32 + bf16 outputs)
    gemm_bt<0, 1, 1><<<dim3(kC / 64, kN / 64), dim3(256), 0, stream>>>(
        xbf, wbf + OFF_INW, in_b, h, hbf, kN, kC, kIn);

    for (int l = 0; l < kL; ++l) {
        // GATv2 transforms (bf16 outputs)
        gemm_bt<0, 0, 1><<<dim3(1024 / 64, kN / 64), dim3(256), 0, stream>>>(
            hbf, wbf + OFF_GWL + (size_t)l * 1024 * kC, nullptr, nullptr, xlbf, kN, 1024, kC);
        gemm_bt<0, 0, 1><<<dim3(1024 / 64, kN / 64), dim3(256), 0, stream>>>(
            hbf, wbf + OFF_GWR + (size_t)l * 1024 * kC, nullptr, nullptr, xrbf, kN, 1024, kC);
        gat_agg<<<dim3(kN), dim3(256), 0, stream>>>(
            xlbf, xrbf, gat_att + (size_t)l * 1024, gat_b + (size_t)l * kC, coff, csrc, locb);
        ln_res<<<dim3(kN / 4), dim3(256), 0, stream>>>(
            h, locb, ln1_g + (size_t)l * kC, ln1_b + (size_t)l * kC, h, hbf);

        // MHA
        gemm_bt<0, 0, 1><<<dim3(768 / 64, kN / 64), dim3(256), 0, stream>>>(
            hbf, wbf + OFF_MIN + (size_t)l * 768 * kC, mha_in_b + (size_t)l * 768, nullptr, qkvb, kN, 768, kC);
        qkv_repack<<<dim3(kN / 64, 4), dim3(256), 0, stream>>>(qkvb, Qb, Kb, VTb);
        mha_mfma2<<<dim3(kN / 64, 4, NSPLIT), dim3(256), 0, stream>>>(Qb, Kb, VTb, opart, mlpart);
        mha_merge<<<dim3(kN / 4, 4), dim3(256), 0, stream>>>(opart, mlpart, attnb);
        gemm_bt<0, 1, 0><<<dim3(kC / 64, kN / 64), dim3(256), 0, stream>>>(
            attnb, wbf + OFF_MOUT + (size_t)l * kC * kC, mha_out_b + (size_t)l * kC, locb, nullptr, kN, kC, kC);
        ln_res<<<dim3(kN / 4), dim3(256), 0, stream>>>(
            h, locb, ln2_g + (size_t)l * kC, ln2_b + (size_t)l * kC, h, hbf);

        // FFN
        gemm_bt<1, 0, 1><<<dim3(512 / 64, kN / 64), dim3(256), 0, stream>>>(
            hbf, wbf + OFF_F1 + (size_t)l * 512 * kC, ffn_b1 + (size_t)l * 512, nullptr, midb, kN, 512, kC);
        gemm_bt<0, 1, 0><<<dim3(kC / 64, kN / 64), dim3(256), 0, stream>>>(
            midb, wbf + OFF_F2 + (size_t)l * kC * 512, ffn_b2 + (size_t)l * kC, locb, nullptr, kN, kC, 512);
        ln_res<<<dim3(kN / 4), dim3(256), 0, stream>>>(
            h, locb, ln3_g + (size_t)l * kC, ln3_b + (size_t)l * kC, h, hbf);
    }

    // output head
    gemm_bt<1, 0, 1><<<dim3(kC / 64, kN / 64), dim3(256), 0, stream>>>(
        hbf, wbf + OFF_O1, out_b1, nullptr, tbf, kN, kC, kC);
    final_out<<<dim3(kN / 4), dim3(256), 0, stream>>>(tbf, out_w2, out_b2, out);
}

// Round 9
// 534.408 us; speedup vs baseline: 9.0163x; 1.1598x over previous
//
#include <hip/hip_runtime.h>
#include <cstdint>
#include <cstddef>

typedef unsigned short u16;
typedef __bf16 bf16x8 __attribute__((ext_vector_type(8)));
typedef float f32x4 __attribute__((ext_vector_type(4)));

constexpr int kN  = 4096;
constexpr int kE  = 131072;
constexpr int kET = kE + kN;   // with self loops
constexpr int kIn = 512;
constexpr int kC  = 256;
constexpr int kL  = 3;

constexpr int NSPLIT = 4;
constexpr int KSPAN  = kN / NSPLIT;  // 1024 keys per split
constexpr int NSTEP  = KSPAN / 64;   // 16 steps of 64 keys

__device__ __forceinline__ u16 f2bf(float f) {
    unsigned u = __builtin_bit_cast(unsigned, f);
    u += 0x7fffu + ((u >> 16) & 1u);
    return (u16)(u >> 16);
}
__device__ __forceinline__ float bf2f(u16 s) {
    unsigned u = ((unsigned)s) << 16;
    return __builtin_bit_cast(float, u);
}
__device__ __forceinline__ float gelu_erf(float x) {
    return 0.5f * x * (1.f + erff(x * 0.70710678118654752f));
}
// async global->LDS, 16B per lane; ldst must be wave-uniform base (HW adds lane*16)
__device__ __forceinline__ void gload_lds16(const u16* gsrc, u16* ldst) {
    __builtin_amdgcn_global_load_lds(
        (const __attribute__((address_space(1))) unsigned int*)gsrc,
        (__attribute__((address_space(3))) unsigned int*)ldst, 16, 0, 0);
}
// sum over each row of 16 lanes via DPP row_ror adds (full-rate VALU, no LDS pipe)
__device__ __forceinline__ float dpp_ror_add16(float x) {
    int t;
    t = __builtin_amdgcn_update_dpp(0, __builtin_bit_cast(int, x), 0x121, 0xf, 0xf, true);
    x += __builtin_bit_cast(float, t);
    t = __builtin_amdgcn_update_dpp(0, __builtin_bit_cast(int, x), 0x122, 0xf, 0xf, true);
    x += __builtin_bit_cast(float, t);
    t = __builtin_amdgcn_update_dpp(0, __builtin_bit_cast(int, x), 0x124, 0xf, 0xf, true);
    x += __builtin_bit_cast(float, t);
    t = __builtin_amdgcn_update_dpp(0, __builtin_bit_cast(int, x), 0x128, 0xf, 0xf, true);
    x += __builtin_bit_cast(float, t);
    return x;
}
// unpack 8 bf16 (uint4) -> 8 f32
__device__ __forceinline__ void unpack8(uint4 u, float* x) {
    x[0] = __builtin_bit_cast(float, u.x << 16);
    x[1] = __builtin_bit_cast(float, u.x & 0xffff0000u);
    x[2] = __builtin_bit_cast(float, u.y << 16);
    x[3] = __builtin_bit_cast(float, u.y & 0xffff0000u);
    x[4] = __builtin_bit_cast(float, u.z << 16);
    x[5] = __builtin_bit_cast(float, u.z & 0xffff0000u);
    x[6] = __builtin_bit_cast(float, u.w << 16);
    x[7] = __builtin_bit_cast(float, u.w & 0xffff0000u);
}

// ---------------- cast fp32 -> bf16 (vector4) ----------------
__global__ void cast_f2b(const float* __restrict__ src, u16* __restrict__ dst, int n4) {
    int i = blockIdx.x * blockDim.x + threadIdx.x;
    if (i >= n4) return;
    float4 v = ((const float4*)src)[i];
    ushort4 o;
    o.x = f2bf(v.x); o.y = f2bf(v.y); o.z = f2bf(v.z); o.w = f2bf(v.w);
    ((ushort4*)dst)[i] = o;
}

// ---------------- CSR build (by dst) ----------------
__global__ void csr_count(const int* __restrict__ ei, int* __restrict__ cnt) {
    int e = blockIdx.x * 256 + threadIdx.x;
    if (e >= kET) return;
    int d = (e < kE) ? ei[kE + e] : (e - kE);
    atomicAdd(cnt + d, 1);
}

__global__ __launch_bounds__(1024) void csr_scan(int* __restrict__ cnt_cur, int* __restrict__ off) {
    __shared__ int lds[1024];
    int t = threadIdx.x;
    int c[4], s = 0;
#pragma unroll
    for (int j = 0; j < 4; ++j) { c[j] = cnt_cur[t * 4 + j]; s += c[j]; }
    lds[t] = s;
    __syncthreads();
    for (int d = 1; d < 1024; d <<= 1) {
        int v = (t >= d) ? lds[t - d] : 0;
        __syncthreads();
        lds[t] += v;
        __syncthreads();
    }
    int excl = lds[t] - s;
#pragma unroll
    for (int j = 0; j < 4; ++j) { off[t * 4 + j] = excl; cnt_cur[t * 4 + j] = excl; excl += c[j]; }
    if (t == 1023) off[4096] = excl;
}

__global__ void csr_scatter(const int* __restrict__ ei, int* __restrict__ cur, int* __restrict__ csrc) {
    int e = blockIdx.x * 256 + threadIdx.x;
    if (e >= kET) return;
    int s, d;
    if (e < kE) { s = ei[e]; d = ei[kE + e]; } else { s = d = e - kE; }
    int pos = atomicAdd(cur + d, 1);
    csrc[pos] = s;
}

// ---------------- staged bf16 MFMA GEMM: C[M,N] = act(A[M,K] @ W[N,K]^T + bias) ----
// block 256 = 4 waves (2x2); block tile BM x 64; LDS double-buffered via
// global_load_lds (BK=32). Fragment reads are contiguous 1KB regions per
// instruction -> bank-conflict-free with linear (unswizzled) staging.
template <int BM, int K, int ACT, int WF32, int WBF16>
__global__ __launch_bounds__(256) void gemm_st(
    const u16* __restrict__ A, const u16* __restrict__ W,
    const float* __restrict__ bias, float* __restrict__ Cf,
    u16* __restrict__ Cb, int N) {
    constexpr int BK = 32;
    constexpr int NK = K / BK;
    constexpr int MF = BM / 32;          // A fragments per wave
    int tid = threadIdx.x;
    int w = tid >> 6, lane = tid & 63;
    int wr = w >> 1, wc = w & 1;
    int g = lane >> 4, r = lane & 15;
    int bm = blockIdx.y * BM;
    int bn = blockIdx.x * 64;
    __shared__ __align__(16) u16 Ab[2][BM * BK];
    __shared__ __align__(16) u16 Bb[2][64 * BK];
    // staging: wave w covers rows [i*64 + w*16, +16): lane -> row w*16+(lane>>2), chunk lane&3
    int srow = w * 16 + (lane >> 2);
    int scol = (lane & 3) * 8;
    auto stage = [&](int buf, int k0) {
#pragma unroll
        for (int i = 0; i < BM / 64; ++i)
            gload_lds16(A + (size_t)(bm + i * 64 + srow) * K + k0 + scol,
                        &Ab[buf][(i * 64 + w * 16) * BK]);
        gload_lds16(W + (size_t)(bn + srow) * K + k0 + scol, &Bb[buf][w * 16 * BK]);
    };
    f32x4 acc[MF][2] = {};
    stage(0, 0);
    __syncthreads();
    for (int st = 0; st < NK; ++st) {
        int cur = st & 1;
        if (st + 1 < NK) stage(cur ^ 1, (st + 1) * BK);
        const u16* Al = &Ab[cur][0];
        const u16* Bl = &Bb[cur][0];
        bf16x8 bf[2];
#pragma unroll
        for (int u = 0; u < 2; ++u)
            bf[u] = *(const bf16x8*)(Bl + (wc * 32 + u * 16 + r) * BK + g * 8);
#pragma unroll
        for (int t = 0; t < MF; ++t) {
            bf16x8 af = *(const bf16x8*)(Al + (wr * (BM / 2) + t * 16 + r) * BK + g * 8);
#pragma unroll
            for (int u = 0; u < 2; ++u)
                acc[t][u] = __builtin_amdgcn_mfma_f32_16x16x32_bf16(af, bf[u], acc[t][u], 0, 0, 0);
        }
        __syncthreads();   // vmcnt(0): next buffer staged; lgkm: reads of cur done
    }
    int r0 = bm + wr * (BM / 2) + g * 4;
    int c0 = bn + wc * 32 + r;
#pragma unroll
    for (int t = 0; t < MF; ++t)
#pragma unroll
        for (int u = 0; u < 2; ++u)
#pragma unroll
            for (int e = 0; e < 4; ++e) {
                int row = r0 + t * 16 + e, col = c0 + u * 16;
                float v = acc[t][u][e];
                if (bias) v += bias[col];
                if (ACT == 1) v = gelu_erf(v);
                if (WF32) Cf[(size_t)row * N + col] = v;
                if (WBF16) Cb[(size_t)row * N + col] = f2bf(v);
            }
}

// ---------------- LayerNorm(h + add) -> h (fp32) and h_bf (bf16); wave per row ----------------
__global__ __launch_bounds__(256) void ln_res(
    const float* hin, const float* add,
    const float* __restrict__ g, const float* __restrict__ b,
    float* hout, u16* __restrict__ hbf) {
    int row = blockIdx.x * 4 + (threadIdx.x >> 6);
    int lane = threadIdx.x & 63;
    const float4 x4 = *(const float4*)(hin + (size_t)row * kC + lane * 4);
    const float4 a4 = *(const float4*)(add + (size_t)row * kC + lane * 4);
    float v[4] = {x4.x + a4.x, x4.y + a4.y, x4.z + a4.z, x4.w + a4.w};
    float s = v[0] + v[1] + v[2] + v[3];
    for (int d = 1; d < 64; d <<= 1) s += __shfl_xor(s, d);
    float mu = s * (1.f / kC);
    float q = 0.f;
#pragma unroll
    for (int j = 0; j < 4; ++j) { float d = v[j] - mu; q += d * d; }
    for (int d = 1; d < 64; d <<= 1) q += __shfl_xor(q, d);
    float rstd = rsqrtf(q * (1.f / kC) + 1e-5f);
    const float4 g4 = *(const float4*)(g + lane * 4);
    const float4 b4 = *(const float4*)(b + lane * 4);
    float y0 = (v[0] - mu) * rstd * g4.x + b4.x;
    float y1 = (v[1] - mu) * rstd * g4.y + b4.y;
    float y2 = (v[2] - mu) * rstd * g4.z + b4.z;
    float y3 = (v[3] - mu) * rstd * g4.w + b4.w;
    *(float4*)(hout + (size_t)row * kC + lane * 4) = make_float4(y0, y1, y2, y3);
    ushort4 o; o.x = f2bf(y0); o.y = f2bf(y1); o.z = f2bf(y2); o.w = f2bf(y3);
    *(ushort4*)(hbf + (size_t)row * kC + lane * 4) = o;
}

// ---------------- GATv2: per-node online softmax aggregation ----------------
// xg: fused [4096][2048] bf16 (cols 0..1023 = xl transform, 1024..2047 = xr).
// Block = node, wave = head; 4 quarters/wave each process their own edge
// (16 channels/lane). leaky(e) = 0.6e + 0.4|e| -> score via 2 fma/channel
// (|e| is a free input modifier). DPP row_ror reduce; 4-way LSE merge.
__global__ __launch_bounds__(256) void gat_agg(
    const u16* __restrict__ xg,
    const float* __restrict__ att, const float* __restrict__ gb,
    const int* __restrict__ off, const int* __restrict__ srcs,
    float* __restrict__ outloc) {
    int n = blockIdx.x;
    int w = threadIdx.x >> 6, lane = threadIdx.x & 63;
    int q = lane >> 4, t = lane & 15;
    int cb = w * 256 + t * 16;   // channel slice [cb, cb+16) of 1024

    uint4 xru0 = *(const uint4*)(xg + (size_t)n * 2048 + 1024 + cb);
    uint4 xru1 = *(const uint4*)(xg + (size_t)n * 2048 + 1024 + cb + 8);
    float xrv[16];
    unpack8(xru0, xrv); unpack8(xru1, xrv + 8);
    float att6[16], att4[16];
#pragma unroll
    for (int j = 0; j < 16; j += 4) {
        float4 a4 = *(const float4*)(att + cb + j);
        att6[j] = 0.6f * a4.x; att6[j + 1] = 0.6f * a4.y;
        att6[j + 2] = 0.6f * a4.z; att6[j + 3] = 0.6f * a4.w;
        att4[j] = (2.f / 3.f) * att6[j]; att4[j + 1] = (2.f / 3.f) * att6[j + 1];
        att4[j + 2] = (2.f / 3.f) * att6[j + 2]; att4[j + 3] = (2.f / 3.f) * att6[j + 3];
    }

    int i0 = off[n], i1 = off[n + 1];
    float m = -1e30f, ls = 0.f;
    float acc[16] = {};
    int i = i0 + q;
    uint4 p0, p1;
    if (i < i1) {
        int s = srcs[i];
        p0 = *(const uint4*)(xg + (size_t)s * 2048 + cb);
        p1 = *(const uint4*)(xg + (size_t)s * 2048 + cb + 8);
    }
    while (i < i1) {
        uint4 c0 = p0, c1 = p1;
        int inext = i + 4;
        if (inext < i1) {
            int s2 = srcs[inext];
            p0 = *(const uint4*)(xg + (size_t)s2 * 2048 + cb);
            p1 = *(const uint4*)(xg + (size_t)s2 * 2048 + cb + 8);
        }
        float x[16];
        unpack8(c0, x); unpack8(c1, x + 8);
        float p = 0.f;
#pragma unroll
        for (int j = 0; j < 16; ++j) {
            float e = x[j] + xrv[j];
            p = fmaf(att6[j], e, p);
            p = fmaf(att4[j], __builtin_fabsf(e), p);
        }
        p = dpp_ror_add16(p);   // all 16 lanes of the quarter now hold the score
        if (p > m) {            // quarter-uniform; divergence between quarters is rare
            float c = __expf(m - p);
            ls = ls * c + 1.f;
#pragma unroll
            for (int j = 0; j < 16; ++j) acc[j] = acc[j] * c + x[j];
            m = p;
        } else {
            float pw = __expf(p - m);
            ls += pw;
#pragma unroll
            for (int j = 0; j < 16; ++j) acc[j] = fmaf(pw, x[j], acc[j]);
        }
        i = inext;
    }
    // exact LSE merge of the 4 quarter states (quarter index = lane bits 4..5)
    float mm = fmaxf(m, __shfl_xor(m, 16));
    mm = fmaxf(mm, __shfl_xor(mm, 32));
    float c = __expf(m - mm);   // 0 for empty quarters (m = -1e30)
    ls *= c;
    ls += __shfl_xor(ls, 16);
    ls += __shfl_xor(ls, 32);
#pragma unroll
    for (int j = 0; j < 16; ++j) {
        float a = acc[j] * c;
        a += __shfl_xor(a, 16);
        a += __shfl_xor(a, 32);
        acc[j] = a;
    }
    float inv = 1.f / ls;
    __shared__ float red[4][256];
    if (q == 0) {
#pragma unroll
        for (int j = 0; j < 16; ++j) red[w][t * 16 + j] = acc[j] * inv;
    }
    __syncthreads();
    int cc = threadIdx.x;
    float vsum = 0.25f * (red[0][cc] + red[1][cc] + red[2][cc] + red[3][cc]) + gb[cc];
    outloc[(size_t)n * kC + cc] = vsum;
}

// ---------------- qkv repack: qkvb bf16 [4096][768] -> Qb/Kb [4][4096][64], VTb [4][64][4096]
// Q scaled by 1/sqrt(64) * log2(e) so attention can use exp2 directly.
__global__ __launch_bounds__(256) void qkv_repack(
    const u16* __restrict__ qkvb, u16* __restrict__ Qb, u16* __restrict__ Kb,
    u16* __restrict__ VTb) {
    int h = blockIdx.y;
    int n0 = blockIdx.x * 64;
    int t = threadIdx.x;
    int nr = t >> 2, cb = (t & 3) * 16;
    const u16* src = qkvb + (size_t)(n0 + nr) * 768 + h * 64 + cb;
    u16* qd = Qb + ((size_t)h * kN + n0 + nr) * 64 + cb;
    u16* kd = Kb + ((size_t)h * kN + n0 + nr) * 64 + cb;
    __shared__ u16 lds[64][72];
    constexpr float QS = 0.125f * 1.4426950408889634f;  // 1/sqrt(DH) * log2(e)
#pragma unroll
    for (int j = 0; j < 16; j += 4) {
        ushort4 q4 = *(const ushort4*)(src + j);
        ushort4 k4 = *(const ushort4*)(src + 256 + j);
        ushort4 v4 = *(const ushort4*)(src + 512 + j);
        ushort4 qo;
        qo.x = f2bf(bf2f(q4.x) * QS); qo.y = f2bf(bf2f(q4.y) * QS);
        qo.z = f2bf(bf2f(q4.z) * QS); qo.w = f2bf(bf2f(q4.w) * QS);
        *(ushort4*)(qd + j) = qo;
        *(ushort4*)(kd + j) = k4;
        *(ushort4*)(&lds[nr][cb + j]) = v4;
    }
    __syncthreads();
    int d = t >> 2, nb = (t & 3) * 16;
    u16* vd = VTb + ((size_t)h * 64 + d) * kN + n0 + nb;
#pragma unroll
    for (int j = 0; j < 16; j += 4) {
        ushort4 vo;
        vo.x = lds[nb + j + 0][d];
        vo.y = lds[nb + j + 1][d];
        vo.z = lds[nb + j + 2][d];
        vo.w = lds[nb + j + 3][d];
        *(ushort4*)(vd + j) = vo;
    }
}

// ---------------- MFMA flash attention, LDS-shared K/V, split-K ----------------
// Block = 4 waves, 64 q rows (16/wave). Grid (kN/64, heads, NSPLIT).
// K and VT 64x64 tiles double-buffered in LDS via global_load_lds with XOR-swizzled
// source (chunk ^= row&7); plds uses the SAME chunk swizzle (c ^= r&7) so the
// P C->A roundtrip is bank-conflict-free.
// Writes unnormalized partial O + (m,l) per split; mha_merge recombines (LSE merge).
__global__ __launch_bounds__(256, 4) void mha_mfma2(
    const u16* __restrict__ Qb, const u16* __restrict__ Kb,
    const u16* __restrict__ VTb, float* __restrict__ opart, float* __restrict__ mlpart) {
    int qt = blockIdx.x, head = blockIdx.y, sp = blockIdx.z;
    int tid = threadIdx.x;
    int w = tid >> 6, lane = tid & 63;
    int g = lane >> 4, r = lane & 15;
    int q0 = qt * 64;
    const u16* Qh = Qb + ((size_t)head * kN + q0 + w * 16) * 64;
    const u16* Kh = Kb + (size_t)head * kN * 64;
    const u16* VTh = VTb + (size_t)head * 64 * kN;
    __shared__ u16 Kt[2][64 * 64];
    __shared__ u16 Vt[2][64 * 64];
    __shared__ u16 plds[4][16 * 64];
    int srow = w * 8 + (lane >> 3);
    int schunk = ((lane & 7) ^ ((lane >> 3) & 7)) * 8;   // element offset within row
    int kbase = sp * KSPAN;

    bf16x8 qf0 = *(const bf16x8*)(Qh + r * 64 + g * 8);
    bf16x8 qf1 = *(const bf16x8*)(Qh + r * 64 + 32 + g * 8);

    auto stage = [&](int buf, int k0) {
#pragma unroll
        for (int i = 0; i < 2; ++i) {
            int row = i * 32 + srow;
            gload_lds16(Kh + (size_t)(k0 + row) * 64 + schunk, &Kt[buf][(i * 32 + w * 8) * 64]);
            gload_lds16(VTh + (size_t)row * kN + k0 + schunk, &Vt[buf][(i * 32 + w * 8) * 64]);
        }
    };

    f32x4 o[4] = {};
    float m = -3.0e38f, l = 0.f;

    stage(0, kbase);
    __syncthreads();   // vmcnt(0) drain + barrier: buffer 0 ready

    int rx = r & 7;
    for (int st = 0; st < NSTEP; ++st) {
        int cur = st & 1;
        if (st + 1 < NSTEP) stage(cur ^ 1, kbase + (st + 1) * 64);
        const u16* Kl = &Kt[cur][0];
        const u16* Vl = &Vt[cur][0];
        // S^T tiles: rows = keys (16t + 4g + reg), cols = q (r)
        f32x4 stt[4] = {};
#pragma unroll
        for (int t = 0; t < 4; ++t) {
            bf16x8 kf0 = *(const bf16x8*)(Kl + (16 * t + r) * 64 + ((0 + g) ^ rx) * 8);
            bf16x8 kf1 = *(const bf16x8*)(Kl + (16 * t + r) * 64 + ((4 + g) ^ rx) * 8);
            stt[t] = __builtin_amdgcn_mfma_f32_16x16x32_bf16(kf0, qf0, stt[t], 0, 0, 0);
            stt[t] = __builtin_amdgcn_mfma_f32_16x16x32_bf16(kf1, qf1, stt[t], 0, 0, 0);
        }
        // online softmax (exp2 domain), state per q=r (replicated across g groups)
        float pm = stt[0][0];
#pragma unroll
        for (int t = 0; t < 4; ++t)
#pragma unroll
            for (int e = 0; e < 4; ++e) pm = fmaxf(pm, stt[t][e]);
        pm = fmaxf(pm, __shfl_xor(pm, 16));
        pm = fmaxf(pm, __shfl_xor(pm, 32));
        float mn = fmaxf(m, pm);
        float corr = __builtin_amdgcn_exp2f(m - mn);
        float ls = 0.f;
        float p[4][4];
#pragma unroll
        for (int t = 0; t < 4; ++t)
#pragma unroll
            for (int e = 0; e < 4; ++e) { p[t][e] = __builtin_amdgcn_exp2f(stt[t][e] - mn); ls += p[t][e]; }
        ls += __shfl_xor(ls, 16);
        ls += __shfl_xor(ls, 32);
        l = l * corr + ls;
        m = mn;
        float corrq[4];
#pragma unroll
        for (int e = 0; e < 4; ++e) corrq[e] = __shfl(corr, g * 4 + e);
#pragma unroll
        for (int dt = 0; dt < 4; ++dt)
#pragma unroll
            for (int e = 0; e < 4; ++e) o[dt][e] *= corrq[e];
        // P: C-layout -> LDS -> A-layout. plds chunk-swizzled by q-row (c ^= r&7)
#pragma unroll
        for (int t = 0; t < 4; ++t) {
            ushort4 pk;
            pk.x = f2bf(p[t][0]); pk.y = f2bf(p[t][1]);
            pk.z = f2bf(p[t][2]); pk.w = f2bf(p[t][3]);
            int lc = (2 * t + (g >> 1)) ^ rx;
            *(ushort4*)(&plds[w][r * 64 + lc * 8 + (g & 1) * 4]) = pk;
        }
        bf16x8 pa0 = *(const bf16x8*)(&plds[w][r * 64 + (g ^ rx) * 8]);
        bf16x8 pa1 = *(const bf16x8*)(&plds[w][r * 64 + ((4 + g) ^ rx) * 8]);
#pragma unroll
        for (int dt = 0; dt < 4; ++dt) {
            bf16x8 vf0 = *(const bf16x8*)(Vl + (dt * 16 + r) * 64 + ((0 + g) ^ rx) * 8);
            bf16x8 vf1 = *(const bf16x8*)(Vl + (dt * 16 + r) * 64 + ((4 + g) ^ rx) * 8);
            o[dt] = __builtin_amdgcn_mfma_f32_16x16x32_bf16(pa0, vf0, o[dt], 0, 0, 0);
            o[dt] = __builtin_amdgcn_mfma_f32_16x16x32_bf16(pa1, vf1, o[dt], 0, 0, 0);
        }
        __syncthreads();   // vmcnt(0): next buffer staged; lgkmcnt: all reads of cur done
    }

    // store unnormalized partials
    size_t slot = (size_t)(head * 64 + qt) * NSPLIT + sp;
    float* ob = opart + slot * 4096;
#pragma unroll
    for (int dt = 0; dt < 4; ++dt)
#pragma unroll
        for (int e = 0; e < 4; ++e)
            ob[(w * 16 + g * 4 + e) * 64 + dt * 16 + r] = o[dt][e];
    float* mlb = mlpart + slot * 128;
    if (g == 0) { mlb[w * 16 + r] = m; mlb[64 + w * 16 + r] = l; }
}

// ---------------- merge split-K attention partials -> attnb (bf16) ----------------
// grid (kN/4, heads), block 256: wave w = one q row, lane = d (0..63)
__global__ __launch_bounds__(256) void mha_merge(
    const float* __restrict__ opart, const float* __restrict__ mlpart,
    u16* __restrict__ attnb) {
    int head = blockIdx.y;
    int q = blockIdx.x * 4 + (threadIdx.x >> 6);
    int d = threadIdx.x & 63;
    int qt = q >> 6, ql = q & 63;
    size_t sb = (size_t)(head * 64 + qt) * NSPLIT;
    float ms[NSPLIT], lsv[NSPLIT];
    float mstar = -3.0e38f;
#pragma unroll
    for (int s = 0; s < NSPLIT; ++s) {
        ms[s] = mlpart[(sb + s) * 128 + ql];
        lsv[s] = mlpart[(sb + s) * 128 + 64 + ql];
        mstar = fmaxf(mstar, ms[s]);
    }
    float acc = 0.f, lsum = 0.f;
#pragma unroll
    for (int s = 0; s < NSPLIT; ++s) {
        float wgt = __builtin_amdgcn_exp2f(ms[s] - mstar);
        lsum += lsv[s] * wgt;
        acc += opart[(sb + s) * 4096 + ql * 64 + d] * wgt;
    }
    attnb[(size_t)q * kC + head * 64 + d] = f2bf(acc / lsum);
}

// ---------------- final: out[4096,2] = t_bf @ out_w2^T + b2; wave per row ----------------
__global__ __launch_bounds__(256) void final_out(
    const u16* __restrict__ tbf, const float* __restrict__ w2,
    const float* __restrict__ b2, float* __restrict__ out) {
    int row = blockIdx.x * 4 + (threadIdx.x >> 6);
    int lane = threadIdx.x & 63;
    const ushort4 tv = *(const ushort4*)(tbf + (size_t)row * 256 + lane * 4);
    float t0 = bf2f(tv.x), t1 = bf2f(tv.y), t2 = bf2f(tv.z), t3 = bf2f(tv.w);
    const float4 w0 = *(const float4*)(w2 + lane * 4);
    const float4 w1 = *(const float4*)(w2 + 256 + lane * 4);
    float d0 = t0 * w0.x + t1 * w0.y + t2 * w0.z + t3 * w0.w;
    float d1 = t0 * w1.x + t1 * w1.y + t2 * w1.z + t3 * w1.w;
    for (int d = 1; d < 64; d <<= 1) { d0 += __shfl_xor(d0, d); d1 += __shfl_xor(d1, d); }
    if (lane == 0) {
        out[(size_t)row * 2 + 0] = d0 + b2[0];
        out[(size_t)row * 2 + 1] = d1 + b2[1];
    }
}

extern "C" void kernel_launch(void* const* d_in, const int* in_sizes, int n_in,
                              void* d_out, int out_size, void* d_ws, size_t ws_size,
                              hipStream_t stream) {
    (void)in_sizes; (void)n_in; (void)out_size;
    const float* x        = (const float*)d_in[0];
    const int*   ei       = (const int*)d_in[1];
    const float* in_w     = (const float*)d_in[2];
    const float* in_b     = (const float*)d_in[3];
    const float* gat_wl   = (const float*)d_in[4];
    const float* gat_wr   = (const float*)d_in[5];
    const float* gat_att  = (const float*)d_in[6];
    const float* gat_b    = (const float*)d_in[7];
    const float* mha_in_w = (const float*)d_in[8];
    const float* mha_in_b = (const float*)d_in[9];
    const float* mha_out_w= (const float*)d_in[10];
    const float* mha_out_b= (const float*)d_in[11];
    const float* ln1_g = (const float*)d_in[12];
    const float* ln1_b = (const float*)d_in[13];
    const float* ln2_g = (const float*)d_in[14];
    const float* ln2_b = (const float*)d_in[15];
    const float* ln3_g = (const float*)d_in[16];
    const float* ln3_b = (const float*)d_in[17];
    const float* ffn_w1 = (const float*)d_in[18];
    const float* ffn_b1 = (const float*)d_in[19];
    const float* ffn_w2 = (const float*)d_in[20];
    const float* ffn_b2 = (const float*)d_in[21];
    const float* out_w1 = (const float*)d_in[22];
    const float* out_b1 = (const float*)d_in[23];
    const float* out_w2 = (const float*)d_in[24];
    const float* out_b2 = (const float*)d_in[25];
    float* out = (float*)d_out;

    char* ws = (char*)d_ws;
    size_t off = 0;
    auto alloc = [&](size_t bytes) -> void* {
        void* p = (void*)(ws + off);
        off += (bytes + 255) & ~(size_t)255;
        return p;
    };
    float* h     = (float*)alloc((size_t)kN * kC * 4);
    u16*   hbf   = (u16*)  alloc((size_t)kN * kC * 2);
    float* xlb   = (float*)alloc((size_t)kN * 1024 * 4);   // slot reused: xgbf / Qb+Kb+VTb
    float* xrb   = (float*)alloc((size_t)kN * 1024 * 4);   // slot reused: opart
    float* qkv   = (float*)alloc((size_t)kN * 768 * 4);    // slot reused: qkvb (bf16)
    float* locb  = (float*)alloc((size_t)kN * kC * 4);
    u16*   attnb = (u16*)  alloc((size_t)kN * kC * 2);
    u16*   midb  = (u16*)  alloc((size_t)kN * 512 * 2);
    u16*   tbf   = (u16*)  alloc((size_t)kN * kC * 2);
    u16*   xbf   = (u16*)  alloc((size_t)kN * kIn * 2);
    u16*   wbf   = (u16*)  alloc((size_t)3342336 * 2);
    int*   coff  = (int*)  alloc((size_t)4097 * 4);
    int*   ccur  = (int*)  alloc((size_t)4096 * 4);
    int*   csrc  = (int*)  alloc((size_t)kET * 4);
    if (ws_size < off) return;  // not enough scratch: bail loudly (output stays poisoned)

    // Fused GAT transform output [4096][2048] bf16 (cols 0..1023 = xl, 1024.. = xr)
    // = exactly the 16 MB xlb slot.
    u16* xgbf = (u16*)xlb;
    // MHA attention operands: alias the same slot (xgbf dead after gat_agg).
    u16* Qb  = (u16*)xlb;                       // [4][4096][64]
    u16* Kb  = Qb + (size_t)4 * kN * 64;        // [4][4096][64]
    u16* VTb = Kb + (size_t)4 * kN * 64;        // [4][64][4096]
    u16* qkvb = (u16*)qkv;                      // [4096][768] bf16
    float* opart  = xrb;                        // 1024 slots x 4096 f32 = 16 MB exact
    float* mlpart = locb;                       // dead between ln1 and the mout GEMM

    // bf16 weight buffer offsets (elements); gat wl/wr interleaved per layer [2048][256]
    const size_t OFF_INW  = 0;
    const size_t OFF_GAT  = 131072;
    const size_t OFF_MIN  = 1703936;
    const size_t OFF_MOUT = 2293760;
    const size_t OFF_F1   = 2490368;
    const size_t OFF_F2   = 2883584;
    const size_t OFF_O1   = 3276800;

    auto cast = [&](const float* s, u16* d, int n) {
        int n4 = n >> 2;
        cast_f2b<<<dim3((n4 + 255) / 256), dim3(256), 0, stream>>>(s, d, n4);
    };
    cast(x, xbf, kN * kIn);
    cast(in_w, wbf + OFF_INW, kC * kIn);
    for (int l = 0; l < kL; ++l) {
        cast(gat_wl + (size_t)l * 262144, wbf + OFF_GAT + (size_t)l * 524288, 262144);
        cast(gat_wr + (size_t)l * 262144, wbf + OFF_GAT + (size_t)l * 524288 + 262144, 262144);
    }
    cast(mha_in_w, wbf + OFF_MIN, kL * 768 * kC);
    cast(mha_out_w, wbf + OFF_MOUT, kL * kC * kC);
    cast(ffn_w1, wbf + OFF_F1, kL * 512 * kC);
    cast(ffn_w2, wbf + OFF_F2, kL * kC * 512);
    cast(out_w1, wbf + OFF_O1, kC * kC);

    // CSR build (once per launch; same graph for all layers)
    hipMemsetAsync(ccur, 0, 4096 * 4, stream);
    csr_count<<<dim3((kET + 255) / 256), dim3(256), 0, stream>>>(ei, ccur);
    csr_scan<<<dim3(1), dim3(1024), 0, stream>>>(ccur, coff);
    csr_scatter<<<dim3((kET + 255) / 256), dim3(256), 0, stream>>>(ei, ccur, csrc);

    // input projection: h = x @ in_w^T + in_b  (fp32 + bf16 outputs)
    gemm_st<64, 512, 0, 1, 1><<<dim3(kC / 64, kN / 64), dim3(256), 0, stream>>>(
        xbf, wbf + OFF_INW, in_b, h, hbf, kC);

    for (int l = 0; l < kL; ++l) {
        // GATv2 transforms: fused wl|wr GEMM -> xgbf [4096][2048]
        gemm_st<128, 256, 0, 0, 1><<<dim3(2048 / 64, kN / 128), dim3(256), 0, stream>>>(
            hbf, wbf + OFF_GAT + (size_t)l * 524288, nullptr, nullptr, xgbf, 2048);
        gat_agg<<<dim3(kN), dim3(256), 0, stream>>>(
            xgbf, gat_att + (size_t)l * 1024, gat_b + (size_t)l * kC, coff, csrc, locb);
        ln_res<<<dim3(kN / 4), dim3(256), 0, stream>>>(
            h, locb, ln1_g + (size_t)l * kC, ln1_b + (size_t)l * kC, h, hbf);

        // MHA
        gemm_st<128, 256, 0, 0, 1><<<dim3(768 / 64, kN / 128), dim3(256), 0, stream>>>(
            hbf, wbf + OFF_MIN + (size_t)l * 768 * kC, mha_in_b + (size_t)l * 768, nullptr, qkvb, 768);
        qkv_repack<<<dim3(kN / 64, 4), dim3(256), 0, stream>>>(qkvb, Qb, Kb, VTb);
        mha_mfma2<<<dim3(kN / 64, 4, NSPLIT), dim3(256), 0, stream>>>(Qb, Kb, VTb, opart, mlpart);
        mha_merge<<<dim3(kN / 4, 4), dim3(256), 0, stream>>>(opart, mlpart, attnb);
        gemm_st<64, 256, 0, 1, 0><<<dim3(kC / 64, kN / 64), dim3(256), 0, stream>>>(
            attnb, wbf + OFF_MOUT + (size_t)l * kC * kC, mha_out_b + (size_t)l * kC, locb, nullptr, kC);
        ln_res<<<dim3(kN / 4), dim3(256), 0, stream>>>(
            h, locb, ln2_g + (size_t)l * kC, ln2_b + (size_t)l * kC, h, hbf);

        // FFN
        gemm_st<64, 256, 1, 0, 1><<<dim3(512 / 64, kN / 64), dim3(256), 0, stream>>>(
            hbf, wbf + OFF_F1 + (size_t)l * 512 * kC, ffn_b1 + (size_t)l * 512, nullptr, midb, 512);
        gemm_st<64, 512, 0, 1, 0><<<dim3(kC / 64, kN / 64), dim3(256), 0, stream>>>(
            midb, wbf + OFF_F2 + (size_t)l * kC * 512, ffn_b2 + (size_t)l * kC, locb, nullptr, kC);
        ln_res<<<dim3(kN / 4), dim3(256), 0, stream>>>(
            h, locb, ln3_g + (size_t)l * kC, ln3_b + (size_t)l * kC, h, hbf);
    }

    // output head
    gemm_st<64, 256, 1, 0, 1><<<dim3(kC / 64, kN / 64), dim3(256), 0, stream>>>(
        hbf, wbf + OFF_O1, out_b1, nullptr, tbf, kC);
    final_out<<<dim3(kN / 4), dim3(256), 0, stream>>>(tbf, out_w2, out_b2, out);
}

// Round 10
// 529.027 us; speedup vs baseline: 9.1080x; 1.0102x over previous
//
#include <hip/hip_runtime.h>
#include <cstdint>
#include <cstddef>

typedef unsigned short u16;
typedef __bf16 bf16x8 __attribute__((ext_vector_type(8)));
typedef float f32x4 __attribute__((ext_vector_type(4)));

constexpr int kN  = 4096;
constexpr int kE  = 131072;
constexpr int kET = kE + kN;   // with self loops
constexpr int kIn = 512;
constexpr int kC  = 256;
constexpr int kL  = 3;

constexpr int NSPLIT = 4;
constexpr int KSPAN  = kN / NSPLIT;  // 1024 keys per split
constexpr int NSTEP  = KSPAN / 64;   // 16 steps of 64 keys

__device__ __forceinline__ u16 f2bf(float f) {
    unsigned u = __builtin_bit_cast(unsigned, f);
    u += 0x7fffu + ((u >> 16) & 1u);
    return (u16)(u >> 16);
}
__device__ __forceinline__ float bf2f(u16 s) {
    unsigned u = ((unsigned)s) << 16;
    return __builtin_bit_cast(float, u);
}
__device__ __forceinline__ float gelu_erf(float x) {
    return 0.5f * x * (1.f + erff(x * 0.70710678118654752f));
}
// async global->LDS, 16B per lane; ldst must be wave-uniform base (HW adds lane*16)
__device__ __forceinline__ void gload_lds16(const u16* gsrc, u16* ldst) {
    __builtin_amdgcn_global_load_lds(
        (const __attribute__((address_space(1))) unsigned int*)gsrc,
        (__attribute__((address_space(3))) unsigned int*)ldst, 16, 0, 0);
}
// sum over each row of 16 lanes via DPP row_ror adds (full-rate VALU, no LDS pipe)
__device__ __forceinline__ float dpp_ror_add16(float x) {
    int t;
    t = __builtin_amdgcn_update_dpp(0, __builtin_bit_cast(int, x), 0x121, 0xf, 0xf, true);
    x += __builtin_bit_cast(float, t);
    t = __builtin_amdgcn_update_dpp(0, __builtin_bit_cast(int, x), 0x122, 0xf, 0xf, true);
    x += __builtin_bit_cast(float, t);
    t = __builtin_amdgcn_update_dpp(0, __builtin_bit_cast(int, x), 0x124, 0xf, 0xf, true);
    x += __builtin_bit_cast(float, t);
    t = __builtin_amdgcn_update_dpp(0, __builtin_bit_cast(int, x), 0x128, 0xf, 0xf, true);
    x += __builtin_bit_cast(float, t);
    return x;
}
// unpack 8 bf16 (uint4) -> 8 f32
__device__ __forceinline__ void unpack8(uint4 u, float* x) {
    x[0] = __builtin_bit_cast(float, u.x << 16);
    x[1] = __builtin_bit_cast(float, u.x & 0xffff0000u);
    x[2] = __builtin_bit_cast(float, u.y << 16);
    x[3] = __builtin_bit_cast(float, u.y & 0xffff0000u);
    x[4] = __builtin_bit_cast(float, u.z << 16);
    x[5] = __builtin_bit_cast(float, u.z & 0xffff0000u);
    x[6] = __builtin_bit_cast(float, u.w << 16);
    x[7] = __builtin_bit_cast(float, u.w & 0xffff0000u);
}

// ---------------- cast fp32 -> bf16 (vector4) ----------------
__global__ void cast_f2b(const float* __restrict__ src, u16* __restrict__ dst, int n4) {
    int i = blockIdx.x * blockDim.x + threadIdx.x;
    if (i >= n4) return;
    float4 v = ((const float4*)src)[i];
    ushort4 o;
    o.x = f2bf(v.x); o.y = f2bf(v.y); o.z = f2bf(v.z); o.w = f2bf(v.w);
    ((ushort4*)dst)[i] = o;
}

// ---------------- CSR build (by dst) ----------------
__global__ void csr_count(const int* __restrict__ ei, int* __restrict__ cnt) {
    int e = blockIdx.x * 256 + threadIdx.x;
    if (e >= kET) return;
    int d = (e < kE) ? ei[kE + e] : (e - kE);
    atomicAdd(cnt + d, 1);
}

__global__ __launch_bounds__(1024) void csr_scan(int* __restrict__ cnt_cur, int* __restrict__ off) {
    __shared__ int lds[1024];
    int t = threadIdx.x;
    int c[4], s = 0;
#pragma unroll
    for (int j = 0; j < 4; ++j) { c[j] = cnt_cur[t * 4 + j]; s += c[j]; }
    lds[t] = s;
    __syncthreads();
    for (int d = 1; d < 1024; d <<= 1) {
        int v = (t >= d) ? lds[t - d] : 0;
        __syncthreads();
        lds[t] += v;
        __syncthreads();
    }
    int excl = lds[t] - s;
#pragma unroll
    for (int j = 0; j < 4; ++j) { off[t * 4 + j] = excl; cnt_cur[t * 4 + j] = excl; excl += c[j]; }
    if (t == 1023) off[4096] = excl;
}

__global__ void csr_scatter(const int* __restrict__ ei, int* __restrict__ cur, int* __restrict__ csrc) {
    int e = blockIdx.x * 256 + threadIdx.x;
    if (e >= kET) return;
    int s, d;
    if (e < kE) { s = ei[e]; d = ei[kE + e]; } else { s = d = e - kE; }
    int pos = atomicAdd(cur + d, 1);
    csrc[pos] = s;
}

// ---------------- staged bf16 MFMA GEMM: C[M,N] = act(A[M,K] @ W[N,K]^T + bias) ----
// block 256 = 4 waves (2x2); block tile BM x 64; LDS double-buffered via
// global_load_lds (BK=32). Fragment reads are contiguous 1KB regions per
// instruction -> bank-conflict-free with linear (unswizzled) staging.
template <int BM, int K, int ACT, int WF32, int WBF16>
__global__ __launch_bounds__(256) void gemm_st(
    const u16* __restrict__ A, const u16* __restrict__ W,
    const float* __restrict__ bias, float* __restrict__ Cf,
    u16* __restrict__ Cb, int N) {
    constexpr int BK = 32;
    constexpr int NK = K / BK;
    constexpr int MF = BM / 32;          // A fragments per wave
    int tid = threadIdx.x;
    int w = tid >> 6, lane = tid & 63;
    int wr = w >> 1, wc = w & 1;
    int g = lane >> 4, r = lane & 15;
    int bm = blockIdx.y * BM;
    int bn = blockIdx.x * 64;
    __shared__ __align__(16) u16 Ab[2][BM * BK];
    __shared__ __align__(16) u16 Bb[2][64 * BK];
    // staging: wave w covers rows [i*64 + w*16, +16): lane -> row w*16+(lane>>2), chunk lane&3
    int srow = w * 16 + (lane >> 2);
    int scol = (lane & 3) * 8;
    auto stage = [&](int buf, int k0) {
#pragma unroll
        for (int i = 0; i < BM / 64; ++i)
            gload_lds16(A + (size_t)(bm + i * 64 + srow) * K + k0 + scol,
                        &Ab[buf][(i * 64 + w * 16) * BK]);
        gload_lds16(W + (size_t)(bn + srow) * K + k0 + scol, &Bb[buf][w * 16 * BK]);
    };
    f32x4 acc[MF][2] = {};
    stage(0, 0);
    __syncthreads();
    for (int st = 0; st < NK; ++st) {
        int cur = st & 1;
        if (st + 1 < NK) stage(cur ^ 1, (st + 1) * BK);
        const u16* Al = &Ab[cur][0];
        const u16* Bl = &Bb[cur][0];
        bf16x8 bf[2];
#pragma unroll
        for (int u = 0; u < 2; ++u)
            bf[u] = *(const bf16x8*)(Bl + (wc * 32 + u * 16 + r) * BK + g * 8);
#pragma unroll
        for (int t = 0; t < MF; ++t) {
            bf16x8 af = *(const bf16x8*)(Al + (wr * (BM / 2) + t * 16 + r) * BK + g * 8);
#pragma unroll
            for (int u = 0; u < 2; ++u)
                acc[t][u] = __builtin_amdgcn_mfma_f32_16x16x32_bf16(af, bf[u], acc[t][u], 0, 0, 0);
        }
        __syncthreads();   // vmcnt(0): next buffer staged; lgkm: reads of cur done
    }
    int r0 = bm + wr * (BM / 2) + g * 4;
    int c0 = bn + wc * 32 + r;
#pragma unroll
    for (int t = 0; t < MF; ++t)
#pragma unroll
        for (int u = 0; u < 2; ++u)
#pragma unroll
            for (int e = 0; e < 4; ++e) {
                int row = r0 + t * 16 + e, col = c0 + u * 16;
                float v = acc[t][u][e];
                if (bias) v += bias[col];
                if (ACT == 1) v = gelu_erf(v);
                if (WF32) Cf[(size_t)row * N + col] = v;
                if (WBF16) Cb[(size_t)row * N + col] = f2bf(v);
            }
}

// ---------------- LayerNorm(h + add) -> h (fp32) and h_bf (bf16); wave per row ----------------
__global__ __launch_bounds__(256) void ln_res(
    const float* hin, const float* add,
    const float* __restrict__ g, const float* __restrict__ b,
    float* hout, u16* __restrict__ hbf) {
    int row = blockIdx.x * 4 + (threadIdx.x >> 6);
    int lane = threadIdx.x & 63;
    const float4 x4 = *(const float4*)(hin + (size_t)row * kC + lane * 4);
    const float4 a4 = *(const float4*)(add + (size_t)row * kC + lane * 4);
    float v[4] = {x4.x + a4.x, x4.y + a4.y, x4.z + a4.z, x4.w + a4.w};
    float s = v[0] + v[1] + v[2] + v[3];
    for (int d = 1; d < 64; d <<= 1) s += __shfl_xor(s, d);
    float mu = s * (1.f / kC);
    float q = 0.f;
#pragma unroll
    for (int j = 0; j < 4; ++j) { float d = v[j] - mu; q += d * d; }
    for (int d = 1; d < 64; d <<= 1) q += __shfl_xor(q, d);
    float rstd = rsqrtf(q * (1.f / kC) + 1e-5f);
    const float4 g4 = *(const float4*)(g + lane * 4);
    const float4 b4 = *(const float4*)(b + lane * 4);
    float y0 = (v[0] - mu) * rstd * g4.x + b4.x;
    float y1 = (v[1] - mu) * rstd * g4.y + b4.y;
    float y2 = (v[2] - mu) * rstd * g4.z + b4.z;
    float y3 = (v[3] - mu) * rstd * g4.w + b4.w;
    *(float4*)(hout + (size_t)row * kC + lane * 4) = make_float4(y0, y1, y2, y3);
    ushort4 o; o.x = f2bf(y0); o.y = f2bf(y1); o.z = f2bf(y2); o.w = f2bf(y3);
    *(ushort4*)(hbf + (size_t)row * kC + lane * 4) = o;
}

// ---------------- GATv2: per-node online softmax aggregation + fused residual LN ----
// xg: fused [4096][2048] bf16 (cols 0..1023 = xl transform, 1024..2047 = xr).
// Block = node, wave = head; 4 quarters/wave each process their own edge
// (16 channels/lane); 2-deep edge prefetch hides the L2 gather latency.
// leaky(e) = 0.6e + 0.4|e|; DPP row_ror reduce; 4-way LSE merge.
// Epilogue: h = LN(h + local + gb) written as fp32 h and bf16 hbf (replaces ln1).
__global__ __launch_bounds__(256) void gat_agg(
    const u16* __restrict__ xg,
    const float* __restrict__ att, const float* __restrict__ gb,
    const int* __restrict__ off, const int* __restrict__ srcs,
    const float* __restrict__ lng, const float* __restrict__ lnb,
    float* __restrict__ h, u16* __restrict__ hbf) {
    int n = blockIdx.x;
    int w = threadIdx.x >> 6, lane = threadIdx.x & 63;
    int q = lane >> 4, t = lane & 15;
    int cb = w * 256 + t * 16;   // channel slice [cb, cb+16) of 1024

    uint4 xru0 = *(const uint4*)(xg + (size_t)n * 2048 + 1024 + cb);
    uint4 xru1 = *(const uint4*)(xg + (size_t)n * 2048 + 1024 + cb + 8);
    float xrv[16];
    unpack8(xru0, xrv); unpack8(xru1, xrv + 8);
    float att6[16], att4[16];
#pragma unroll
    for (int j = 0; j < 16; j += 4) {
        float4 a4 = *(const float4*)(att + cb + j);
        att6[j] = 0.6f * a4.x; att6[j + 1] = 0.6f * a4.y;
        att6[j + 2] = 0.6f * a4.z; att6[j + 3] = 0.6f * a4.w;
        att4[j] = (2.f / 3.f) * att6[j]; att4[j + 1] = (2.f / 3.f) * att6[j + 1];
        att4[j + 2] = (2.f / 3.f) * att6[j + 2]; att4[j + 3] = (2.f / 3.f) * att6[j + 3];
    }

    int i0 = off[n], i1 = off[n + 1];
    float m = -1e30f, ls = 0.f;
    float acc[16] = {};
    int i = i0 + q;
    uint4 p0a, p1a, p0b, p1b;
    if (i < i1) {
        int s = srcs[i];
        p0a = *(const uint4*)(xg + (size_t)s * 2048 + cb);
        p1a = *(const uint4*)(xg + (size_t)s * 2048 + cb + 8);
    }
    if (i + 4 < i1) {
        int s = srcs[i + 4];
        p0b = *(const uint4*)(xg + (size_t)s * 2048 + cb);
        p1b = *(const uint4*)(xg + (size_t)s * 2048 + cb + 8);
    }
    while (i < i1) {
        uint4 c0 = p0a, c1 = p1a;
        p0a = p0b; p1a = p1b;
        if (i + 8 < i1) {
            int s2 = srcs[i + 8];
            p0b = *(const uint4*)(xg + (size_t)s2 * 2048 + cb);
            p1b = *(const uint4*)(xg + (size_t)s2 * 2048 + cb + 8);
        }
        float x[16];
        unpack8(c0, x); unpack8(c1, x + 8);
        float p = 0.f;
#pragma unroll
        for (int j = 0; j < 16; ++j) {
            float e = x[j] + xrv[j];
            p = fmaf(att6[j], e, p);
            p = fmaf(att4[j], __builtin_fabsf(e), p);
        }
        p = dpp_ror_add16(p);   // all 16 lanes of the quarter now hold the score
        if (p > m) {            // quarter-uniform; divergence between quarters is rare
            float c = __expf(m - p);
            ls = ls * c + 1.f;
#pragma unroll
            for (int j = 0; j < 16; ++j) acc[j] = acc[j] * c + x[j];
            m = p;
        } else {
            float pw = __expf(p - m);
            ls += pw;
#pragma unroll
            for (int j = 0; j < 16; ++j) acc[j] = fmaf(pw, x[j], acc[j]);
        }
        i += 4;
    }
    // exact LSE merge of the 4 quarter states (quarter index = lane bits 4..5)
    float mm = fmaxf(m, __shfl_xor(m, 16));
    mm = fmaxf(mm, __shfl_xor(mm, 32));
    float c = __expf(m - mm);   // 0 for empty quarters (m = -1e30)
    ls *= c;
    ls += __shfl_xor(ls, 16);
    ls += __shfl_xor(ls, 32);
#pragma unroll
    for (int j = 0; j < 16; ++j) {
        float a = acc[j] * c;
        a += __shfl_xor(a, 16);
        a += __shfl_xor(a, 32);
        acc[j] = a;
    }
    float inv = 1.f / ls;
    __shared__ float red[4][256];
    __shared__ float rs[8];
    if (q == 0) {
#pragma unroll
        for (int j = 0; j < 16; ++j) red[w][t * 16 + j] = acc[j] * inv;
    }
    __syncthreads();
    int cc = threadIdx.x;
    float vsum = 0.25f * (red[0][cc] + red[1][cc] + red[2][cc] + red[3][cc]) + gb[cc];
    // fused residual + LayerNorm over the block's 256 channels
    float v = h[(size_t)n * kC + cc] + vsum;
    float s1 = v, s2 = v * v;
    for (int d = 1; d < 64; d <<= 1) { s1 += __shfl_xor(s1, d); s2 += __shfl_xor(s2, d); }
    if (lane == 0) { rs[w] = s1; rs[4 + w] = s2; }
    __syncthreads();
    s1 = rs[0] + rs[1] + rs[2] + rs[3];
    s2 = rs[4] + rs[5] + rs[6] + rs[7];
    float mu = s1 * (1.f / kC);
    float rstd = rsqrtf(s2 * (1.f / kC) - mu * mu + 1e-5f);
    float y = (v - mu) * rstd * lng[cc] + lnb[cc];
    h[(size_t)n * kC + cc] = y;
    hbf[(size_t)n * kC + cc] = f2bf(y);
}

// ---------------- qkv repack: qkvb bf16 [4096][768] -> Qb/Kb [4][4096][64], VTb [4][64][4096]
// Q scaled by 1/sqrt(64) * log2(e) so attention can use exp2 directly.
__global__ __launch_bounds__(256) void qkv_repack(
    const u16* __restrict__ qkvb, u16* __restrict__ Qb, u16* __restrict__ Kb,
    u16* __restrict__ VTb) {
    int h = blockIdx.y;
    int n0 = blockIdx.x * 64;
    int t = threadIdx.x;
    int nr = t >> 2, cb = (t & 3) * 16;
    const u16* src = qkvb + (size_t)(n0 + nr) * 768 + h * 64 + cb;
    u16* qd = Qb + ((size_t)h * kN + n0 + nr) * 64 + cb;
    u16* kd = Kb + ((size_t)h * kN + n0 + nr) * 64 + cb;
    __shared__ u16 lds[64][72];
    constexpr float QS = 0.125f * 1.4426950408889634f;  // 1/sqrt(DH) * log2(e)
#pragma unroll
    for (int j = 0; j < 16; j += 4) {
        ushort4 q4 = *(const ushort4*)(src + j);
        ushort4 k4 = *(const ushort4*)(src + 256 + j);
        ushort4 v4 = *(const ushort4*)(src + 512 + j);
        ushort4 qo;
        qo.x = f2bf(bf2f(q4.x) * QS); qo.y = f2bf(bf2f(q4.y) * QS);
        qo.z = f2bf(bf2f(q4.z) * QS); qo.w = f2bf(bf2f(q4.w) * QS);
        *(ushort4*)(qd + j) = qo;
        *(ushort4*)(kd + j) = k4;
        *(ushort4*)(&lds[nr][cb + j]) = v4;
    }
    __syncthreads();
    int d = t >> 2, nb = (t & 3) * 16;
    u16* vd = VTb + ((size_t)h * 64 + d) * kN + n0 + nb;
#pragma unroll
    for (int j = 0; j < 16; j += 4) {
        ushort4 vo;
        vo.x = lds[nb + j + 0][d];
        vo.y = lds[nb + j + 1][d];
        vo.z = lds[nb + j + 2][d];
        vo.w = lds[nb + j + 3][d];
        *(ushort4*)(vd + j) = vo;
    }
}

// ---------------- MFMA flash attention, LDS-shared K/V, split-K ----------------
// Block = 4 waves, 64 q rows (16/wave). Grid (kN/64, heads, NSPLIT).
// K and VT 64x64 tiles double-buffered in LDS via global_load_lds with XOR-swizzled
// source (chunk ^= row&7); plds uses the SAME chunk swizzle (c ^= r&7) so the
// P C->A roundtrip is bank-conflict-free. Defer-max: the O-rescale block is
// skipped entirely (wave vote) when no q-row's max increased this step (exact).
// Writes unnormalized partial O + (m,l) per split; mha_merge recombines (LSE merge).
__global__ __launch_bounds__(256, 4) void mha_mfma2(
    const u16* __restrict__ Qb, const u16* __restrict__ Kb,
    const u16* __restrict__ VTb, float* __restrict__ opart, float* __restrict__ mlpart) {
    int qt = blockIdx.x, head = blockIdx.y, sp = blockIdx.z;
    int tid = threadIdx.x;
    int w = tid >> 6, lane = tid & 63;
    int g = lane >> 4, r = lane & 15;
    int q0 = qt * 64;
    const u16* Qh = Qb + ((size_t)head * kN + q0 + w * 16) * 64;
    const u16* Kh = Kb + (size_t)head * kN * 64;
    const u16* VTh = VTb + (size_t)head * 64 * kN;
    __shared__ u16 Kt[2][64 * 64];
    __shared__ u16 Vt[2][64 * 64];
    __shared__ u16 plds[4][16 * 64];
    int srow = w * 8 + (lane >> 3);
    int schunk = ((lane & 7) ^ ((lane >> 3) & 7)) * 8;   // element offset within row
    int kbase = sp * KSPAN;

    bf16x8 qf0 = *(const bf16x8*)(Qh + r * 64 + g * 8);
    bf16x8 qf1 = *(const bf16x8*)(Qh + r * 64 + 32 + g * 8);

    auto stage = [&](int buf, int k0) {
#pragma unroll
        for (int i = 0; i < 2; ++i) {
            int row = i * 32 + srow;
            gload_lds16(Kh + (size_t)(k0 + row) * 64 + schunk, &Kt[buf][(i * 32 + w * 8) * 64]);
            gload_lds16(VTh + (size_t)row * kN + k0 + schunk, &Vt[buf][(i * 32 + w * 8) * 64]);
        }
    };

    f32x4 o[4] = {};
    float m = -3.0e38f, l = 0.f;

    stage(0, kbase);
    __syncthreads();   // vmcnt(0) drain + barrier: buffer 0 ready

    int rx = r & 7;
    for (int st = 0; st < NSTEP; ++st) {
        int cur = st & 1;
        if (st + 1 < NSTEP) stage(cur ^ 1, kbase + (st + 1) * 64);
        const u16* Kl = &Kt[cur][0];
        const u16* Vl = &Vt[cur][0];
        // S^T tiles: rows = keys (16t + 4g + reg), cols = q (r)
        f32x4 stt[4] = {};
#pragma unroll
        for (int t = 0; t < 4; ++t) {
            bf16x8 kf0 = *(const bf16x8*)(Kl + (16 * t + r) * 64 + ((0 + g) ^ rx) * 8);
            bf16x8 kf1 = *(const bf16x8*)(Kl + (16 * t + r) * 64 + ((4 + g) ^ rx) * 8);
            stt[t] = __builtin_amdgcn_mfma_f32_16x16x32_bf16(kf0, qf0, stt[t], 0, 0, 0);
            stt[t] = __builtin_amdgcn_mfma_f32_16x16x32_bf16(kf1, qf1, stt[t], 0, 0, 0);
        }
        // online softmax (exp2 domain), state per q=r (replicated across g groups)
        float pm = stt[0][0];
#pragma unroll
        for (int t = 0; t < 4; ++t)
#pragma unroll
            for (int e = 0; e < 4; ++e) pm = fmaxf(pm, stt[t][e]);
        pm = fmaxf(pm, __shfl_xor(pm, 16));
        pm = fmaxf(pm, __shfl_xor(pm, 32));
        // defer-max: rescale only when some q-row's max increased (wave-uniform vote)
        if (__any(pm > m)) {
            float mn = fmaxf(m, pm);
            float corr = __builtin_amdgcn_exp2f(m - mn);
            l *= corr;
            float corrq[4];
#pragma unroll
            for (int e = 0; e < 4; ++e) corrq[e] = __shfl(corr, g * 4 + e);
#pragma unroll
            for (int dt = 0; dt < 4; ++dt)
#pragma unroll
                for (int e = 0; e < 4; ++e) o[dt][e] *= corrq[e];
            m = mn;
        }
        float ls = 0.f;
        float p[4][4];
#pragma unroll
        for (int t = 0; t < 4; ++t)
#pragma unroll
            for (int e = 0; e < 4; ++e) { p[t][e] = __builtin_amdgcn_exp2f(stt[t][e] - m); ls += p[t][e]; }
        ls += __shfl_xor(ls, 16);
        ls += __shfl_xor(ls, 32);
        l += ls;
        // P: C-layout -> LDS -> A-layout. plds chunk-swizzled by q-row (c ^= r&7)
#pragma unroll
        for (int t = 0; t < 4; ++t) {
            ushort4 pk;
            pk.x = f2bf(p[t][0]); pk.y = f2bf(p[t][1]);
            pk.z = f2bf(p[t][2]); pk.w = f2bf(p[t][3]);
            int lc = (2 * t + (g >> 1)) ^ rx;
            *(ushort4*)(&plds[w][r * 64 + lc * 8 + (g & 1) * 4]) = pk;
        }
        bf16x8 pa0 = *(const bf16x8*)(&plds[w][r * 64 + (g ^ rx) * 8]);
        bf16x8 pa1 = *(const bf16x8*)(&plds[w][r * 64 + ((4 + g) ^ rx) * 8]);
#pragma unroll
        for (int dt = 0; dt < 4; ++dt) {
            bf16x8 vf0 = *(const bf16x8*)(Vl + (dt * 16 + r) * 64 + ((0 + g) ^ rx) * 8);
            bf16x8 vf1 = *(const bf16x8*)(Vl + (dt * 16 + r) * 64 + ((4 + g) ^ rx) * 8);
            o[dt] = __builtin_amdgcn_mfma_f32_16x16x32_bf16(pa0, vf0, o[dt], 0, 0, 0);
            o[dt] = __builtin_amdgcn_mfma_f32_16x16x32_bf16(pa1, vf1, o[dt], 0, 0, 0);
        }
        __syncthreads();   // vmcnt(0): next buffer staged; lgkmcnt: all reads of cur done
    }

    // store unnormalized partials
    size_t slot = (size_t)(head * 64 + qt) * NSPLIT + sp;
    float* ob = opart + slot * 4096;
#pragma unroll
    for (int dt = 0; dt < 4; ++dt)
#pragma unroll
        for (int e = 0; e < 4; ++e)
            ob[(w * 16 + g * 4 + e) * 64 + dt * 16 + r] = o[dt][e];
    float* mlb = mlpart + slot * 128;
    if (g == 0) { mlb[w * 16 + r] = m; mlb[64 + w * 16 + r] = l; }
}

// ---------------- merge split-K attention partials -> attnb (bf16) ----------------
// grid (kN/4, heads), block 256: wave w = one q row, lane = d (0..63)
__global__ __launch_bounds__(256) void mha_merge(
    const float* __restrict__ opart, const float* __restrict__ mlpart,
    u16* __restrict__ attnb) {
    int head = blockIdx.y;
    int q = blockIdx.x * 4 + (threadIdx.x >> 6);
    int d = threadIdx.x & 63;
    int qt = q >> 6, ql = q & 63;
    size_t sb = (size_t)(head * 64 + qt) * NSPLIT;
    float ms[NSPLIT], lsv[NSPLIT];
    float mstar = -3.0e38f;
#pragma unroll
    for (int s = 0; s < NSPLIT; ++s) {
        ms[s] = mlpart[(sb + s) * 128 + ql];
        lsv[s] = mlpart[(sb + s) * 128 + 64 + ql];
        mstar = fmaxf(mstar, ms[s]);
    }
    float acc = 0.f, lsum = 0.f;
#pragma unroll
    for (int s = 0; s < NSPLIT; ++s) {
        float wgt = __builtin_amdgcn_exp2f(ms[s] - mstar);
        lsum += lsv[s] * wgt;
        acc += opart[(sb + s) * 4096 + ql * 64 + d] * wgt;
    }
    attnb[(size_t)q * kC + head * 64 + d] = f2bf(acc / lsum);
}

// ---------------- final: out[4096,2] = t_bf @ out_w2^T + b2; wave per row ----------------
__global__ __launch_bounds__(256) void final_out(
    const u16* __restrict__ tbf, const float* __restrict__ w2,
    const float* __restrict__ b2, float* __restrict__ out) {
    int row = blockIdx.x * 4 + (threadIdx.x >> 6);
    int lane = threadIdx.x & 63;
    const ushort4 tv = *(const ushort4*)(tbf + (size_t)row * 256 + lane * 4);
    float t0 = bf2f(tv.x), t1 = bf2f(tv.y), t2 = bf2f(tv.z), t3 = bf2f(tv.w);
    const float4 w0 = *(const float4*)(w2 + lane * 4);
    const float4 w1 = *(const float4*)(w2 + 256 + lane * 4);
    float d0 = t0 * w0.x + t1 * w0.y + t2 * w0.z + t3 * w0.w;
    float d1 = t0 * w1.x + t1 * w1.y + t2 * w1.z + t3 * w1.w;
    for (int d = 1; d < 64; d <<= 1) { d0 += __shfl_xor(d0, d); d1 += __shfl_xor(d1, d); }
    if (lane == 0) {
        out[(size_t)row * 2 + 0] = d0 + b2[0];
        out[(size_t)row * 2 + 1] = d1 + b2[1];
    }
}

extern "C" void kernel_launch(void* const* d_in, const int* in_sizes, int n_in,
                              void* d_out, int out_size, void* d_ws, size_t ws_size,
                              hipStream_t stream) {
    (void)in_sizes; (void)n_in; (void)out_size;
    const float* x        = (const float*)d_in[0];
    const int*   ei       = (const int*)d_in[1];
    const float* in_w     = (const float*)d_in[2];
    const float* in_b     = (const float*)d_in[3];
    const float* gat_wl   = (const float*)d_in[4];
    const float* gat_wr   = (const float*)d_in[5];
    const float* gat_att  = (const float*)d_in[6];
    const float* gat_b    = (const float*)d_in[7];
    const float* mha_in_w = (const float*)d_in[8];
    const float* mha_in_b = (const float*)d_in[9];
    const float* mha_out_w= (const float*)d_in[10];
    const float* mha_out_b= (const float*)d_in[11];
    const float* ln1_g = (const float*)d_in[12];
    const float* ln1_b = (const float*)d_in[13];
    const float* ln2_g = (const float*)d_in[14];
    const float* ln2_b = (const float*)d_in[15];
    const float* ln3_g = (const float*)d_in[16];
    const float* ln3_b = (const float*)d_in[17];
    const float* ffn_w1 = (const float*)d_in[18];
    const float* ffn_b1 = (const float*)d_in[19];
    const float* ffn_w2 = (const float*)d_in[20];
    const float* ffn_b2 = (const float*)d_in[21];
    const float* out_w1 = (const float*)d_in[22];
    const float* out_b1 = (const float*)d_in[23];
    const float* out_w2 = (const float*)d_in[24];
    const float* out_b2 = (const float*)d_in[25];
    float* out = (float*)d_out;

    char* ws = (char*)d_ws;
    size_t off = 0;
    auto alloc = [&](size_t bytes) -> void* {
        void* p = (void*)(ws + off);
        off += (bytes + 255) & ~(size_t)255;
        return p;
    };
    float* h     = (float*)alloc((size_t)kN * kC * 4);
    u16*   hbf   = (u16*)  alloc((size_t)kN * kC * 2);
    float* xlb   = (float*)alloc((size_t)kN * 1024 * 4);   // slot reused: xgbf / Qb+Kb+VTb
    float* xrb   = (float*)alloc((size_t)kN * 1024 * 4);   // slot reused: opart
    float* qkv   = (float*)alloc((size_t)kN * 768 * 4);    // slot reused: qkvb (bf16)
    float* locb  = (float*)alloc((size_t)kN * kC * 4);
    u16*   attnb = (u16*)  alloc((size_t)kN * kC * 2);
    u16*   midb  = (u16*)  alloc((size_t)kN * 512 * 2);
    u16*   tbf   = (u16*)  alloc((size_t)kN * kC * 2);
    u16*   xbf   = (u16*)  alloc((size_t)kN * kIn * 2);
    u16*   wbf   = (u16*)  alloc((size_t)3342336 * 2);
    int*   coff  = (int*)  alloc((size_t)4097 * 4);
    int*   ccur  = (int*)  alloc((size_t)4096 * 4);
    int*   csrc  = (int*)  alloc((size_t)kET * 4);
    if (ws_size < off) return;  // not enough scratch: bail loudly (output stays poisoned)

    // Fused GAT transform output [4096][2048] bf16 (cols 0..1023 = xl, 1024.. = xr)
    // = exactly the 16 MB xlb slot.
    u16* xgbf = (u16*)xlb;
    // MHA attention operands: alias the same slot (xgbf dead after gat_agg).
    u16* Qb  = (u16*)xlb;                       // [4][4096][64]
    u16* Kb  = Qb + (size_t)4 * kN * 64;        // [4][4096][64]
    u16* VTb = Kb + (size_t)4 * kN * 64;        // [4][64][4096]
    u16* qkvb = (u16*)qkv;                      // [4096][768] bf16
    float* opart  = xrb;                        // 1024 slots x 4096 f32 = 16 MB exact
    float* mlpart = locb;                       // dead between gat_agg and the mout GEMM

    // bf16 weight buffer offsets (elements); gat wl/wr interleaved per layer [2048][256]
    const size_t OFF_INW  = 0;
    const size_t OFF_GAT  = 131072;
    const size_t OFF_MIN  = 1703936;
    const size_t OFF_MOUT = 2293760;
    const size_t OFF_F1   = 2490368;
    const size_t OFF_F2   = 2883584;
    const size_t OFF_O1   = 3276800;

    auto cast = [&](const float* s, u16* d, int n) {
        int n4 = n >> 2;
        cast_f2b<<<dim3((n4 + 255) / 256), dim3(256), 0, stream>>>(s, d, n4);
    };
    cast(x, xbf, kN * kIn);
    cast(in_w, wbf + OFF_INW, kC * kIn);
    for (int l = 0; l < kL; ++l) {
        cast(gat_wl + (size_t)l * 262144, wbf + OFF_GAT + (size_t)l * 524288, 262144);
        cast(gat_wr + (size_t)l * 262144, wbf + OFF_GAT + (size_t)l * 524288 + 262144, 262144);
    }
    cast(mha_in_w, wbf + OFF_MIN, kL * 768 * kC);
    cast(mha_out_w, wbf + OFF_MOUT, kL * kC * kC);
    cast(ffn_w1, wbf + OFF_F1, kL * 512 * kC);
    cast(ffn_w2, wbf + OFF_F2, kL * kC * 512);
    cast(out_w1, wbf + OFF_O1, kC * kC);

    // CSR build (once per launch; same graph for all layers)
    hipMemsetAsync(ccur, 0, 4096 * 4, stream);
    csr_count<<<dim3((kET + 255) / 256), dim3(256), 0, stream>>>(ei, ccur);
    csr_scan<<<dim3(1), dim3(1024), 0, stream>>>(ccur, coff);
    csr_scatter<<<dim3((kET + 255) / 256), dim3(256), 0, stream>>>(ei, ccur, csrc);

    // input projection: h = x @ in_w^T + in_b  (fp32 + bf16 outputs)
    gemm_st<64, 512, 0, 1, 1><<<dim3(kC / 64, kN / 64), dim3(256), 0, stream>>>(
        xbf, wbf + OFF_INW, in_b, h, hbf, kC);

    for (int l = 0; l < kL; ++l) {
        // GATv2 transforms: fused wl|wr GEMM -> xgbf [4096][2048]
        gemm_st<128, 256, 0, 0, 1><<<dim3(2048 / 64, kN / 128), dim3(256), 0, stream>>>(
            hbf, wbf + OFF_GAT + (size_t)l * 524288, nullptr, nullptr, xgbf, 2048);
        // gat_agg with fused residual + ln1 (writes h, hbf directly)
        gat_agg<<<dim3(kN), dim3(256), 0, stream>>>(
            xgbf, gat_att + (size_t)l * 1024, gat_b + (size_t)l * kC, coff, csrc,
            ln1_g + (size_t)l * kC, ln1_b + (size_t)l * kC, h, hbf);

        // MHA
        gemm_st<128, 256, 0, 0, 1><<<dim3(768 / 64, kN / 128), dim3(256), 0, stream>>>(
            hbf, wbf + OFF_MIN + (size_t)l * 768 * kC, mha_in_b + (size_t)l * 768, nullptr, qkvb, 768);
        qkv_repack<<<dim3(kN / 64, 4), dim3(256), 0, stream>>>(qkvb, Qb, Kb, VTb);
        mha_mfma2<<<dim3(kN / 64, 4, NSPLIT), dim3(256), 0, stream>>>(Qb, Kb, VTb, opart, mlpart);
        mha_merge<<<dim3(kN / 4, 4), dim3(256), 0, stream>>>(opart, mlpart, attnb);
        gemm_st<64, 256, 0, 1, 0><<<dim3(kC / 64, kN / 64), dim3(256), 0, stream>>>(
            attnb, wbf + OFF_MOUT + (size_t)l * kC * kC, mha_out_b + (size_t)l * kC, locb, nullptr, kC);
        ln_res<<<dim3(kN / 4), dim3(256), 0, stream>>>(
            h, locb, ln2_g + (size_t)l * kC, ln2_b + (size_t)l * kC, h, hbf);

        // FFN
        gemm_st<64, 256, 1, 0, 1><<<dim3(512 / 64, kN / 64), dim3(256), 0, stream>>>(
            hbf, wbf + OFF_F1 + (size_t)l * 512 * kC, ffn_b1 + (size_t)l * 512, nullptr, midb, 512);
        gemm_st<64, 512, 0, 1, 0><<<dim3(kC / 64, kN / 64), dim3(256), 0, stream>>>(
            midb, wbf + OFF_F2 + (size_t)l * kC * 512, ffn_b2 + (size_t)l * kC, locb, nullptr, kC);
        ln_res<<<dim3(kN / 4), dim3(256), 0, stream>>>(
            h, locb, ln3_g + (size_t)l * kC, ln3_b + (size_t)l * kC, h, hbf);
    }

    // output head
    gemm_st<64, 256, 1, 0, 1><<<dim3(kC / 64, kN / 64), dim3(256), 0, stream>>>(
        hbf, wbf + OFF_O1, out_b1, nullptr, tbf, kC);
    final_out<<<dim3(kN / 4), dim3(256), 0, stream>>>(tbf, out_w2, out_b2, out);
}

// Round 11
// 522.265 us; speedup vs baseline: 9.2259x; 1.0129x over previous
//
#include <hip/hip_runtime.h>
#include <cstdint>
#include <cstddef>

typedef unsigned short u16;
typedef __bf16 bf16x8 __attribute__((ext_vector_type(8)));
typedef float f32x4 __attribute__((ext_vector_type(4)));

constexpr int kN  = 4096;
constexpr int kE  = 131072;
constexpr int kET = kE + kN;   // with self loops
constexpr int kIn = 512;
constexpr int kC  = 256;
constexpr int kL  = 3;

constexpr int NSPLIT = 4;
constexpr int KSPAN  = kN / NSPLIT;  // 1024 keys per split
constexpr int NSTEP  = KSPAN / 64;   // 16 steps of 64 keys

__device__ __forceinline__ u16 f2bf(float f) {
    unsigned u = __builtin_bit_cast(unsigned, f);
    u += 0x7fffu + ((u >> 16) & 1u);
    return (u16)(u >> 16);
}
__device__ __forceinline__ float bf2f(u16 s) {
    unsigned u = ((unsigned)s) << 16;
    return __builtin_bit_cast(float, u);
}
__device__ __forceinline__ float gelu_erf(float x) {
    return 0.5f * x * (1.f + erff(x * 0.70710678118654752f));
}
// async global->LDS, 16B per lane; ldst must be wave-uniform base (HW adds lane*16)
__device__ __forceinline__ void gload_lds16(const u16* gsrc, u16* ldst) {
    __builtin_amdgcn_global_load_lds(
        (const __attribute__((address_space(1))) unsigned int*)gsrc,
        (__attribute__((address_space(3))) unsigned int*)ldst, 16, 0, 0);
}
// sum over each row of 16 lanes via DPP row_ror adds (full-rate VALU, no LDS pipe)
__device__ __forceinline__ float dpp_ror_add16(float x) {
    int t;
    t = __builtin_amdgcn_update_dpp(0, __builtin_bit_cast(int, x), 0x121, 0xf, 0xf, true);
    x += __builtin_bit_cast(float, t);
    t = __builtin_amdgcn_update_dpp(0, __builtin_bit_cast(int, x), 0x122, 0xf, 0xf, true);
    x += __builtin_bit_cast(float, t);
    t = __builtin_amdgcn_update_dpp(0, __builtin_bit_cast(int, x), 0x124, 0xf, 0xf, true);
    x += __builtin_bit_cast(float, t);
    t = __builtin_amdgcn_update_dpp(0, __builtin_bit_cast(int, x), 0x128, 0xf, 0xf, true);
    x += __builtin_bit_cast(float, t);
    return x;
}
// unpack 8 bf16 (uint4) -> 8 f32
__device__ __forceinline__ void unpack8(uint4 u, float* x) {
    x[0] = __builtin_bit_cast(float, u.x << 16);
    x[1] = __builtin_bit_cast(float, u.x & 0xffff0000u);
    x[2] = __builtin_bit_cast(float, u.y << 16);
    x[3] = __builtin_bit_cast(float, u.y & 0xffff0000u);
    x[4] = __builtin_bit_cast(float, u.z << 16);
    x[5] = __builtin_bit_cast(float, u.z & 0xffff0000u);
    x[6] = __builtin_bit_cast(float, u.w << 16);
    x[7] = __builtin_bit_cast(float, u.w & 0xffff0000u);
}

// ---------------- cast fp32 -> bf16 (vector4) ----------------
__global__ void cast_f2b(const float* __restrict__ src, u16* __restrict__ dst, int n4) {
    int i = blockIdx.x * blockDim.x + threadIdx.x;
    if (i >= n4) return;
    float4 v = ((const float4*)src)[i];
    ushort4 o;
    o.x = f2bf(v.x); o.y = f2bf(v.y); o.z = f2bf(v.z); o.w = f2bf(v.w);
    ((ushort4*)dst)[i] = o;
}

// ---------------- CSR build (by dst) ----------------
__global__ void csr_count(const int* __restrict__ ei, int* __restrict__ cnt) {
    int e = blockIdx.x * 256 + threadIdx.x;
    if (e >= kET) return;
    int d = (e < kE) ? ei[kE + e] : (e - kE);
    atomicAdd(cnt + d, 1);
}

__global__ __launch_bounds__(1024) void csr_scan(int* __restrict__ cnt_cur, int* __restrict__ off) {
    __shared__ int lds[1024];
    int t = threadIdx.x;
    int c[4], s = 0;
#pragma unroll
    for (int j = 0; j < 4; ++j) { c[j] = cnt_cur[t * 4 + j]; s += c[j]; }
    lds[t] = s;
    __syncthreads();
    for (int d = 1; d < 1024; d <<= 1) {
        int v = (t >= d) ? lds[t - d] : 0;
        __syncthreads();
        lds[t] += v;
        __syncthreads();
    }
    int excl = lds[t] - s;
#pragma unroll
    for (int j = 0; j < 4; ++j) { off[t * 4 + j] = excl; cnt_cur[t * 4 + j] = excl; excl += c[j]; }
    if (t == 1023) off[4096] = excl;
}

__global__ void csr_scatter(const int* __restrict__ ei, int* __restrict__ cur, int* __restrict__ csrc) {
    int e = blockIdx.x * 256 + threadIdx.x;
    if (e >= kET) return;
    int s, d;
    if (e < kE) { s = ei[e]; d = ei[kE + e]; } else { s = d = e - kE; }
    int pos = atomicAdd(cur + d, 1);
    csrc[pos] = s;
}

// ---------------- staged bf16 MFMA GEMM: C[M,N] = act(A[M,K] @ W[N,K]^T + bias) ----
// block 256 = 4 waves (2x2); block tile BM x 64; LDS double-buffered via
// global_load_lds (BK=32).
template <int BM, int K, int ACT, int WF32, int WBF16>
__global__ __launch_bounds__(256) void gemm_st(
    const u16* __restrict__ A, const u16* __restrict__ W,
    const float* __restrict__ bias, float* __restrict__ Cf,
    u16* __restrict__ Cb, int N) {
    constexpr int BK = 32;
    constexpr int NK = K / BK;
    constexpr int MF = BM / 32;          // A fragments per wave
    int tid = threadIdx.x;
    int w = tid >> 6, lane = tid & 63;
    int wr = w >> 1, wc = w & 1;
    int g = lane >> 4, r = lane & 15;
    int bm = blockIdx.y * BM;
    int bn = blockIdx.x * 64;
    __shared__ __align__(16) u16 Ab[2][BM * BK];
    __shared__ __align__(16) u16 Bb[2][64 * BK];
    int srow = w * 16 + (lane >> 2);
    int scol = (lane & 3) * 8;
    auto stage = [&](int buf, int k0) {
#pragma unroll
        for (int i = 0; i < BM / 64; ++i)
            gload_lds16(A + (size_t)(bm + i * 64 + srow) * K + k0 + scol,
                        &Ab[buf][(i * 64 + w * 16) * BK]);
        gload_lds16(W + (size_t)(bn + srow) * K + k0 + scol, &Bb[buf][w * 16 * BK]);
    };
    f32x4 acc[MF][2] = {};
    stage(0, 0);
    __syncthreads();
    for (int st = 0; st < NK; ++st) {
        int cur = st & 1;
        if (st + 1 < NK) stage(cur ^ 1, (st + 1) * BK);
        const u16* Al = &Ab[cur][0];
        const u16* Bl = &Bb[cur][0];
        bf16x8 bf[2];
#pragma unroll
        for (int u = 0; u < 2; ++u)
            bf[u] = *(const bf16x8*)(Bl + (wc * 32 + u * 16 + r) * BK + g * 8);
#pragma unroll
        for (int t = 0; t < MF; ++t) {
            bf16x8 af = *(const bf16x8*)(Al + (wr * (BM / 2) + t * 16 + r) * BK + g * 8);
#pragma unroll
            for (int u = 0; u < 2; ++u)
                acc[t][u] = __builtin_amdgcn_mfma_f32_16x16x32_bf16(af, bf[u], acc[t][u], 0, 0, 0);
        }
        __syncthreads();
    }
    int r0 = bm + wr * (BM / 2) + g * 4;
    int c0 = bn + wc * 32 + r;
#pragma unroll
    for (int t = 0; t < MF; ++t)
#pragma unroll
        for (int u = 0; u < 2; ++u)
#pragma unroll
            for (int e = 0; e < 4; ++e) {
                int row = r0 + t * 16 + e, col = c0 + u * 16;
                float v = acc[t][u][e];
                if (bias) v += bias[col];
                if (ACT == 1) v = gelu_erf(v);
                if (WF32) Cf[(size_t)row * N + col] = v;
                if (WBF16) Cb[(size_t)row * N + col] = f2bf(v);
            }
}

// ---------------- 128x128-tile staged GEMM (bf16 out, no bias/act) ----------------
// block 256 = 4 waves (2x2), wave tile 64x64 (4x4 frags, 16 MFMA/K-step).
// LDS chunk-swizzle c ^= (row>>1)&3 on both staging source and frag reads ->
// fragment ds_read_b128 hits 2 lanes/bank-quad (free).
template <int K>
__global__ __launch_bounds__(256) void gemm_128(
    const u16* __restrict__ A, const u16* __restrict__ W,
    u16* __restrict__ Cb, int N) {
    constexpr int BK = 32;
    constexpr int NK = K / BK;
    int tid = threadIdx.x;
    int w = tid >> 6, lane = tid & 63;
    int wr = w >> 1, wc = w & 1;
    int g = lane >> 4, r = lane & 15;
    int bm = blockIdx.y * 128;
    int bn = blockIdx.x * 128;
    __shared__ __align__(16) u16 Ab[2][128 * BK];
    __shared__ __align__(16) u16 Bb[2][128 * BK];
    int srd = lane >> 2;                 // row delta within 16-row group
    int schunk = ((lane & 3) ^ ((lane >> 3) & 3)) * 8;  // source chunk, pre-swizzled
    auto stage = [&](int buf, int k0) {
#pragma unroll
        for (int i = 0; i < 2; ++i) {
            int rowA = bm + i * 64 + w * 16 + srd;
            int rowB = bn + i * 64 + w * 16 + srd;
            gload_lds16(A + (size_t)rowA * K + k0 + schunk, &Ab[buf][(i * 64 + w * 16) * BK]);
            gload_lds16(W + (size_t)rowB * K + k0 + schunk, &Bb[buf][(i * 64 + w * 16) * BK]);
        }
    };
    f32x4 acc[4][4] = {};
    stage(0, 0);
    __syncthreads();
    int rs = (r >> 1) & 3;               // read-side swizzle
    for (int st = 0; st < NK; ++st) {
        int cur = st & 1;
        if (st + 1 < NK) stage(cur ^ 1, (st + 1) * BK);
        const u16* Al = &Ab[cur][0];
        const u16* Bl = &Bb[cur][0];
        bf16x8 bf[4];
#pragma unroll
        for (int u = 0; u < 4; ++u)
            bf[u] = *(const bf16x8*)(Bl + (wc * 64 + u * 16 + r) * BK + ((g ^ rs) * 8));
#pragma unroll
        for (int t = 0; t < 4; ++t) {
            bf16x8 af = *(const bf16x8*)(Al + (wr * 64 + t * 16 + r) * BK + ((g ^ rs) * 8));
#pragma unroll
            for (int u = 0; u < 4; ++u)
                acc[t][u] = __builtin_amdgcn_mfma_f32_16x16x32_bf16(af, bf[u], acc[t][u], 0, 0, 0);
        }
        __syncthreads();
    }
#pragma unroll
    for (int t = 0; t < 4; ++t)
#pragma unroll
        for (int u = 0; u < 4; ++u)
#pragma unroll
            for (int e = 0; e < 4; ++e) {
                int row = bm + wr * 64 + t * 16 + g * 4 + e;
                int col = bn + wc * 64 + u * 16 + r;
                Cb[(size_t)row * N + col] = f2bf(acc[t][u][e]);
            }
}

// ---------------- GEMM (N=256) + fused bias + residual + LayerNorm ----------------
// block tile 32x256: 4 waves, wave w covers cols [w*64, w*64+64) (2x4 frags,
// 8 MFMA/K-step). Same chunk swizzle as gemm_128. Epilogue: v = acc+bias+h;
// LN over the 256 cols (DPP row-reduce + cross-wave LDS); writes h (f32), hbf.
template <int K>
__global__ __launch_bounds__(256) void gemm_ln(
    const u16* __restrict__ A, const u16* __restrict__ W,
    const float* __restrict__ bias,
    const float* __restrict__ lng, const float* __restrict__ lnb,
    float* __restrict__ h, u16* __restrict__ hbf) {
    constexpr int BK = 32;
    constexpr int NK = K / BK;
    int tid = threadIdx.x;
    int w = tid >> 6, lane = tid & 63;
    int g = lane >> 4, r = lane & 15;
    int bm = blockIdx.x * 32;
    __shared__ __align__(16) u16 Ab[2][32 * BK];
    __shared__ __align__(16) u16 Bb[2][256 * BK];
    __shared__ float sums[32][4][2];
    int srd = lane >> 2;
    int schunk = ((lane & 3) ^ ((lane >> 3) & 3)) * 8;
    auto stage = [&](int buf, int k0) {
        if (w < 2)
            gload_lds16(A + (size_t)(bm + w * 16 + srd) * K + k0 + schunk,
                        &Ab[buf][(w * 16) * BK]);
#pragma unroll
        for (int i = 0; i < 4; ++i)
            gload_lds16(W + (size_t)(w * 64 + i * 16 + srd) * K + k0 + schunk,
                        &Bb[buf][(w * 64 + i * 16) * BK]);
    };
    f32x4 acc[2][4] = {};
    stage(0, 0);
    __syncthreads();
    int rs = (r >> 1) & 3;
    for (int st = 0; st < NK; ++st) {
        int cur = st & 1;
        if (st + 1 < NK) stage(cur ^ 1, (st + 1) * BK);
        const u16* Al = &Ab[cur][0];
        const u16* Bl = &Bb[cur][0];
        bf16x8 bf[4];
#pragma unroll
        for (int u = 0; u < 4; ++u)
            bf[u] = *(const bf16x8*)(Bl + (w * 64 + u * 16 + r) * BK + ((g ^ rs) * 8));
#pragma unroll
        for (int t = 0; t < 2; ++t) {
            bf16x8 af = *(const bf16x8*)(Al + (t * 16 + r) * BK + ((g ^ rs) * 8));
#pragma unroll
            for (int u = 0; u < 4; ++u)
                acc[t][u] = __builtin_amdgcn_mfma_f32_16x16x32_bf16(af, bf[u], acc[t][u], 0, 0, 0);
        }
        __syncthreads();
    }
    // epilogue: full value (bias + residual), strip stats, cross-wave LN
    float val[2][4][4];
#pragma unroll
    for (int t = 0; t < 2; ++t)
#pragma unroll
        for (int e = 0; e < 4; ++e) {
            int row = bm + t * 16 + g * 4 + e;
            float s1 = 0.f, s2 = 0.f;
#pragma unroll
            for (int u = 0; u < 4; ++u) {
                int col = w * 64 + u * 16 + r;
                float v = acc[t][u][e] + bias[col] + h[(size_t)row * kC + col];
                val[t][u][e] = v;
                s1 += v;
                s2 += v * v;
            }
            s1 = dpp_ror_add16(s1);
            s2 = dpp_ror_add16(s2);
            if (r == 0) {
                sums[t * 16 + g * 4 + e][w][0] = s1;
                sums[t * 16 + g * 4 + e][w][1] = s2;
            }
        }
    __syncthreads();
#pragma unroll
    for (int t = 0; t < 2; ++t)
#pragma unroll
        for (int e = 0; e < 4; ++e) {
            int lr = t * 16 + g * 4 + e;
            int row = bm + lr;
            float S1 = sums[lr][0][0] + sums[lr][1][0] + sums[lr][2][0] + sums[lr][3][0];
            float S2 = sums[lr][0][1] + sums[lr][1][1] + sums[lr][2][1] + sums[lr][3][1];
            float mu = S1 * (1.f / kC);
            float rstd = rsqrtf(S2 * (1.f / kC) - mu * mu + 1e-5f);
#pragma unroll
            for (int u = 0; u < 4; ++u) {
                int col = w * 64 + u * 16 + r;
                float y = (val[t][u][e] - mu) * rstd * lng[col] + lnb[col];
                h[(size_t)row * kC + col] = y;
                hbf[(size_t)row * kC + col] = f2bf(y);
            }
        }
}

// ---------------- GATv2: per-node online softmax aggregation + fused residual LN ----
__global__ __launch_bounds__(256) void gat_agg(
    const u16* __restrict__ xg,
    const float* __restrict__ att, const float* __restrict__ gb,
    const int* __restrict__ off, const int* __restrict__ srcs,
    const float* __restrict__ lng, const float* __restrict__ lnb,
    float* __restrict__ h, u16* __restrict__ hbf) {
    int n = blockIdx.x;
    int w = threadIdx.x >> 6, lane = threadIdx.x & 63;
    int q = lane >> 4, t = lane & 15;
    int cb = w * 256 + t * 16;   // channel slice [cb, cb+16) of 1024

    uint4 xru0 = *(const uint4*)(xg + (size_t)n * 2048 + 1024 + cb);
    uint4 xru1 = *(const uint4*)(xg + (size_t)n * 2048 + 1024 + cb + 8);
    float xrv[16];
    unpack8(xru0, xrv); unpack8(xru1, xrv + 8);
    float att6[16], att4[16];
#pragma unroll
    for (int j = 0; j < 16; j += 4) {
        float4 a4 = *(const float4*)(att + cb + j);
        att6[j] = 0.6f * a4.x; att6[j + 1] = 0.6f * a4.y;
        att6[j + 2] = 0.6f * a4.z; att6[j + 3] = 0.6f * a4.w;
        att4[j] = (2.f / 3.f) * att6[j]; att4[j + 1] = (2.f / 3.f) * att6[j + 1];
        att4[j + 2] = (2.f / 3.f) * att6[j + 2]; att4[j + 3] = (2.f / 3.f) * att6[j + 3];
    }

    int i0 = off[n], i1 = off[n + 1];
    float m = -1e30f, ls = 0.f;
    float acc[16] = {};
    int i = i0 + q;
    uint4 p0a, p1a, p0b, p1b;
    if (i < i1) {
        int s = srcs[i];
        p0a = *(const uint4*)(xg + (size_t)s * 2048 + cb);
        p1a = *(const uint4*)(xg + (size_t)s * 2048 + cb + 8);
    }
    if (i + 4 < i1) {
        int s = srcs[i + 4];
        p0b = *(const uint4*)(xg + (size_t)s * 2048 + cb);
        p1b = *(const uint4*)(xg + (size_t)s * 2048 + cb + 8);
    }
    while (i < i1) {
        uint4 c0 = p0a, c1 = p1a;
        p0a = p0b; p1a = p1b;
        if (i + 8 < i1) {
            int s2 = srcs[i + 8];
            p0b = *(const uint4*)(xg + (size_t)s2 * 2048 + cb);
            p1b = *(const uint4*)(xg + (size_t)s2 * 2048 + cb + 8);
        }
        float x[16];
        unpack8(c0, x); unpack8(c1, x + 8);
        float p = 0.f;
#pragma unroll
        for (int j = 0; j < 16; ++j) {
            float e = x[j] + xrv[j];
            p = fmaf(att6[j], e, p);
            p = fmaf(att4[j], __builtin_fabsf(e), p);
        }
        p = dpp_ror_add16(p);   // all 16 lanes of the quarter now hold the score
        if (p > m) {            // quarter-uniform
            float c = __expf(m - p);
            ls = ls * c + 1.f;
#pragma unroll
            for (int j = 0; j < 16; ++j) acc[j] = acc[j] * c + x[j];
            m = p;
        } else {
            float pw = __expf(p - m);
            ls += pw;
#pragma unroll
            for (int j = 0; j < 16; ++j) acc[j] = fmaf(pw, x[j], acc[j]);
        }
        i += 4;
    }
    // exact LSE merge of the 4 quarter states
    float mm = fmaxf(m, __shfl_xor(m, 16));
    mm = fmaxf(mm, __shfl_xor(mm, 32));
    float c = __expf(m - mm);   // 0 for empty quarters (m = -1e30)
    ls *= c;
    ls += __shfl_xor(ls, 16);
    ls += __shfl_xor(ls, 32);
#pragma unroll
    for (int j = 0; j < 16; ++j) {
        float a = acc[j] * c;
        a += __shfl_xor(a, 16);
        a += __shfl_xor(a, 32);
        acc[j] = a;
    }
    float inv = 1.f / ls;
    __shared__ float red[4][256];
    __shared__ float rs[8];
    if (q == 0) {
#pragma unroll
        for (int j = 0; j < 16; ++j) red[w][t * 16 + j] = acc[j] * inv;
    }
    __syncthreads();
    int cc = threadIdx.x;
    float vsum = 0.25f * (red[0][cc] + red[1][cc] + red[2][cc] + red[3][cc]) + gb[cc];
    // fused residual + LayerNorm over the block's 256 channels
    float v = h[(size_t)n * kC + cc] + vsum;
    float s1 = v, s2 = v * v;
    for (int d = 1; d < 64; d <<= 1) { s1 += __shfl_xor(s1, d); s2 += __shfl_xor(s2, d); }
    if (lane == 0) { rs[w] = s1; rs[4 + w] = s2; }
    __syncthreads();
    s1 = rs[0] + rs[1] + rs[2] + rs[3];
    s2 = rs[4] + rs[5] + rs[6] + rs[7];
    float mu = s1 * (1.f / kC);
    float rstd = rsqrtf(s2 * (1.f / kC) - mu * mu + 1e-5f);
    float y = (v - mu) * rstd * lng[cc] + lnb[cc];
    h[(size_t)n * kC + cc] = y;
    hbf[(size_t)n * kC + cc] = f2bf(y);
}

// ---------------- qkv repack: qkvb bf16 [4096][768] -> Qb/Kb [4][4096][64], VTb [4][64][4096]
__global__ __launch_bounds__(256) void qkv_repack(
    const u16* __restrict__ qkvb, u16* __restrict__ Qb, u16* __restrict__ Kb,
    u16* __restrict__ VTb) {
    int h = blockIdx.y;
    int n0 = blockIdx.x * 64;
    int t = threadIdx.x;
    int nr = t >> 2, cb = (t & 3) * 16;
    const u16* src = qkvb + (size_t)(n0 + nr) * 768 + h * 64 + cb;
    u16* qd = Qb + ((size_t)h * kN + n0 + nr) * 64 + cb;
    u16* kd = Kb + ((size_t)h * kN + n0 + nr) * 64 + cb;
    __shared__ u16 lds[64][72];
    constexpr float QS = 0.125f * 1.4426950408889634f;  // 1/sqrt(DH) * log2(e)
#pragma unroll
    for (int j = 0; j < 16; j += 4) {
        ushort4 q4 = *(const ushort4*)(src + j);
        ushort4 k4 = *(const ushort4*)(src + 256 + j);
        ushort4 v4 = *(const ushort4*)(src + 512 + j);
        ushort4 qo;
        qo.x = f2bf(bf2f(q4.x) * QS); qo.y = f2bf(bf2f(q4.y) * QS);
        qo.z = f2bf(bf2f(q4.z) * QS); qo.w = f2bf(bf2f(q4.w) * QS);
        *(ushort4*)(qd + j) = qo;
        *(ushort4*)(kd + j) = k4;
        *(ushort4*)(&lds[nr][cb + j]) = v4;
    }
    __syncthreads();
    int d = t >> 2, nb = (t & 3) * 16;
    u16* vd = VTb + ((size_t)h * 64 + d) * kN + n0 + nb;
#pragma unroll
    for (int j = 0; j < 16; j += 4) {
        ushort4 vo;
        vo.x = lds[nb + j + 0][d];
        vo.y = lds[nb + j + 1][d];
        vo.z = lds[nb + j + 2][d];
        vo.w = lds[nb + j + 3][d];
        *(ushort4*)(vd + j) = vo;
    }
}

// ---------------- MFMA flash attention, LDS-shared K/V, split-K ----------------
__global__ __launch_bounds__(256, 4) void mha_mfma2(
    const u16* __restrict__ Qb, const u16* __restrict__ Kb,
    const u16* __restrict__ VTb, float* __restrict__ opart, float* __restrict__ mlpart) {
    int qt = blockIdx.x, head = blockIdx.y, sp = blockIdx.z;
    int tid = threadIdx.x;
    int w = tid >> 6, lane = tid & 63;
    int g = lane >> 4, r = lane & 15;
    int q0 = qt * 64;
    const u16* Qh = Qb + ((size_t)head * kN + q0 + w * 16) * 64;
    const u16* Kh = Kb + (size_t)head * kN * 64;
    const u16* VTh = VTb + (size_t)head * 64 * kN;
    __shared__ u16 Kt[2][64 * 64];
    __shared__ u16 Vt[2][64 * 64];
    __shared__ u16 plds[4][16 * 64];
    int srow = w * 8 + (lane >> 3);
    int schunk = ((lane & 7) ^ ((lane >> 3) & 7)) * 8;   // element offset within row
    int kbase = sp * KSPAN;

    bf16x8 qf0 = *(const bf16x8*)(Qh + r * 64 + g * 8);
    bf16x8 qf1 = *(const bf16x8*)(Qh + r * 64 + 32 + g * 8);

    auto stage = [&](int buf, int k0) {
#pragma unroll
        for (int i = 0; i < 2; ++i) {
            int row = i * 32 + srow;
            gload_lds16(Kh + (size_t)(k0 + row) * 64 + schunk, &Kt[buf][(i * 32 + w * 8) * 64]);
            gload_lds16(VTh + (size_t)row * kN + k0 + schunk, &Vt[buf][(i * 32 + w * 8) * 64]);
        }
    };

    f32x4 o[4] = {};
    float m = -3.0e38f, l = 0.f;

    stage(0, kbase);
    __syncthreads();

    int rx = r & 7;
    for (int st = 0; st < NSTEP; ++st) {
        int cur = st & 1;
        if (st + 1 < NSTEP) stage(cur ^ 1, kbase + (st + 1) * 64);
        const u16* Kl = &Kt[cur][0];
        const u16* Vl = &Vt[cur][0];
        f32x4 stt[4] = {};
#pragma unroll
        for (int t = 0; t < 4; ++t) {
            bf16x8 kf0 = *(const bf16x8*)(Kl + (16 * t + r) * 64 + ((0 + g) ^ rx) * 8);
            bf16x8 kf1 = *(const bf16x8*)(Kl + (16 * t + r) * 64 + ((4 + g) ^ rx) * 8);
            stt[t] = __builtin_amdgcn_mfma_f32_16x16x32_bf16(kf0, qf0, stt[t], 0, 0, 0);
            stt[t] = __builtin_amdgcn_mfma_f32_16x16x32_bf16(kf1, qf1, stt[t], 0, 0, 0);
        }
        float pm = stt[0][0];
#pragma unroll
        for (int t = 0; t < 4; ++t)
#pragma unroll
            for (int e = 0; e < 4; ++e) pm = fmaxf(pm, stt[t][e]);
        pm = fmaxf(pm, __shfl_xor(pm, 16));
        pm = fmaxf(pm, __shfl_xor(pm, 32));
        if (__any(pm > m)) {
            float mn = fmaxf(m, pm);
            float corr = __builtin_amdgcn_exp2f(m - mn);
            l *= corr;
            float corrq[4];
#pragma unroll
            for (int e = 0; e < 4; ++e) corrq[e] = __shfl(corr, g * 4 + e);
#pragma unroll
            for (int dt = 0; dt < 4; ++dt)
#pragma unroll
                for (int e = 0; e < 4; ++e) o[dt][e] *= corrq[e];
            m = mn;
        }
        float ls = 0.f;
        float p[4][4];
#pragma unroll
        for (int t = 0; t < 4; ++t)
#pragma unroll
            for (int e = 0; e < 4; ++e) { p[t][e] = __builtin_amdgcn_exp2f(stt[t][e] - m); ls += p[t][e]; }
        ls += __shfl_xor(ls, 16);
        ls += __shfl_xor(ls, 32);
        l += ls;
#pragma unroll
        for (int t = 0; t < 4; ++t) {
            ushort4 pk;
            pk.x = f2bf(p[t][0]); pk.y = f2bf(p[t][1]);
            pk.z = f2bf(p[t][2]); pk.w = f2bf(p[t][3]);
            int lc = (2 * t + (g >> 1)) ^ rx;
            *(ushort4*)(&plds[w][r * 64 + lc * 8 + (g & 1) * 4]) = pk;
        }
        bf16x8 pa0 = *(const bf16x8*)(&plds[w][r * 64 + (g ^ rx) * 8]);
        bf16x8 pa1 = *(const bf16x8*)(&plds[w][r * 64 + ((4 + g) ^ rx) * 8]);
#pragma unroll
        for (int dt = 0; dt < 4; ++dt) {
            bf16x8 vf0 = *(const bf16x8*)(Vl + (dt * 16 + r) * 64 + ((0 + g) ^ rx) * 8);
            bf16x8 vf1 = *(const bf16x8*)(Vl + (dt * 16 + r) * 64 + ((4 + g) ^ rx) * 8);
            o[dt] = __builtin_amdgcn_mfma_f32_16x16x32_bf16(pa0, vf0, o[dt], 0, 0, 0);
            o[dt] = __builtin_amdgcn_mfma_f32_16x16x32_bf16(pa1, vf1, o[dt], 0, 0, 0);
        }
        __syncthreads();
    }

    size_t slot = (size_t)(head * 64 + qt) * NSPLIT + sp;
    float* ob = opart + slot * 4096;
#pragma unroll
    for (int dt = 0; dt < 4; ++dt)
#pragma unroll
        for (int e = 0; e < 4; ++e)
            ob[(w * 16 + g * 4 + e) * 64 + dt * 16 + r] = o[dt][e];
    float* mlb = mlpart + slot * 128;
    if (g == 0) { mlb[w * 16 + r] = m; mlb[64 + w * 16 + r] = l; }
}

// ---------------- merge split-K attention partials -> attnb (bf16) ----------------
__global__ __launch_bounds__(256) void mha_merge(
    const float* __restrict__ opart, const float* __restrict__ mlpart,
    u16* __restrict__ attnb) {
    int head = blockIdx.y;
    int q = blockIdx.x * 4 + (threadIdx.x >> 6);
    int d = threadIdx.x & 63;
    int qt = q >> 6, ql = q & 63;
    size_t sb = (size_t)(head * 64 + qt) * NSPLIT;
    float ms[NSPLIT], lsv[NSPLIT];
    float mstar = -3.0e38f;
#pragma unroll
    for (int s = 0; s < NSPLIT; ++s) {
        ms[s] = mlpart[(sb + s) * 128 + ql];
        lsv[s] = mlpart[(sb + s) * 128 + 64 + ql];
        mstar = fmaxf(mstar, ms[s]);
    }
    float acc = 0.f, lsum = 0.f;
#pragma unroll
    for (int s = 0; s < NSPLIT; ++s) {
        float wgt = __builtin_amdgcn_exp2f(ms[s] - mstar);
        lsum += lsv[s] * wgt;
        acc += opart[(sb + s) * 4096 + ql * 64 + d] * wgt;
    }
    attnb[(size_t)q * kC + head * 64 + d] = f2bf(acc / lsum);
}

// ---------------- final: out[4096,2] = t_bf @ out_w2^T + b2; wave per row ----------------
__global__ __launch_bounds__(256) void final_out(
    const u16* __restrict__ tbf, const float* __restrict__ w2,
    const float* __restrict__ b2, float* __restrict__ out) {
    int row = blockIdx.x * 4 + (threadIdx.x >> 6);
    int lane = threadIdx.x & 63;
    const ushort4 tv = *(const ushort4*)(tbf + (size_t)row * 256 + lane * 4);
    float t0 = bf2f(tv.x), t1 = bf2f(tv.y), t2 = bf2f(tv.z), t3 = bf2f(tv.w);
    const float4 w0 = *(const float4*)(w2 + lane * 4);
    const float4 w1 = *(const float4*)(w2 + 256 + lane * 4);
    float d0 = t0 * w0.x + t1 * w0.y + t2 * w0.z + t3 * w0.w;
    float d1 = t0 * w1.x + t1 * w1.y + t2 * w1.z + t3 * w1.w;
    for (int d = 1; d < 64; d <<= 1) { d0 += __shfl_xor(d0, d); d1 += __shfl_xor(d1, d); }
    if (lane == 0) {
        out[(size_t)row * 2 + 0] = d0 + b2[0];
        out[(size_t)row * 2 + 1] = d1 + b2[1];
    }
}

extern "C" void kernel_launch(void* const* d_in, const int* in_sizes, int n_in,
                              void* d_out, int out_size, void* d_ws, size_t ws_size,
                              hipStream_t stream) {
    (void)in_sizes; (void)n_in; (void)out_size;
    const float* x        = (const float*)d_in[0];
    const int*   ei       = (const int*)d_in[1];
    const float* in_w     = (const float*)d_in[2];
    const float* in_b     = (const float*)d_in[3];
    const float* gat_wl   = (const float*)d_in[4];
    const float* gat_wr   = (const float*)d_in[5];
    const float* gat_att  = (const float*)d_in[6];
    const float* gat_b    = (const float*)d_in[7];
    const float* mha_in_w = (const float*)d_in[8];
    const float* mha_in_b = (const float*)d_in[9];
    const float* mha_out_w= (const float*)d_in[10];
    const float* mha_out_b= (const float*)d_in[11];
    const float* ln1_g = (const float*)d_in[12];
    const float* ln1_b = (const float*)d_in[13];
    const float* ln2_g = (const float*)d_in[14];
    const float* ln2_b = (const float*)d_in[15];
    const float* ln3_g = (const float*)d_in[16];
    const float* ln3_b = (const float*)d_in[17];
    const float* ffn_w1 = (const float*)d_in[18];
    const float* ffn_b1 = (const float*)d_in[19];
    const float* ffn_w2 = (const float*)d_in[20];
    const float* ffn_b2 = (const float*)d_in[21];
    const float* out_w1 = (const float*)d_in[22];
    const float* out_b1 = (const float*)d_in[23];
    const float* out_w2 = (const float*)d_in[24];
    const float* out_b2 = (const float*)d_in[25];
    float* out = (float*)d_out;

    char* ws = (char*)d_ws;
    size_t off = 0;
    auto alloc = [&](size_t bytes) -> void* {
        void* p = (void*)(ws + off);
        off += (bytes + 255) & ~(size_t)255;
        return p;
    };
    float* h     = (float*)alloc((size_t)kN * kC * 4);
    u16*   hbf   = (u16*)  alloc((size_t)kN * kC * 2);
    float* xlb   = (float*)alloc((size_t)kN * 1024 * 4);   // slot reused: xgbf / Qb+Kb+VTb
    float* xrb   = (float*)alloc((size_t)kN * 1024 * 4);   // slot reused: opart
    float* qkv   = (float*)alloc((size_t)kN * 768 * 4);    // slot reused: qkvb (bf16)
    float* locb  = (float*)alloc((size_t)kN * kC * 4);     // slot reused: mlpart
    u16*   attnb = (u16*)  alloc((size_t)kN * kC * 2);
    u16*   midb  = (u16*)  alloc((size_t)kN * 512 * 2);
    u16*   tbf   = (u16*)  alloc((size_t)kN * kC * 2);
    u16*   xbf   = (u16*)  alloc((size_t)kN * kIn * 2);
    u16*   wbf   = (u16*)  alloc((size_t)3342336 * 2);
    int*   coff  = (int*)  alloc((size_t)4097 * 4);
    int*   ccur  = (int*)  alloc((size_t)4096 * 4);
    int*   csrc  = (int*)  alloc((size_t)kET * 4);
    if (ws_size < off) return;  // not enough scratch: bail loudly (output stays poisoned)

    u16* xgbf = (u16*)xlb;                      // [4096][2048] bf16 (xl|xr fused)
    u16* Qb  = (u16*)xlb;                       // [4][4096][64]
    u16* Kb  = Qb + (size_t)4 * kN * 64;        // [4][4096][64]
    u16* VTb = Kb + (size_t)4 * kN * 64;        // [4][64][4096]
    u16* qkvb = (u16*)qkv;                      // [4096][768] bf16
    float* opart  = xrb;                        // 1024 slots x 4096 f32 = 16 MB exact
    float* mlpart = locb;

    // bf16 weight buffer offsets (elements); gat wl/wr interleaved per layer [2048][256]
    const size_t OFF_INW  = 0;
    const size_t OFF_GAT  = 131072;
    const size_t OFF_MIN  = 1703936;
    const size_t OFF_MOUT = 2293760;
    const size_t OFF_F1   = 2490368;
    const size_t OFF_F2   = 2883584;
    const size_t OFF_O1   = 3276800;

    auto cast = [&](const float* s, u16* d, int n) {
        int n4 = n >> 2;
        cast_f2b<<<dim3((n4 + 255) / 256), dim3(256), 0, stream>>>(s, d, n4);
    };
    cast(x, xbf, kN * kIn);
    cast(in_w, wbf + OFF_INW, kC * kIn);
    for (int l = 0; l < kL; ++l) {
        cast(gat_wl + (size_t)l * 262144, wbf + OFF_GAT + (size_t)l * 524288, 262144);
        cast(gat_wr + (size_t)l * 262144, wbf + OFF_GAT + (size_t)l * 524288 + 262144, 262144);
    }
    cast(mha_in_w, wbf + OFF_MIN, kL * 768 * kC);
    cast(mha_out_w, wbf + OFF_MOUT, kL * kC * kC);
    cast(ffn_w1, wbf + OFF_F1, kL * 512 * kC);
    cast(ffn_w2, wbf + OFF_F2, kL * kC * 512);
    cast(out_w1, wbf + OFF_O1, kC * kC);

    // CSR build (once per launch; same graph for all layers)
    hipMemsetAsync(ccur, 0, 4096 * 4, stream);
    csr_count<<<dim3((kET + 255) / 256), dim3(256), 0, stream>>>(ei, ccur);
    csr_scan<<<dim3(1), dim3(1024), 0, stream>>>(ccur, coff);
    csr_scatter<<<dim3((kET + 255) / 256), dim3(256), 0, stream>>>(ei, ccur, csrc);

    // input projection: h = x @ in_w^T + in_b  (fp32 + bf16 outputs)
    gemm_st<64, 512, 0, 1, 1><<<dim3(kC / 64, kN / 64), dim3(256), 0, stream>>>(
        xbf, wbf + OFF_INW, in_b, h, hbf, kC);

    for (int l = 0; l < kL; ++l) {
        // GATv2 transforms: fused wl|wr 128x128-tile GEMM -> xgbf [4096][2048]
        gemm_128<256><<<dim3(2048 / 128, kN / 128), dim3(256), 0, stream>>>(
            hbf, wbf + OFF_GAT + (size_t)l * 524288, xgbf, 2048);
        // gat_agg with fused residual + ln1 (writes h, hbf directly)
        gat_agg<<<dim3(kN), dim3(256), 0, stream>>>(
            xgbf, gat_att + (size_t)l * 1024, gat_b + (size_t)l * kC, coff, csrc,
            ln1_g + (size_t)l * kC, ln1_b + (size_t)l * kC, h, hbf);

        // MHA
        gemm_st<128, 256, 0, 0, 1><<<dim3(768 / 64, kN / 128), dim3(256), 0, stream>>>(
            hbf, wbf + OFF_MIN + (size_t)l * 768 * kC, mha_in_b + (size_t)l * 768, nullptr, qkvb, 768);
        qkv_repack<<<dim3(kN / 64, 4), dim3(256), 0, stream>>>(qkvb, Qb, Kb, VTb);
        mha_mfma2<<<dim3(kN / 64, 4, NSPLIT), dim3(256), 0, stream>>>(Qb, Kb, VTb, opart, mlpart);
        mha_merge<<<dim3(kN / 4, 4), dim3(256), 0, stream>>>(opart, mlpart, attnb);
        // mout GEMM + fused residual + ln2
        gemm_ln<256><<<dim3(kN / 32), dim3(256), 0, stream>>>(
            attnb, wbf + OFF_MOUT + (size_t)l * kC * kC, mha_out_b + (size_t)l * kC,
            ln2_g + (size_t)l * kC, ln2_b + (size_t)l * kC, h, hbf);

        // FFN
        gemm_st<64, 256, 1, 0, 1><<<dim3(512 / 64, kN / 64), dim3(256), 0, stream>>>(
            hbf, wbf + OFF_F1 + (size_t)l * 512 * kC, ffn_b1 + (size_t)l * 512, nullptr, midb, 512);
        // ffn2 GEMM + fused residual + ln3
        gemm_ln<512><<<dim3(kN / 32), dim3(256), 0, stream>>>(
            midb, wbf + OFF_F2 + (size_t)l * kC * 512, ffn_b2 + (size_t)l * kC,
            ln3_g + (size_t)l * kC, ln3_b + (size_t)l * kC, h, hbf);
    }

    // output head
    gemm_st<64, 256, 1, 0, 1><<<dim3(kC / 64, kN / 64), dim3(256), 0, stream>>>(
        hbf, wbf + OFF_O1, out_b1, nullptr, tbf, kC);
    final_out<<<dim3(kN / 4), dim3(256), 0, stream>>>(tbf, out_w2, out_b2, out);
}

// Round 12
// 479.049 us; speedup vs baseline: 10.0582x; 1.0902x over previous
//
#include <hip/hip_runtime.h>
#include <cstdint>
#include <cstddef>

typedef unsigned short u16;
typedef __bf16 bf16x8 __attribute__((ext_vector_type(8)));
typedef float f32x4 __attribute__((ext_vector_type(4)));

constexpr int kN  = 4096;
constexpr int kE  = 131072;
constexpr int kET = kE + kN;   // with self loops
constexpr int kIn = 512;
constexpr int kC  = 256;
constexpr int kL  = 3;

constexpr int NSPLIT = 4;
constexpr int KSPAN  = kN / NSPLIT;  // 1024 keys per split
constexpr int NSTEP  = KSPAN / 64;   // 16 steps of 64 keys

__device__ __forceinline__ u16 f2bf(float f) {
    unsigned u = __builtin_bit_cast(unsigned, f);
    u += 0x7fffu + ((u >> 16) & 1u);
    return (u16)(u >> 16);
}
__device__ __forceinline__ float bf2f(u16 s) {
    unsigned u = ((unsigned)s) << 16;
    return __builtin_bit_cast(float, u);
}
__device__ __forceinline__ float gelu_erf(float x) {
    return 0.5f * x * (1.f + erff(x * 0.70710678118654752f));
}
// async global->LDS, 16B per lane; ldst must be wave-uniform base (HW adds lane*16)
__device__ __forceinline__ void gload_lds16(const u16* gsrc, u16* ldst) {
    __builtin_amdgcn_global_load_lds(
        (const __attribute__((address_space(1))) unsigned int*)gsrc,
        (__attribute__((address_space(3))) unsigned int*)ldst, 16, 0, 0);
}
// sum over each row of 16 lanes via DPP row_ror adds (full-rate VALU, no LDS pipe)
__device__ __forceinline__ float dpp_ror_add16(float x) {
    int t;
    t = __builtin_amdgcn_update_dpp(0, __builtin_bit_cast(int, x), 0x121, 0xf, 0xf, true);
    x += __builtin_bit_cast(float, t);
    t = __builtin_amdgcn_update_dpp(0, __builtin_bit_cast(int, x), 0x122, 0xf, 0xf, true);
    x += __builtin_bit_cast(float, t);
    t = __builtin_amdgcn_update_dpp(0, __builtin_bit_cast(int, x), 0x124, 0xf, 0xf, true);
    x += __builtin_bit_cast(float, t);
    t = __builtin_amdgcn_update_dpp(0, __builtin_bit_cast(int, x), 0x128, 0xf, 0xf, true);
    x += __builtin_bit_cast(float, t);
    return x;
}
// unpack 8 bf16 (uint4) -> 8 f32
__device__ __forceinline__ void unpack8(uint4 u, float* x) {
    x[0] = __builtin_bit_cast(float, u.x << 16);
    x[1] = __builtin_bit_cast(float, u.x & 0xffff0000u);
    x[2] = __builtin_bit_cast(float, u.y << 16);
    x[3] = __builtin_bit_cast(float, u.y & 0xffff0000u);
    x[4] = __builtin_bit_cast(float, u.z << 16);
    x[5] = __builtin_bit_cast(float, u.z & 0xffff0000u);
    x[6] = __builtin_bit_cast(float, u.w << 16);
    x[7] = __builtin_bit_cast(float, u.w & 0xffff0000u);
}

// ---------------- fused fp32->bf16 cast of ALL weights + x (one dispatch) ----------
// Region table in vec4 units (compile-time). gat wl/wr are interleaved per layer
// into wbf [2048][256] blocks (layer stride 131072 vec4).
__global__ void cast_all(
    const float* __restrict__ x, const float* __restrict__ in_w,
    const float* __restrict__ gwl, const float* __restrict__ gwr,
    const float* __restrict__ minw, const float* __restrict__ moutw,
    const float* __restrict__ f1, const float* __restrict__ f2,
    const float* __restrict__ o1,
    u16* __restrict__ xbf, u16* __restrict__ wbf) {
    int i = blockIdx.x * 256 + threadIdx.x;
    if (i >= 1359872) return;
    const float* s;
    u16* dbase;
    int sj, dj;
    if (i < 524288) {                       // x: 4096x512
        s = x; dbase = xbf; sj = i; dj = i;
    } else if (i < 557056) {                // in_w
        s = in_w; dbase = wbf; sj = i - 524288; dj = sj;           // OFF_INW/4 = 0
    } else if (i < 753664) {                // gat_wl (interleaved)
        int j = i - 557056; int l = j >> 16, wi = j & 65535;
        s = gwl; dbase = wbf; sj = j; dj = 32768 + l * 131072 + wi;
    } else if (i < 950272) {                // gat_wr (interleaved, +65536)
        int j = i - 753664; int l = j >> 16, wi = j & 65535;
        s = gwr; dbase = wbf; sj = j; dj = 32768 + l * 131072 + 65536 + wi;
    } else if (i < 1097728) {               // mha_in_w
        s = minw; dbase = wbf; sj = i - 950272; dj = 425984 + sj;  // OFF_MIN/4
    } else if (i < 1146880) {               // mha_out_w
        s = moutw; dbase = wbf; sj = i - 1097728; dj = 573440 + sj;
    } else if (i < 1245184) {               // ffn_w1
        s = f1; dbase = wbf; sj = i - 1146880; dj = 622592 + sj;
    } else if (i < 1343488) {               // ffn_w2
        s = f2; dbase = wbf; sj = i - 1245184; dj = 720896 + sj;
    } else {                                // out_w1
        s = o1; dbase = wbf; sj = i - 1343488; dj = 819200 + sj;
    }
    float4 v = ((const float4*)s)[sj];
    ushort4 o;
    o.x = f2bf(v.x); o.y = f2bf(v.y); o.z = f2bf(v.z); o.w = f2bf(v.w);
    ((ushort4*)dbase)[dj] = o;
}

// ---------------- CSR build (by dst) ----------------
__global__ void csr_count(const int* __restrict__ ei, int* __restrict__ cnt) {
    int e = blockIdx.x * 256 + threadIdx.x;
    if (e >= kET) return;
    int d = (e < kE) ? ei[kE + e] : (e - kE);
    atomicAdd(cnt + d, 1);
}

__global__ __launch_bounds__(1024) void csr_scan(int* __restrict__ cnt_cur, int* __restrict__ off) {
    __shared__ int lds[1024];
    int t = threadIdx.x;
    int c[4], s = 0;
#pragma unroll
    for (int j = 0; j < 4; ++j) { c[j] = cnt_cur[t * 4 + j]; s += c[j]; }
    lds[t] = s;
    __syncthreads();
    for (int d = 1; d < 1024; d <<= 1) {
        int v = (t >= d) ? lds[t - d] : 0;
        __syncthreads();
        lds[t] += v;
        __syncthreads();
    }
    int excl = lds[t] - s;
#pragma unroll
    for (int j = 0; j < 4; ++j) { off[t * 4 + j] = excl; cnt_cur[t * 4 + j] = excl; excl += c[j]; }
    if (t == 1023) off[4096] = excl;
}

__global__ void csr_scatter(const int* __restrict__ ei, int* __restrict__ cur, int* __restrict__ csrc) {
    int e = blockIdx.x * 256 + threadIdx.x;
    if (e >= kET) return;
    int s, d;
    if (e < kE) { s = ei[e]; d = ei[kE + e]; } else { s = d = e - kE; }
    int pos = atomicAdd(cur + d, 1);
    csrc[pos] = s;
}

// ---------------- staged bf16 MFMA GEMM: C[M,N] = act(A[M,K] @ W[N,K]^T + bias) ----
template <int BM, int K, int ACT, int WF32, int WBF16>
__global__ __launch_bounds__(256) void gemm_st(
    const u16* __restrict__ A, const u16* __restrict__ W,
    const float* __restrict__ bias, float* __restrict__ Cf,
    u16* __restrict__ Cb, int N) {
    constexpr int BK = 32;
    constexpr int NK = K / BK;
    constexpr int MF = BM / 32;          // A fragments per wave
    int tid = threadIdx.x;
    int w = tid >> 6, lane = tid & 63;
    int wr = w >> 1, wc = w & 1;
    int g = lane >> 4, r = lane & 15;
    int bm = blockIdx.y * BM;
    int bn = blockIdx.x * 64;
    __shared__ __align__(16) u16 Ab[2][BM * BK];
    __shared__ __align__(16) u16 Bb[2][64 * BK];
    int srow = w * 16 + (lane >> 2);
    int scol = (lane & 3) * 8;
    auto stage = [&](int buf, int k0) {
#pragma unroll
        for (int i = 0; i < BM / 64; ++i)
            gload_lds16(A + (size_t)(bm + i * 64 + srow) * K + k0 + scol,
                        &Ab[buf][(i * 64 + w * 16) * BK]);
        gload_lds16(W + (size_t)(bn + srow) * K + k0 + scol, &Bb[buf][w * 16 * BK]);
    };
    f32x4 acc[MF][2] = {};
    stage(0, 0);
    __syncthreads();
    for (int st = 0; st < NK; ++st) {
        int cur = st & 1;
        if (st + 1 < NK) stage(cur ^ 1, (st + 1) * BK);
        const u16* Al = &Ab[cur][0];
        const u16* Bl = &Bb[cur][0];
        bf16x8 bf[2];
#pragma unroll
        for (int u = 0; u < 2; ++u)
            bf[u] = *(const bf16x8*)(Bl + (wc * 32 + u * 16 + r) * BK + g * 8);
#pragma unroll
        for (int t = 0; t < MF; ++t) {
            bf16x8 af = *(const bf16x8*)(Al + (wr * (BM / 2) + t * 16 + r) * BK + g * 8);
#pragma unroll
            for (int u = 0; u < 2; ++u)
                acc[t][u] = __builtin_amdgcn_mfma_f32_16x16x32_bf16(af, bf[u], acc[t][u], 0, 0, 0);
        }
        __syncthreads();
    }
    int r0 = bm + wr * (BM / 2) + g * 4;
    int c0 = bn + wc * 32 + r;
#pragma unroll
    for (int t = 0; t < MF; ++t)
#pragma unroll
        for (int u = 0; u < 2; ++u)
#pragma unroll
            for (int e = 0; e < 4; ++e) {
                int row = r0 + t * 16 + e, col = c0 + u * 16;
                float v = acc[t][u][e];
                if (bias) v += bias[col];
                if (ACT == 1) v = gelu_erf(v);
                if (WF32) Cf[(size_t)row * N + col] = v;
                if (WBF16) Cb[(size_t)row * N + col] = f2bf(v);
            }
}

// ---------------- fused qkv GEMM: writes Qb/Kb [head][n][64] and VTb [head][d][n] ---
// Copy of gemm_st<128,256> with region/head epilogue. blockIdx.x: 0-3 q heads,
// 4-7 k heads, 8-11 v heads (wave-uniform region). Q scaled by QS (exp2 domain).
__global__ __launch_bounds__(256) void gemm_qkv(
    const u16* __restrict__ A, const u16* __restrict__ W,
    const float* __restrict__ bias,
    u16* __restrict__ Qb, u16* __restrict__ Kb, u16* __restrict__ VTb) {
    constexpr int BK = 32, K = 256, NK = 8, BM = 128, MF = 4;
    int tid = threadIdx.x;
    int w = tid >> 6, lane = tid & 63;
    int wr = w >> 1, wc = w & 1;
    int g = lane >> 4, r = lane & 15;
    int bm = blockIdx.y * BM;
    int bn = blockIdx.x * 64;
    __shared__ __align__(16) u16 Ab[2][BM * BK];
    __shared__ __align__(16) u16 Bb[2][64 * BK];
    int srow = w * 16 + (lane >> 2);
    int scol = (lane & 3) * 8;
    auto stage = [&](int buf, int k0) {
#pragma unroll
        for (int i = 0; i < 2; ++i)
            gload_lds16(A + (size_t)(bm + i * 64 + srow) * K + k0 + scol,
                        &Ab[buf][(i * 64 + w * 16) * BK]);
        gload_lds16(W + (size_t)(bn + srow) * K + k0 + scol, &Bb[buf][w * 16 * BK]);
    };
    f32x4 acc[MF][2] = {};
    stage(0, 0);
    __syncthreads();
    for (int st = 0; st < NK; ++st) {
        int cur = st & 1;
        if (st + 1 < NK) stage(cur ^ 1, (st + 1) * BK);
        const u16* Al = &Ab[cur][0];
        const u16* Bl = &Bb[cur][0];
        bf16x8 bf[2];
#pragma unroll
        for (int u = 0; u < 2; ++u)
            bf[u] = *(const bf16x8*)(Bl + (wc * 32 + u * 16 + r) * BK + g * 8);
#pragma unroll
        for (int t = 0; t < MF; ++t) {
            bf16x8 af = *(const bf16x8*)(Al + (wr * 64 + t * 16 + r) * BK + g * 8);
#pragma unroll
            for (int u = 0; u < 2; ++u)
                acc[t][u] = __builtin_amdgcn_mfma_f32_16x16x32_bf16(af, bf[u], acc[t][u], 0, 0, 0);
        }
        __syncthreads();
    }
    constexpr float QS = 0.125f * 1.4426950408889634f;  // 1/sqrt(DH) * log2(e)
    int region = blockIdx.x >> 2;        // 0=q, 1=k, 2=v
    int head = blockIdx.x & 3;
    int r0 = bm + wr * 64 + g * 4;
    if (region == 2) {
        // V: transpose in-register -> VTb[head][d][n], 8B stores (4 consecutive n)
#pragma unroll
        for (int t = 0; t < MF; ++t)
#pragma unroll
            for (int u = 0; u < 2; ++u) {
                int d = wc * 32 + u * 16 + r;
                int col = bn + d;
                ushort4 vo;
                vo.x = f2bf(acc[t][u][0] + bias[col]);
                vo.y = f2bf(acc[t][u][1] + bias[col]);
                vo.z = f2bf(acc[t][u][2] + bias[col]);
                vo.w = f2bf(acc[t][u][3] + bias[col]);
                *(ushort4*)(VTb + ((size_t)head * 64 + d) * kN + r0 + t * 16) = vo;
            }
    } else {
        u16* dst = (region == 0) ? Qb : Kb;
        float sc = (region == 0) ? QS : 1.f;
#pragma unroll
        for (int t = 0; t < MF; ++t)
#pragma unroll
            for (int u = 0; u < 2; ++u)
#pragma unroll
                for (int e = 0; e < 4; ++e) {
                    int d = wc * 32 + u * 16 + r;
                    int row = r0 + t * 16 + e;
                    dst[((size_t)head * kN + row) * 64 + d] =
                        f2bf((acc[t][u][e] + bias[bn + d]) * sc);
                }
    }
}

// ---------------- 128x128-tile staged GEMM (bf16 out, no bias/act) ----------------
template <int K>
__global__ __launch_bounds__(256) void gemm_128(
    const u16* __restrict__ A, const u16* __restrict__ W,
    u16* __restrict__ Cb, int N) {
    constexpr int BK = 32;
    constexpr int NK = K / BK;
    int tid = threadIdx.x;
    int w = tid >> 6, lane = tid & 63;
    int wr = w >> 1, wc = w & 1;
    int g = lane >> 4, r = lane & 15;
    int bm = blockIdx.y * 128;
    int bn = blockIdx.x * 128;
    __shared__ __align__(16) u16 Ab[2][128 * BK];
    __shared__ __align__(16) u16 Bb[2][128 * BK];
    int srd = lane >> 2;
    int schunk = ((lane & 3) ^ ((lane >> 3) & 3)) * 8;
    auto stage = [&](int buf, int k0) {
#pragma unroll
        for (int i = 0; i < 2; ++i) {
            int rowA = bm + i * 64 + w * 16 + srd;
            int rowB = bn + i * 64 + w * 16 + srd;
            gload_lds16(A + (size_t)rowA * K + k0 + schunk, &Ab[buf][(i * 64 + w * 16) * BK]);
            gload_lds16(W + (size_t)rowB * K + k0 + schunk, &Bb[buf][(i * 64 + w * 16) * BK]);
        }
    };
    f32x4 acc[4][4] = {};
    stage(0, 0);
    __syncthreads();
    int rs = (r >> 1) & 3;
    for (int st = 0; st < NK; ++st) {
        int cur = st & 1;
        if (st + 1 < NK) stage(cur ^ 1, (st + 1) * BK);
        const u16* Al = &Ab[cur][0];
        const u16* Bl = &Bb[cur][0];
        bf16x8 bf[4];
#pragma unroll
        for (int u = 0; u < 4; ++u)
            bf[u] = *(const bf16x8*)(Bl + (wc * 64 + u * 16 + r) * BK + ((g ^ rs) * 8));
#pragma unroll
        for (int t = 0; t < 4; ++t) {
            bf16x8 af = *(const bf16x8*)(Al + (wr * 64 + t * 16 + r) * BK + ((g ^ rs) * 8));
#pragma unroll
            for (int u = 0; u < 4; ++u)
                acc[t][u] = __builtin_amdgcn_mfma_f32_16x16x32_bf16(af, bf[u], acc[t][u], 0, 0, 0);
        }
        __syncthreads();
    }
#pragma unroll
    for (int t = 0; t < 4; ++t)
#pragma unroll
        for (int u = 0; u < 4; ++u)
#pragma unroll
            for (int e = 0; e < 4; ++e) {
                int row = bm + wr * 64 + t * 16 + g * 4 + e;
                int col = bn + wc * 64 + u * 16 + r;
                Cb[(size_t)row * N + col] = f2bf(acc[t][u][e]);
            }
}

// ---------------- GEMM (N=256) + fused bias + residual + LayerNorm ----------------
// block tile BM x 256: 4 waves, wave w covers cols [w*64, w*64+64).
template <int BM, int K>
__global__ __launch_bounds__(256) void gemm_ln(
    const u16* __restrict__ A, const u16* __restrict__ W,
    const float* __restrict__ bias,
    const float* __restrict__ lng, const float* __restrict__ lnb,
    float* __restrict__ h, u16* __restrict__ hbf) {
    constexpr int BK = 32;
    constexpr int NK = K / BK;
    constexpr int MT = BM / 16;
    int tid = threadIdx.x;
    int w = tid >> 6, lane = tid & 63;
    int g = lane >> 4, r = lane & 15;
    int bm = blockIdx.x * BM;
    __shared__ __align__(16) u16 Ab[2][BM * BK];
    __shared__ __align__(16) u16 Bb[2][256 * BK];
    __shared__ float sums[BM][4][2];
    int srd = lane >> 2;
    int schunk = ((lane & 3) ^ ((lane >> 3) & 3)) * 8;
    auto stage = [&](int buf, int k0) {
        if (w < MT)
            gload_lds16(A + (size_t)(bm + w * 16 + srd) * K + k0 + schunk,
                        &Ab[buf][(w * 16) * BK]);
#pragma unroll
        for (int i = 0; i < 4; ++i)
            gload_lds16(W + (size_t)(w * 64 + i * 16 + srd) * K + k0 + schunk,
                        &Bb[buf][(w * 64 + i * 16) * BK]);
    };
    f32x4 acc[MT][4] = {};
    stage(0, 0);
    __syncthreads();
    int rs = (r >> 1) & 3;
    for (int st = 0; st < NK; ++st) {
        int cur = st & 1;
        if (st + 1 < NK) stage(cur ^ 1, (st + 1) * BK);
        const u16* Al = &Ab[cur][0];
        const u16* Bl = &Bb[cur][0];
        bf16x8 bf[4];
#pragma unroll
        for (int u = 0; u < 4; ++u)
            bf[u] = *(const bf16x8*)(Bl + (w * 64 + u * 16 + r) * BK + ((g ^ rs) * 8));
#pragma unroll
        for (int t = 0; t < MT; ++t) {
            bf16x8 af = *(const bf16x8*)(Al + (t * 16 + r) * BK + ((g ^ rs) * 8));
#pragma unroll
            for (int u = 0; u < 4; ++u)
                acc[t][u] = __builtin_amdgcn_mfma_f32_16x16x32_bf16(af, bf[u], acc[t][u], 0, 0, 0);
        }
        __syncthreads();
    }
    float val[MT][4][4];
#pragma unroll
    for (int t = 0; t < MT; ++t)
#pragma unroll
        for (int e = 0; e < 4; ++e) {
            int row = bm + t * 16 + g * 4 + e;
            float s1 = 0.f, s2 = 0.f;
#pragma unroll
            for (int u = 0; u < 4; ++u) {
                int col = w * 64 + u * 16 + r;
                float v = acc[t][u][e] + bias[col] + h[(size_t)row * kC + col];
                val[t][u][e] = v;
                s1 += v;
                s2 += v * v;
            }
            s1 = dpp_ror_add16(s1);
            s2 = dpp_ror_add16(s2);
            if (r == 0) {
                sums[t * 16 + g * 4 + e][w][0] = s1;
                sums[t * 16 + g * 4 + e][w][1] = s2;
            }
        }
    __syncthreads();
#pragma unroll
    for (int t = 0; t < MT; ++t)
#pragma unroll
        for (int e = 0; e < 4; ++e) {
            int lr = t * 16 + g * 4 + e;
            int row = bm + lr;
            float S1 = sums[lr][0][0] + sums[lr][1][0] + sums[lr][2][0] + sums[lr][3][0];
            float S2 = sums[lr][0][1] + sums[lr][1][1] + sums[lr][2][1] + sums[lr][3][1];
            float mu = S1 * (1.f / kC);
            float rstd = rsqrtf(S2 * (1.f / kC) - mu * mu + 1e-5f);
#pragma unroll
            for (int u = 0; u < 4; ++u) {
                int col = w * 64 + u * 16 + r;
                float y = (val[t][u][e] - mu) * rstd * lng[col] + lnb[col];
                h[(size_t)row * kC + col] = y;
                hbf[(size_t)row * kC + col] = f2bf(y);
            }
        }
}

// ---------------- GATv2: per-node online softmax aggregation + fused residual LN ----
__global__ __launch_bounds__(256) void gat_agg(
    const u16* __restrict__ xg,
    const float* __restrict__ att, const float* __restrict__ gb,
    const int* __restrict__ off, const int* __restrict__ srcs,
    const float* __restrict__ lng, const float* __restrict__ lnb,
    float* __restrict__ h, u16* __restrict__ hbf) {
    int n = blockIdx.x;
    int w = threadIdx.x >> 6, lane = threadIdx.x & 63;
    int q = lane >> 4, t = lane & 15;
    int cb = w * 256 + t * 16;   // channel slice [cb, cb+16) of 1024

    uint4 xru0 = *(const uint4*)(xg + (size_t)n * 2048 + 1024 + cb);
    uint4 xru1 = *(const uint4*)(xg + (size_t)n * 2048 + 1024 + cb + 8);
    float xrv[16];
    unpack8(xru0, xrv); unpack8(xru1, xrv + 8);
    float att6[16], att4[16];
#pragma unroll
    for (int j = 0; j < 16; j += 4) {
        float4 a4 = *(const float4*)(att + cb + j);
        att6[j] = 0.6f * a4.x; att6[j + 1] = 0.6f * a4.y;
        att6[j + 2] = 0.6f * a4.z; att6[j + 3] = 0.6f * a4.w;
        att4[j] = (2.f / 3.f) * att6[j]; att4[j + 1] = (2.f / 3.f) * att6[j + 1];
        att4[j + 2] = (2.f / 3.f) * att6[j + 2]; att4[j + 3] = (2.f / 3.f) * att6[j + 3];
    }

    int i0 = off[n], i1 = off[n + 1];
    float m = -1e30f, ls = 0.f;
    float acc[16] = {};
    int i = i0 + q;
    uint4 p0a, p1a, p0b, p1b;
    if (i < i1) {
        int s = srcs[i];
        p0a = *(const uint4*)(xg + (size_t)s * 2048 + cb);
        p1a = *(const uint4*)(xg + (size_t)s * 2048 + cb + 8);
    }
    if (i + 4 < i1) {
        int s = srcs[i + 4];
        p0b = *(const uint4*)(xg + (size_t)s * 2048 + cb);
        p1b = *(const uint4*)(xg + (size_t)s * 2048 + cb + 8);
    }
    while (i < i1) {
        uint4 c0 = p0a, c1 = p1a;
        p0a = p0b; p1a = p1b;
        if (i + 8 < i1) {
            int s2 = srcs[i + 8];
            p0b = *(const uint4*)(xg + (size_t)s2 * 2048 + cb);
            p1b = *(const uint4*)(xg + (size_t)s2 * 2048 + cb + 8);
        }
        float x[16];
        unpack8(c0, x); unpack8(c1, x + 8);
        // 4 independent score chains (8-deep each) instead of one 32-deep chain
        float pp[4] = {0.f, 0.f, 0.f, 0.f};
#pragma unroll
        for (int j = 0; j < 16; ++j) {
            float e = x[j] + xrv[j];
            pp[j & 3] = fmaf(att6[j], e, pp[j & 3]);
            pp[j & 3] = fmaf(att4[j], __builtin_fabsf(e), pp[j & 3]);
        }
        float p = dpp_ror_add16((pp[0] + pp[1]) + (pp[2] + pp[3]));
        if (p > m) {            // quarter-uniform
            float c = __expf(m - p);
            ls = ls * c + 1.f;
#pragma unroll
            for (int j = 0; j < 16; ++j) acc[j] = acc[j] * c + x[j];
            m = p;
        } else {
            float pw = __expf(p - m);
            ls += pw;
#pragma unroll
            for (int j = 0; j < 16; ++j) acc[j] = fmaf(pw, x[j], acc[j]);
        }
        i += 4;
    }
    // exact LSE merge of the 4 quarter states
    float mm = fmaxf(m, __shfl_xor(m, 16));
    mm = fmaxf(mm, __shfl_xor(mm, 32));
    float c = __expf(m - mm);   // 0 for empty quarters (m = -1e30)
    ls *= c;
    ls += __shfl_xor(ls, 16);
    ls += __shfl_xor(ls, 32);
#pragma unroll
    for (int j = 0; j < 16; ++j) {
        float a = acc[j] * c;
        a += __shfl_xor(a, 16);
        a += __shfl_xor(a, 32);
        acc[j] = a;
    }
    float inv = 1.f / ls;
    __shared__ float red[4][256];
    __shared__ float rs[8];
    if (q == 0) {
#pragma unroll
        for (int j = 0; j < 16; ++j) red[w][t * 16 + j] = acc[j] * inv;
    }
    __syncthreads();
    int cc = threadIdx.x;
    float vsum = 0.25f * (red[0][cc] + red[1][cc] + red[2][cc] + red[3][cc]) + gb[cc];
    // fused residual + LayerNorm over the block's 256 channels
    float v = h[(size_t)n * kC + cc] + vsum;
    float s1 = v, s2 = v * v;
    for (int d = 1; d < 64; d <<= 1) { s1 += __shfl_xor(s1, d); s2 += __shfl_xor(s2, d); }
    if (lane == 0) { rs[w] = s1; rs[4 + w] = s2; }
    __syncthreads();
    s1 = rs[0] + rs[1] + rs[2] + rs[3];
    s2 = rs[4] + rs[5] + rs[6] + rs[7];
    float mu = s1 * (1.f / kC);
    float rstd = rsqrtf(s2 * (1.f / kC) - mu * mu + 1e-5f);
    float y = (v - mu) * rstd * lng[cc] + lnb[cc];
    h[(size_t)n * kC + cc] = y;
    hbf[(size_t)n * kC + cc] = f2bf(y);
}

// ---------------- MFMA flash attention, LDS-shared K/V, split-K ----------------
__global__ __launch_bounds__(256, 4) void mha_mfma2(
    const u16* __restrict__ Qb, const u16* __restrict__ Kb,
    const u16* __restrict__ VTb, float* __restrict__ opart, float* __restrict__ mlpart) {
    int qt = blockIdx.x, head = blockIdx.y, sp = blockIdx.z;
    int tid = threadIdx.x;
    int w = tid >> 6, lane = tid & 63;
    int g = lane >> 4, r = lane & 15;
    int q0 = qt * 64;
    const u16* Qh = Qb + ((size_t)head * kN + q0 + w * 16) * 64;
    const u16* Kh = Kb + (size_t)head * kN * 64;
    const u16* VTh = VTb + (size_t)head * 64 * kN;
    __shared__ u16 Kt[2][64 * 64];
    __shared__ u16 Vt[2][64 * 64];
    __shared__ u16 plds[4][16 * 64];
    int srow = w * 8 + (lane >> 3);
    int schunk = ((lane & 7) ^ ((lane >> 3) & 7)) * 8;
    int kbase = sp * KSPAN;

    bf16x8 qf0 = *(const bf16x8*)(Qh + r * 64 + g * 8);
    bf16x8 qf1 = *(const bf16x8*)(Qh + r * 64 + 32 + g * 8);

    auto stage = [&](int buf, int k0) {
#pragma unroll
        for (int i = 0; i < 2; ++i) {
            int row = i * 32 + srow;
            gload_lds16(Kh + (size_t)(k0 + row) * 64 + schunk, &Kt[buf][(i * 32 + w * 8) * 64]);
            gload_lds16(VTh + (size_t)row * kN + k0 + schunk, &Vt[buf][(i * 32 + w * 8) * 64]);
        }
    };

    f32x4 o[4] = {};
    float m = -3.0e38f, l = 0.f;

    stage(0, kbase);
    __syncthreads();

    int rx = r & 7;
    for (int st = 0; st < NSTEP; ++st) {
        int cur = st & 1;
        if (st + 1 < NSTEP) stage(cur ^ 1, kbase + (st + 1) * 64);
        const u16* Kl = &Kt[cur][0];
        const u16* Vl = &Vt[cur][0];
        f32x4 stt[4] = {};
#pragma unroll
        for (int t = 0; t < 4; ++t) {
            bf16x8 kf0 = *(const bf16x8*)(Kl + (16 * t + r) * 64 + ((0 + g) ^ rx) * 8);
            bf16x8 kf1 = *(const bf16x8*)(Kl + (16 * t + r) * 64 + ((4 + g) ^ rx) * 8);
            stt[t] = __builtin_amdgcn_mfma_f32_16x16x32_bf16(kf0, qf0, stt[t], 0, 0, 0);
            stt[t] = __builtin_amdgcn_mfma_f32_16x16x32_bf16(kf1, qf1, stt[t], 0, 0, 0);
        }
        float pm = stt[0][0];
#pragma unroll
        for (int t = 0; t < 4; ++t)
#pragma unroll
            for (int e = 0; e < 4; ++e) pm = fmaxf(pm, stt[t][e]);
        pm = fmaxf(pm, __shfl_xor(pm, 16));
        pm = fmaxf(pm, __shfl_xor(pm, 32));
        if (__any(pm > m)) {
            float mn = fmaxf(m, pm);
            float corr = __builtin_amdgcn_exp2f(m - mn);
            l *= corr;
            float corrq[4];
#pragma unroll
            for (int e = 0; e < 4; ++e) corrq[e] = __shfl(corr, g * 4 + e);
#pragma unroll
            for (int dt = 0; dt < 4; ++dt)
#pragma unroll
                for (int e = 0; e < 4; ++e) o[dt][e] *= corrq[e];
            m = mn;
        }
        float ls = 0.f;
        float p[4][4];
#pragma unroll
        for (int t = 0; t < 4; ++t)
#pragma unroll
            for (int e = 0; e < 4; ++e) { p[t][e] = __builtin_amdgcn_exp2f(stt[t][e] - m); ls += p[t][e]; }
        ls += __shfl_xor(ls, 16);
        ls += __shfl_xor(ls, 32);
        l += ls;
#pragma unroll
        for (int t = 0; t < 4; ++t) {
            ushort4 pk;
            pk.x = f2bf(p[t][0]); pk.y = f2bf(p[t][1]);
            pk.z = f2bf(p[t][2]); pk.w = f2bf(p[t][3]);
            int lc = (2 * t + (g >> 1)) ^ rx;
            *(ushort4*)(&plds[w][r * 64 + lc * 8 + (g & 1) * 4]) = pk;
        }
        bf16x8 pa0 = *(const bf16x8*)(&plds[w][r * 64 + (g ^ rx) * 8]);
        bf16x8 pa1 = *(const bf16x8*)(&plds[w][r * 64 + ((4 + g) ^ rx) * 8]);
#pragma unroll
        for (int dt = 0; dt < 4; ++dt) {
            bf16x8 vf0 = *(const bf16x8*)(Vl + (dt * 16 + r) * 64 + ((0 + g) ^ rx) * 8);
            bf16x8 vf1 = *(const bf16x8*)(Vl + (dt * 16 + r) * 64 + ((4 + g) ^ rx) * 8);
            o[dt] = __builtin_amdgcn_mfma_f32_16x16x32_bf16(pa0, vf0, o[dt], 0, 0, 0);
            o[dt] = __builtin_amdgcn_mfma_f32_16x16x32_bf16(pa1, vf1, o[dt], 0, 0, 0);
        }
        __syncthreads();
    }

    size_t slot = (size_t)(head * 64 + qt) * NSPLIT + sp;
    float* ob = opart + slot * 4096;
#pragma unroll
    for (int dt = 0; dt < 4; ++dt)
#pragma unroll
        for (int e = 0; e < 4; ++e)
            ob[(w * 16 + g * 4 + e) * 64 + dt * 16 + r] = o[dt][e];
    float* mlb = mlpart + slot * 128;
    if (g == 0) { mlb[w * 16 + r] = m; mlb[64 + w * 16 + r] = l; }
}

// ---------------- merge split-K attention partials -> attnb (bf16) ----------------
__global__ __launch_bounds__(256) void mha_merge(
    const float* __restrict__ opart, const float* __restrict__ mlpart,
    u16* __restrict__ attnb) {
    int head = blockIdx.y;
    int q = blockIdx.x * 4 + (threadIdx.x >> 6);
    int d = threadIdx.x & 63;
    int qt = q >> 6, ql = q & 63;
    size_t sb = (size_t)(head * 64 + qt) * NSPLIT;
    float ms[NSPLIT], lsv[NSPLIT];
    float mstar = -3.0e38f;
#pragma unroll
    for (int s = 0; s < NSPLIT; ++s) {
        ms[s] = mlpart[(sb + s) * 128 + ql];
        lsv[s] = mlpart[(sb + s) * 128 + 64 + ql];
        mstar = fmaxf(mstar, ms[s]);
    }
    float acc = 0.f, lsum = 0.f;
#pragma unroll
    for (int s = 0; s < NSPLIT; ++s) {
        float wgt = __builtin_amdgcn_exp2f(ms[s] - mstar);
        lsum += lsv[s] * wgt;
        acc += opart[(sb + s) * 4096 + ql * 64 + d] * wgt;
    }
    attnb[(size_t)q * kC + head * 64 + d] = f2bf(acc / lsum);
}

// ---------------- final: out[4096,2] = t_bf @ out_w2^T + b2; wave per row ----------------
__global__ __launch_bounds__(256) void final_out(
    const u16* __restrict__ tbf, const float* __restrict__ w2,
    const float* __restrict__ b2, float* __restrict__ out) {
    int row = blockIdx.x * 4 + (threadIdx.x >> 6);
    int lane = threadIdx.x & 63;
    const ushort4 tv = *(const ushort4*)(tbf + (size_t)row * 256 + lane * 4);
    float t0 = bf2f(tv.x), t1 = bf2f(tv.y), t2 = bf2f(tv.z), t3 = bf2f(tv.w);
    const float4 w0 = *(const float4*)(w2 + lane * 4);
    const float4 w1 = *(const float4*)(w2 + 256 + lane * 4);
    float d0 = t0 * w0.x + t1 * w0.y + t2 * w0.z + t3 * w0.w;
    float d1 = t0 * w1.x + t1 * w1.y + t2 * w1.z + t3 * w1.w;
    for (int d = 1; d < 64; d <<= 1) { d0 += __shfl_xor(d0, d); d1 += __shfl_xor(d1, d); }
    if (lane == 0) {
        out[(size_t)row * 2 + 0] = d0 + b2[0];
        out[(size_t)row * 2 + 1] = d1 + b2[1];
    }
}

extern "C" void kernel_launch(void* const* d_in, const int* in_sizes, int n_in,
                              void* d_out, int out_size, void* d_ws, size_t ws_size,
                              hipStream_t stream) {
    (void)in_sizes; (void)n_in; (void)out_size;
    const float* x        = (const float*)d_in[0];
    const int*   ei       = (const int*)d_in[1];
    const float* in_w     = (const float*)d_in[2];
    const float* in_b     = (const float*)d_in[3];
    const float* gat_wl   = (const float*)d_in[4];
    const float* gat_wr   = (const float*)d_in[5];
    const float* gat_att  = (const float*)d_in[6];
    const float* gat_b    = (const float*)d_in[7];
    const float* mha_in_w = (const float*)d_in[8];
    const float* mha_in_b = (const float*)d_in[9];
    const float* mha_out_w= (const float*)d_in[10];
    const float* mha_out_b= (const float*)d_in[11];
    const float* ln1_g = (const float*)d_in[12];
    const float* ln1_b = (const float*)d_in[13];
    const float* ln2_g = (const float*)d_in[14];
    const float* ln2_b = (const float*)d_in[15];
    const float* ln3_g = (const float*)d_in[16];
    const float* ln3_b = (const float*)d_in[17];
    const float* ffn_w1 = (const float*)d_in[18];
    const float* ffn_b1 = (const float*)d_in[19];
    const float* ffn_w2 = (const float*)d_in[20];
    const float* ffn_b2 = (const float*)d_in[21];
    const float* out_w1 = (const float*)d_in[22];
    const float* out_b1 = (const float*)d_in[23];
    const float* out_w2 = (const float*)d_in[24];
    const float* out_b2 = (const float*)d_in[25];
    float* out = (float*)d_out;

    char* ws = (char*)d_ws;
    size_t off = 0;
    auto alloc = [&](size_t bytes) -> void* {
        void* p = (void*)(ws + off);
        off += (bytes + 255) & ~(size_t)255;
        return p;
    };
    float* h     = (float*)alloc((size_t)kN * kC * 4);
    u16*   hbf   = (u16*)  alloc((size_t)kN * kC * 2);
    float* xlb   = (float*)alloc((size_t)kN * 1024 * 4);   // slot reused: xgbf / Qb+Kb+VTb
    float* xrb   = (float*)alloc((size_t)kN * 1024 * 4);   // slot reused: opart
    float* locb  = (float*)alloc((size_t)kN * kC * 4);     // slot reused: mlpart
    u16*   attnb = (u16*)  alloc((size_t)kN * kC * 2);
    u16*   midb  = (u16*)  alloc((size_t)kN * 512 * 2);
    u16*   tbf   = (u16*)  alloc((size_t)kN * kC * 2);
    u16*   xbf   = (u16*)  alloc((size_t)kN * kIn * 2);
    u16*   wbf   = (u16*)  alloc((size_t)3342336 * 2);
    int*   coff  = (int*)  alloc((size_t)4097 * 4);
    int*   ccur  = (int*)  alloc((size_t)4096 * 4);
    int*   csrc  = (int*)  alloc((size_t)kET * 4);
    if (ws_size < off) return;  // not enough scratch: bail loudly (output stays poisoned)

    u16* xgbf = (u16*)xlb;                      // [4096][2048] bf16 (xl|xr fused)
    u16* Qb  = (u16*)xlb;                       // [4][4096][64]
    u16* Kb  = Qb + (size_t)4 * kN * 64;        // [4][4096][64]
    u16* VTb = Kb + (size_t)4 * kN * 64;        // [4][64][4096]
    float* opart  = xrb;                        // 1024 slots x 4096 f32 = 16 MB exact
    float* mlpart = locb;

    // bf16 weight buffer offsets (elements); gat wl/wr interleaved per layer [2048][256]
    const size_t OFF_INW  = 0;
    const size_t OFF_GAT  = 131072;
    const size_t OFF_MIN  = 1703936;
    const size_t OFF_MOUT = 2293760;
    const size_t OFF_F1   = 2490368;
    const size_t OFF_F2   = 2883584;
    const size_t OFF_O1   = 3276800;

    // one fused cast of x + all weights (region table inside the kernel)
    cast_all<<<dim3((1359872 + 255) / 256), dim3(256), 0, stream>>>(
        x, in_w, gat_wl, gat_wr, mha_in_w, mha_out_w, ffn_w1, ffn_w2, out_w1,
        xbf, wbf);

    // CSR build (once per launch; same graph for all layers)
    hipMemsetAsync(ccur, 0, 4096 * 4, stream);
    csr_count<<<dim3((kET + 255) / 256), dim3(256), 0, stream>>>(ei, ccur);
    csr_scan<<<dim3(1), dim3(1024), 0, stream>>>(ccur, coff);
    csr_scatter<<<dim3((kET + 255) / 256), dim3(256), 0, stream>>>(ei, ccur, csrc);

    // input projection: h = x @ in_w^T + in_b  (fp32 + bf16 outputs)
    gemm_st<64, 512, 0, 1, 1><<<dim3(kC / 64, kN / 64), dim3(256), 0, stream>>>(
        xbf, wbf + OFF_INW, in_b, h, hbf, kC);

    for (int l = 0; l < kL; ++l) {
        // GATv2 transforms: fused wl|wr 128x128-tile GEMM -> xgbf [4096][2048]
        gemm_128<256><<<dim3(2048 / 128, kN / 128), dim3(256), 0, stream>>>(
            hbf, wbf + OFF_GAT + (size_t)l * 524288, xgbf, 2048);
        // gat_agg with fused residual + ln1 (writes h, hbf directly)
        gat_agg<<<dim3(kN), dim3(256), 0, stream>>>(
            xgbf, gat_att + (size_t)l * 1024, gat_b + (size_t)l * kC, coff, csrc,
            ln1_g + (size_t)l * kC, ln1_b + (size_t)l * kC, h, hbf);

        // MHA: fused qkv GEMM writes Qb/Kb/VTb directly (repack eliminated)
        gemm_qkv<<<dim3(768 / 64, kN / 128), dim3(256), 0, stream>>>(
            hbf, wbf + OFF_MIN + (size_t)l * 768 * kC, mha_in_b + (size_t)l * 768,
            Qb, Kb, VTb);
        mha_mfma2<<<dim3(kN / 64, 4, NSPLIT), dim3(256), 0, stream>>>(Qb, Kb, VTb, opart, mlpart);
        mha_merge<<<dim3(kN / 4, 4), dim3(256), 0, stream>>>(opart, mlpart, attnb);
        // mout GEMM + fused residual + ln2
        gemm_ln<16, 256><<<dim3(kN / 16), dim3(256), 0, stream>>>(
            attnb, wbf + OFF_MOUT + (size_t)l * kC * kC, mha_out_b + (size_t)l * kC,
            ln2_g + (size_t)l * kC, ln2_b + (size_t)l * kC, h, hbf);

        // FFN
        gemm_st<64, 256, 1, 0, 1><<<dim3(512 / 64, kN / 64), dim3(256), 0, stream>>>(
            hbf, wbf + OFF_F1 + (size_t)l * 512 * kC, ffn_b1 + (size_t)l * 512, nullptr, midb, 512);
        // ffn2 GEMM + fused residual + ln3
        gemm_ln<16, 512><<<dim3(kN / 16), dim3(256), 0, stream>>>(
            midb, wbf + OFF_F2 + (size_t)l * kC * 512, ffn_b2 + (size_t)l * kC,
            ln3_g + (size_t)l * kC, ln3_b + (size_t)l * kC, h, hbf);
    }

    // output head
    gemm_st<64, 256, 1, 0, 1><<<dim3(kC / 64, kN / 64), dim3(256), 0, stream>>>(
        hbf, wbf + OFF_O1, out_b1, nullptr, tbf, kC);
    final_out<<<dim3(kN / 4), dim3(256), 0, stream>>>(tbf, out_w2, out_b2, out);
}

// Round 13
// 477.249 us; speedup vs baseline: 10.0961x; 1.0038x over previous
//
#include <hip/hip_runtime.h>
#include <cstdint>
#include <cstddef>

typedef unsigned short u16;
typedef __bf16 bf16x8 __attribute__((ext_vector_type(8)));
typedef float f32x4 __attribute__((ext_vector_type(4)));

constexpr int kN  = 4096;
constexpr int kE  = 131072;
constexpr int kET = kE + kN;   // with self loops
constexpr int kIn = 512;
constexpr int kC  = 256;
constexpr int kL  = 3;

constexpr int NSPLIT = 4;
constexpr int KSPAN  = kN / NSPLIT;  // 1024 keys per split
constexpr int NSTEP  = KSPAN / 64;   // 16 steps of 64 keys

__device__ __forceinline__ u16 f2bf(float f) {
    unsigned u = __builtin_bit_cast(unsigned, f);
    u += 0x7fffu + ((u >> 16) & 1u);
    return (u16)(u >> 16);
}
__device__ __forceinline__ float bf2f(u16 s) {
    unsigned u = ((unsigned)s) << 16;
    return __builtin_bit_cast(float, u);
}
__device__ __forceinline__ float gelu_erf(float x) {
    return 0.5f * x * (1.f + erff(x * 0.70710678118654752f));
}
// async global->LDS, 16B per lane; ldst must be wave-uniform base (HW adds lane*16)
__device__ __forceinline__ void gload_lds16(const u16* gsrc, u16* ldst) {
    __builtin_amdgcn_global_load_lds(
        (const __attribute__((address_space(1))) unsigned int*)gsrc,
        (__attribute__((address_space(3))) unsigned int*)ldst, 16, 0, 0);
}
// sum over each row of 16 lanes via DPP row_ror adds (full-rate VALU, no LDS pipe)
__device__ __forceinline__ float dpp_ror_add16(float x) {
    int t;
    t = __builtin_amdgcn_update_dpp(0, __builtin_bit_cast(int, x), 0x121, 0xf, 0xf, true);
    x += __builtin_bit_cast(float, t);
    t = __builtin_amdgcn_update_dpp(0, __builtin_bit_cast(int, x), 0x122, 0xf, 0xf, true);
    x += __builtin_bit_cast(float, t);
    t = __builtin_amdgcn_update_dpp(0, __builtin_bit_cast(int, x), 0x124, 0xf, 0xf, true);
    x += __builtin_bit_cast(float, t);
    t = __builtin_amdgcn_update_dpp(0, __builtin_bit_cast(int, x), 0x128, 0xf, 0xf, true);
    x += __builtin_bit_cast(float, t);
    return x;
}
// unpack 8 bf16 (uint4) -> 8 f32
__device__ __forceinline__ void unpack8(uint4 u, float* x) {
    x[0] = __builtin_bit_cast(float, u.x << 16);
    x[1] = __builtin_bit_cast(float, u.x & 0xffff0000u);
    x[2] = __builtin_bit_cast(float, u.y << 16);
    x[3] = __builtin_bit_cast(float, u.y & 0xffff0000u);
    x[4] = __builtin_bit_cast(float, u.z << 16);
    x[5] = __builtin_bit_cast(float, u.z & 0xffff0000u);
    x[6] = __builtin_bit_cast(float, u.w << 16);
    x[7] = __builtin_bit_cast(float, u.w & 0xffff0000u);
}

// ---------------- fused fp32->bf16 cast of ALL weights + x (one dispatch) ----------
__global__ void cast_all(
    const float* __restrict__ x, const float* __restrict__ in_w,
    const float* __restrict__ gwl, const float* __restrict__ gwr,
    const float* __restrict__ minw, const float* __restrict__ moutw,
    const float* __restrict__ f1, const float* __restrict__ f2,
    const float* __restrict__ o1,
    u16* __restrict__ xbf, u16* __restrict__ wbf) {
    int i = blockIdx.x * 256 + threadIdx.x;
    if (i >= 1359872) return;
    const float* s;
    u16* dbase;
    int sj, dj;
    if (i < 524288) {                       // x: 4096x512
        s = x; dbase = xbf; sj = i; dj = i;
    } else if (i < 557056) {                // in_w
        s = in_w; dbase = wbf; sj = i - 524288; dj = sj;
    } else if (i < 753664) {                // gat_wl (interleaved)
        int j = i - 557056; int l = j >> 16, wi = j & 65535;
        s = gwl; dbase = wbf; sj = j; dj = 32768 + l * 131072 + wi;
    } else if (i < 950272) {                // gat_wr (interleaved, +65536)
        int j = i - 753664; int l = j >> 16, wi = j & 65535;
        s = gwr; dbase = wbf; sj = j; dj = 32768 + l * 131072 + 65536 + wi;
    } else if (i < 1097728) {               // mha_in_w
        s = minw; dbase = wbf; sj = i - 950272; dj = 425984 + sj;
    } else if (i < 1146880) {               // mha_out_w
        s = moutw; dbase = wbf; sj = i - 1097728; dj = 573440 + sj;
    } else if (i < 1245184) {               // ffn_w1
        s = f1; dbase = wbf; sj = i - 1146880; dj = 622592 + sj;
    } else if (i < 1343488) {               // ffn_w2
        s = f2; dbase = wbf; sj = i - 1245184; dj = 720896 + sj;
    } else {                                // out_w1
        s = o1; dbase = wbf; sj = i - 1343488; dj = 819200 + sj;
    }
    float4 v = ((const float4*)s)[sj];
    ushort4 o;
    o.x = f2bf(v.x); o.y = f2bf(v.y); o.z = f2bf(v.z); o.w = f2bf(v.w);
    ((ushort4*)dbase)[dj] = o;
}

// ---------------- CSR build (by dst) ----------------
__global__ void csr_count(const int* __restrict__ ei, int* __restrict__ cnt) {
    int e = blockIdx.x * 256 + threadIdx.x;
    if (e >= kET) return;
    int d = (e < kE) ? ei[kE + e] : (e - kE);
    atomicAdd(cnt + d, 1);
}

__global__ __launch_bounds__(1024) void csr_scan(int* __restrict__ cnt_cur, int* __restrict__ off) {
    __shared__ int lds[1024];
    int t = threadIdx.x;
    int c[4], s = 0;
#pragma unroll
    for (int j = 0; j < 4; ++j) { c[j] = cnt_cur[t * 4 + j]; s += c[j]; }
    lds[t] = s;
    __syncthreads();
    for (int d = 1; d < 1024; d <<= 1) {
        int v = (t >= d) ? lds[t - d] : 0;
        __syncthreads();
        lds[t] += v;
        __syncthreads();
    }
    int excl = lds[t] - s;
#pragma unroll
    for (int j = 0; j < 4; ++j) { off[t * 4 + j] = excl; cnt_cur[t * 4 + j] = excl; excl += c[j]; }
    if (t == 1023) off[4096] = excl;
}

__global__ void csr_scatter(const int* __restrict__ ei, int* __restrict__ cur, int* __restrict__ csrc) {
    int e = blockIdx.x * 256 + threadIdx.x;
    if (e >= kET) return;
    int s, d;
    if (e < kE) { s = ei[e]; d = ei[kE + e]; } else { s = d = e - kE; }
    int pos = atomicAdd(cur + d, 1);
    csrc[pos] = s;
}

// ---------------- staged bf16 MFMA GEMM: C[M,N] = act(A[M,K] @ W[N,K]^T + bias) ----
template <int BM, int K, int ACT, int WF32, int WBF16>
__global__ __launch_bounds__(256) void gemm_st(
    const u16* __restrict__ A, const u16* __restrict__ W,
    const float* __restrict__ bias, float* __restrict__ Cf,
    u16* __restrict__ Cb, int N) {
    constexpr int BK = 32;
    constexpr int NK = K / BK;
    constexpr int MF = BM / 32;          // A fragments per wave
    int tid = threadIdx.x;
    int w = tid >> 6, lane = tid & 63;
    int wr = w >> 1, wc = w & 1;
    int g = lane >> 4, r = lane & 15;
    int bm = blockIdx.y * BM;
    int bn = blockIdx.x * 64;
    __shared__ __align__(16) u16 Ab[2][BM * BK];
    __shared__ __align__(16) u16 Bb[2][64 * BK];
    int srow = w * 16 + (lane >> 2);
    int scol = (lane & 3) * 8;
    auto stage = [&](int buf, int k0) {
#pragma unroll
        for (int i = 0; i < BM / 64; ++i)
            gload_lds16(A + (size_t)(bm + i * 64 + srow) * K + k0 + scol,
                        &Ab[buf][(i * 64 + w * 16) * BK]);
        gload_lds16(W + (size_t)(bn + srow) * K + k0 + scol, &Bb[buf][w * 16 * BK]);
    };
    f32x4 acc[MF][2] = {};
    stage(0, 0);
    __syncthreads();
    for (int st = 0; st < NK; ++st) {
        int cur = st & 1;
        if (st + 1 < NK) stage(cur ^ 1, (st + 1) * BK);
        const u16* Al = &Ab[cur][0];
        const u16* Bl = &Bb[cur][0];
        bf16x8 bf[2];
#pragma unroll
        for (int u = 0; u < 2; ++u)
            bf[u] = *(const bf16x8*)(Bl + (wc * 32 + u * 16 + r) * BK + g * 8);
#pragma unroll
        for (int t = 0; t < MF; ++t) {
            bf16x8 af = *(const bf16x8*)(Al + (wr * (BM / 2) + t * 16 + r) * BK + g * 8);
#pragma unroll
            for (int u = 0; u < 2; ++u)
                acc[t][u] = __builtin_amdgcn_mfma_f32_16x16x32_bf16(af, bf[u], acc[t][u], 0, 0, 0);
        }
        __syncthreads();
    }
    int r0 = bm + wr * (BM / 2) + g * 4;
    int c0 = bn + wc * 32 + r;
#pragma unroll
    for (int t = 0; t < MF; ++t)
#pragma unroll
        for (int u = 0; u < 2; ++u)
#pragma unroll
            for (int e = 0; e < 4; ++e) {
                int row = r0 + t * 16 + e, col = c0 + u * 16;
                float v = acc[t][u][e];
                if (bias) v += bias[col];
                if (ACT == 1) v = gelu_erf(v);
                if (WF32) Cf[(size_t)row * N + col] = v;
                if (WBF16) Cb[(size_t)row * N + col] = f2bf(v);
            }
}

// ---------------- fused qkv GEMM: writes Qb/Kb [head][n][64] and VTb [head][d][n] ---
__global__ __launch_bounds__(256) void gemm_qkv(
    const u16* __restrict__ A, const u16* __restrict__ W,
    const float* __restrict__ bias,
    u16* __restrict__ Qb, u16* __restrict__ Kb, u16* __restrict__ VTb) {
    constexpr int BK = 32, K = 256, NK = 8, BM = 128, MF = 4;
    int tid = threadIdx.x;
    int w = tid >> 6, lane = tid & 63;
    int wr = w >> 1, wc = w & 1;
    int g = lane >> 4, r = lane & 15;
    int bm = blockIdx.y * BM;
    int bn = blockIdx.x * 64;
    __shared__ __align__(16) u16 Ab[2][BM * BK];
    __shared__ __align__(16) u16 Bb[2][64 * BK];
    int srow = w * 16 + (lane >> 2);
    int scol = (lane & 3) * 8;
    auto stage = [&](int buf, int k0) {
#pragma unroll
        for (int i = 0; i < 2; ++i)
            gload_lds16(A + (size_t)(bm + i * 64 + srow) * K + k0 + scol,
                        &Ab[buf][(i * 64 + w * 16) * BK]);
        gload_lds16(W + (size_t)(bn + srow) * K + k0 + scol, &Bb[buf][w * 16 * BK]);
    };
    f32x4 acc[MF][2] = {};
    stage(0, 0);
    __syncthreads();
    for (int st = 0; st < NK; ++st) {
        int cur = st & 1;
        if (st + 1 < NK) stage(cur ^ 1, (st + 1) * BK);
        const u16* Al = &Ab[cur][0];
        const u16* Bl = &Bb[cur][0];
        bf16x8 bf[2];
#pragma unroll
        for (int u = 0; u < 2; ++u)
            bf[u] = *(const bf16x8*)(Bl + (wc * 32 + u * 16 + r) * BK + g * 8);
#pragma unroll
        for (int t = 0; t < MF; ++t) {
            bf16x8 af = *(const bf16x8*)(Al + (wr * 64 + t * 16 + r) * BK + g * 8);
#pragma unroll
            for (int u = 0; u < 2; ++u)
                acc[t][u] = __builtin_amdgcn_mfma_f32_16x16x32_bf16(af, bf[u], acc[t][u], 0, 0, 0);
        }
        __syncthreads();
    }
    constexpr float QS = 0.125f * 1.4426950408889634f;  // 1/sqrt(DH) * log2(e)
    int region = blockIdx.x >> 2;        // 0=q, 1=k, 2=v
    int head = blockIdx.x & 3;
    int r0 = bm + wr * 64 + g * 4;
    if (region == 2) {
#pragma unroll
        for (int t = 0; t < MF; ++t)
#pragma unroll
            for (int u = 0; u < 2; ++u) {
                int d = wc * 32 + u * 16 + r;
                int col = bn + d;
                ushort4 vo;
                vo.x = f2bf(acc[t][u][0] + bias[col]);
                vo.y = f2bf(acc[t][u][1] + bias[col]);
                vo.z = f2bf(acc[t][u][2] + bias[col]);
                vo.w = f2bf(acc[t][u][3] + bias[col]);
                *(ushort4*)(VTb + ((size_t)head * 64 + d) * kN + r0 + t * 16) = vo;
            }
    } else {
        u16* dst = (region == 0) ? Qb : Kb;
        float sc = (region == 0) ? QS : 1.f;
#pragma unroll
        for (int t = 0; t < MF; ++t)
#pragma unroll
            for (int u = 0; u < 2; ++u)
#pragma unroll
                for (int e = 0; e < 4; ++e) {
                    int d = wc * 32 + u * 16 + r;
                    int row = r0 + t * 16 + e;
                    dst[((size_t)head * kN + row) * 64 + d] =
                        f2bf((acc[t][u][e] + bias[bn + d]) * sc);
                }
    }
}

// ---------------- 128x128-tile staged GEMM (bf16 out, no bias/act) ----------------
template <int K>
__global__ __launch_bounds__(256) void gemm_128(
    const u16* __restrict__ A, const u16* __restrict__ W,
    u16* __restrict__ Cb, int N) {
    constexpr int BK = 32;
    constexpr int NK = K / BK;
    int tid = threadIdx.x;
    int w = tid >> 6, lane = tid & 63;
    int wr = w >> 1, wc = w & 1;
    int g = lane >> 4, r = lane & 15;
    int bm = blockIdx.y * 128;
    int bn = blockIdx.x * 128;
    __shared__ __align__(16) u16 Ab[2][128 * BK];
    __shared__ __align__(16) u16 Bb[2][128 * BK];
    int srd = lane >> 2;
    int schunk = ((lane & 3) ^ ((lane >> 3) & 3)) * 8;
    auto stage = [&](int buf, int k0) {
#pragma unroll
        for (int i = 0; i < 2; ++i) {
            int rowA = bm + i * 64 + w * 16 + srd;
            int rowB = bn + i * 64 + w * 16 + srd;
            gload_lds16(A + (size_t)rowA * K + k0 + schunk, &Ab[buf][(i * 64 + w * 16) * BK]);
            gload_lds16(W + (size_t)rowB * K + k0 + schunk, &Bb[buf][(i * 64 + w * 16) * BK]);
        }
    };
    f32x4 acc[4][4] = {};
    stage(0, 0);
    __syncthreads();
    int rs = (r >> 1) & 3;
    for (int st = 0; st < NK; ++st) {
        int cur = st & 1;
        if (st + 1 < NK) stage(cur ^ 1, (st + 1) * BK);
        const u16* Al = &Ab[cur][0];
        const u16* Bl = &Bb[cur][0];
        bf16x8 bf[4];
#pragma unroll
        for (int u = 0; u < 4; ++u)
            bf[u] = *(const bf16x8*)(Bl + (wc * 64 + u * 16 + r) * BK + ((g ^ rs) * 8));
#pragma unroll
        for (int t = 0; t < 4; ++t) {
            bf16x8 af = *(const bf16x8*)(Al + (wr * 64 + t * 16 + r) * BK + ((g ^ rs) * 8));
#pragma unroll
            for (int u = 0; u < 4; ++u)
                acc[t][u] = __builtin_amdgcn_mfma_f32_16x16x32_bf16(af, bf[u], acc[t][u], 0, 0, 0);
        }
        __syncthreads();
    }
#pragma unroll
    for (int t = 0; t < 4; ++t)
#pragma unroll
        for (int u = 0; u < 4; ++u)
#pragma unroll
            for (int e = 0; e < 4; ++e) {
                int row = bm + wr * 64 + t * 16 + g * 4 + e;
                int col = bn + wc * 64 + u * 16 + r;
                Cb[(size_t)row * N + col] = f2bf(acc[t][u][e]);
            }
}

// ---------------- GEMM (N=256) + fused bias + residual + LayerNorm ----------------
template <int BM, int K>
__global__ __launch_bounds__(256) void gemm_ln(
    const u16* __restrict__ A, const u16* __restrict__ W,
    const float* __restrict__ bias,
    const float* __restrict__ lng, const float* __restrict__ lnb,
    float* __restrict__ h, u16* __restrict__ hbf) {
    constexpr int BK = 32;
    constexpr int NK = K / BK;
    constexpr int MT = BM / 16;
    int tid = threadIdx.x;
    int w = tid >> 6, lane = tid & 63;
    int g = lane >> 4, r = lane & 15;
    int bm = blockIdx.x * BM;
    __shared__ __align__(16) u16 Ab[2][BM * BK];
    __shared__ __align__(16) u16 Bb[2][256 * BK];
    __shared__ float sums[BM][4][2];
    int srd = lane >> 2;
    int schunk = ((lane & 3) ^ ((lane >> 3) & 3)) * 8;
    auto stage = [&](int buf, int k0) {
        if (w < MT)
            gload_lds16(A + (size_t)(bm + w * 16 + srd) * K + k0 + schunk,
                        &Ab[buf][(w * 16) * BK]);
#pragma unroll
        for (int i = 0; i < 4; ++i)
            gload_lds16(W + (size_t)(w * 64 + i * 16 + srd) * K + k0 + schunk,
                        &Bb[buf][(w * 64 + i * 16) * BK]);
    };
    f32x4 acc[MT][4] = {};
    stage(0, 0);
    __syncthreads();
    int rs = (r >> 1) & 3;
    for (int st = 0; st < NK; ++st) {
        int cur = st & 1;
        if (st + 1 < NK) stage(cur ^ 1, (st + 1) * BK);
        const u16* Al = &Ab[cur][0];
        const u16* Bl = &Bb[cur][0];
        bf16x8 bf[4];
#pragma unroll
        for (int u = 0; u < 4; ++u)
            bf[u] = *(const bf16x8*)(Bl + (w * 64 + u * 16 + r) * BK + ((g ^ rs) * 8));
#pragma unroll
        for (int t = 0; t < MT; ++t) {
            bf16x8 af = *(const bf16x8*)(Al + (t * 16 + r) * BK + ((g ^ rs) * 8));
#pragma unroll
            for (int u = 0; u < 4; ++u)
                acc[t][u] = __builtin_amdgcn_mfma_f32_16x16x32_bf16(af, bf[u], acc[t][u], 0, 0, 0);
        }
        __syncthreads();
    }
    float val[MT][4][4];
#pragma unroll
    for (int t = 0; t < MT; ++t)
#pragma unroll
        for (int e = 0; e < 4; ++e) {
            int row = bm + t * 16 + g * 4 + e;
            float s1 = 0.f, s2 = 0.f;
#pragma unroll
            for (int u = 0; u < 4; ++u) {
                int col = w * 64 + u * 16 + r;
                float v = acc[t][u][e] + bias[col] + h[(size_t)row * kC + col];
                val[t][u][e] = v;
                s1 += v;
                s2 += v * v;
            }
            s1 = dpp_ror_add16(s1);
            s2 = dpp_ror_add16(s2);
            if (r == 0) {
                sums[t * 16 + g * 4 + e][w][0] = s1;
                sums[t * 16 + g * 4 + e][w][1] = s2;
            }
        }
    __syncthreads();
#pragma unroll
    for (int t = 0; t < MT; ++t)
#pragma unroll
        for (int e = 0; e < 4; ++e) {
            int lr = t * 16 + g * 4 + e;
            int row = bm + lr;
            float S1 = sums[lr][0][0] + sums[lr][1][0] + sums[lr][2][0] + sums[lr][3][0];
            float S2 = sums[lr][0][1] + sums[lr][1][1] + sums[lr][2][1] + sums[lr][3][1];
            float mu = S1 * (1.f / kC);
            float rstd = rsqrtf(S2 * (1.f / kC) - mu * mu + 1e-5f);
#pragma unroll
            for (int u = 0; u < 4; ++u) {
                int col = w * 64 + u * 16 + r;
                float y = (val[t][u][e] - mu) * rstd * lng[col] + lnb[col];
                h[(size_t)row * kC + col] = y;
                hbf[(size_t)row * kC + col] = f2bf(y);
            }
        }
}

// ---------------- GATv2: per-node online softmax aggregation + fused residual LN ----
__global__ __launch_bounds__(256) void gat_agg(
    const u16* __restrict__ xg,
    const float* __restrict__ att, const float* __restrict__ gb,
    const int* __restrict__ off, const int* __restrict__ srcs,
    const float* __restrict__ lng, const float* __restrict__ lnb,
    float* __restrict__ h, u16* __restrict__ hbf) {
    int n = blockIdx.x;
    int w = threadIdx.x >> 6, lane = threadIdx.x & 63;
    int q = lane >> 4, t = lane & 15;
    int cb = w * 256 + t * 16;   // channel slice [cb, cb+16) of 1024

    uint4 xru0 = *(const uint4*)(xg + (size_t)n * 2048 + 1024 + cb);
    uint4 xru1 = *(const uint4*)(xg + (size_t)n * 2048 + 1024 + cb + 8);
    float xrv[16];
    unpack8(xru0, xrv); unpack8(xru1, xrv + 8);
    float att6[16], att4[16];
#pragma unroll
    for (int j = 0; j < 16; j += 4) {
        float4 a4 = *(const float4*)(att + cb + j);
        att6[j] = 0.6f * a4.x; att6[j + 1] = 0.6f * a4.y;
        att6[j + 2] = 0.6f * a4.z; att6[j + 3] = 0.6f * a4.w;
        att4[j] = (2.f / 3.f) * att6[j]; att4[j + 1] = (2.f / 3.f) * att6[j + 1];
        att4[j + 2] = (2.f / 3.f) * att6[j + 2]; att4[j + 3] = (2.f / 3.f) * att6[j + 3];
    }

    int i0 = off[n], i1 = off[n + 1];
    float m = -1e30f, ls = 0.f;
    float acc[16] = {};
    int i = i0 + q;
    uint4 p0a, p1a, p0b, p1b;
    if (i < i1) {
        int s = srcs[i];
        p0a = *(const uint4*)(xg + (size_t)s * 2048 + cb);
        p1a = *(const uint4*)(xg + (size_t)s * 2048 + cb + 8);
    }
    if (i + 4 < i1) {
        int s = srcs[i + 4];
        p0b = *(const uint4*)(xg + (size_t)s * 2048 + cb);
        p1b = *(const uint4*)(xg + (size_t)s * 2048 + cb + 8);
    }
    while (i < i1) {
        uint4 c0 = p0a, c1 = p1a;
        p0a = p0b; p1a = p1b;
        if (i + 8 < i1) {
            int s2 = srcs[i + 8];
            p0b = *(const uint4*)(xg + (size_t)s2 * 2048 + cb);
            p1b = *(const uint4*)(xg + (size_t)s2 * 2048 + cb + 8);
        }
        float x[16];
        unpack8(c0, x); unpack8(c1, x + 8);
        float p = 0.f;
#pragma unroll
        for (int j = 0; j < 16; ++j) {
            float e = x[j] + xrv[j];
            p = fmaf(att6[j], e, p);
            p = fmaf(att4[j], __builtin_fabsf(e), p);
        }
        p = dpp_ror_add16(p);   // all 16 lanes of the quarter now hold the score
        if (p > m) {            // quarter-uniform
            float c = __expf(m - p);
            ls = ls * c + 1.f;
#pragma unroll
            for (int j = 0; j < 16; ++j) acc[j] = acc[j] * c + x[j];
            m = p;
        } else {
            float pw = __expf(p - m);
            ls += pw;
#pragma unroll
            for (int j = 0; j < 16; ++j) acc[j] = fmaf(pw, x[j], acc[j]);
        }
        i += 4;
    }
    // exact LSE merge of the 4 quarter states
    float mm = fmaxf(m, __shfl_xor(m, 16));
    mm = fmaxf(mm, __shfl_xor(mm, 32));
    float c = __expf(m - mm);   // 0 for empty quarters (m = -1e30)
    ls *= c;
    ls += __shfl_xor(ls, 16);
    ls += __shfl_xor(ls, 32);
#pragma unroll
    for (int j = 0; j < 16; ++j) {
        float a = acc[j] * c;
        a += __shfl_xor(a, 16);
        a += __shfl_xor(a, 32);
        acc[j] = a;
    }
    float inv = 1.f / ls;
    __shared__ float red[4][256];
    __shared__ float rs[8];
    if (q == 0) {
#pragma unroll
        for (int j = 0; j < 16; ++j) red[w][t * 16 + j] = acc[j] * inv;
    }
    __syncthreads();
    int cc = threadIdx.x;
    float vsum = 0.25f * (red[0][cc] + red[1][cc] + red[2][cc] + red[3][cc]) + gb[cc];
    float v = h[(size_t)n * kC + cc] + vsum;
    float s1 = v, s2 = v * v;
    for (int d = 1; d < 64; d <<= 1) { s1 += __shfl_xor(s1, d); s2 += __shfl_xor(s2, d); }
    if (lane == 0) { rs[w] = s1; rs[4 + w] = s2; }
    __syncthreads();
    s1 = rs[0] + rs[1] + rs[2] + rs[3];
    s2 = rs[4] + rs[5] + rs[6] + rs[7];
    float mu = s1 * (1.f / kC);
    float rstd = rsqrtf(s2 * (1.f / kC) - mu * mu + 1e-5f);
    float y = (v - mu) * rstd * lng[cc] + lnb[cc];
    h[(size_t)n * kC + cc] = y;
    hbf[(size_t)n * kC + cc] = f2bf(y);
}

// ---------------- MFMA flash attention: 128 q-rows/block (2 q-sets per wave) ------
// Block = 4 waves; wave handles rows q0+w*16 (set A) and q0+64+w*16 (set B);
// kf/vf LDS reads shared across both sets -> half the LDS read traffic per q-row.
// Grid (kN/128, heads, NSPLIT). Staging / swizzles identical to the verified
// mha_mfma2 (chunk ^= row&7 on source; plds chunk ^= r&7). Defer-max per set.
__global__ __launch_bounds__(256, 2) void mha_mfma3(
    const u16* __restrict__ Qb, const u16* __restrict__ Kb,
    const u16* __restrict__ VTb, float* __restrict__ opart, float* __restrict__ mlpart) {
    int qt = blockIdx.x, head = blockIdx.y, sp = blockIdx.z;
    int tid = threadIdx.x;
    int w = tid >> 6, lane = tid & 63;
    int g = lane >> 4, r = lane & 15;
    int q0 = qt * 128;
    const u16* QhA = Qb + ((size_t)head * kN + q0 + w * 16) * 64;
    const u16* QhB = QhA + (size_t)64 * 64;
    const u16* Kh = Kb + (size_t)head * kN * 64;
    const u16* VTh = VTb + (size_t)head * 64 * kN;
    __shared__ u16 Kt[2][64 * 64];
    __shared__ u16 Vt[2][64 * 64];
    __shared__ u16 plds[4][2][16 * 64];
    int srow = w * 8 + (lane >> 3);
    int schunk = ((lane & 7) ^ ((lane >> 3) & 7)) * 8;
    int kbase = sp * KSPAN;

    bf16x8 qfA0 = *(const bf16x8*)(QhA + r * 64 + g * 8);
    bf16x8 qfA1 = *(const bf16x8*)(QhA + r * 64 + 32 + g * 8);
    bf16x8 qfB0 = *(const bf16x8*)(QhB + r * 64 + g * 8);
    bf16x8 qfB1 = *(const bf16x8*)(QhB + r * 64 + 32 + g * 8);

    auto stage = [&](int buf, int k0) {
#pragma unroll
        for (int i = 0; i < 2; ++i) {
            int row = i * 32 + srow;
            gload_lds16(Kh + (size_t)(k0 + row) * 64 + schunk, &Kt[buf][(i * 32 + w * 8) * 64]);
            gload_lds16(VTh + (size_t)row * kN + k0 + schunk, &Vt[buf][(i * 32 + w * 8) * 64]);
        }
    };

    f32x4 oA[4] = {}, oB[4] = {};
    float mA = -3.0e38f, lA = 0.f, mB = -3.0e38f, lB = 0.f;

    stage(0, kbase);
    __syncthreads();

    int rx = r & 7;
    for (int st = 0; st < NSTEP; ++st) {
        int cur = st & 1;
        if (st + 1 < NSTEP) stage(cur ^ 1, kbase + (st + 1) * 64);
        const u16* Kl = &Kt[cur][0];
        const u16* Vl = &Vt[cur][0];
        // ---- set A: S^T, softmax, P->LDS ----
        {
            f32x4 stt[4] = {};
#pragma unroll
            for (int t = 0; t < 4; ++t) {
                bf16x8 kf0 = *(const bf16x8*)(Kl + (16 * t + r) * 64 + ((0 + g) ^ rx) * 8);
                bf16x8 kf1 = *(const bf16x8*)(Kl + (16 * t + r) * 64 + ((4 + g) ^ rx) * 8);
                stt[t] = __builtin_amdgcn_mfma_f32_16x16x32_bf16(kf0, qfA0, stt[t], 0, 0, 0);
                stt[t] = __builtin_amdgcn_mfma_f32_16x16x32_bf16(kf1, qfA1, stt[t], 0, 0, 0);
            }
            float pm = stt[0][0];
#pragma unroll
            for (int t = 0; t < 4; ++t)
#pragma unroll
                for (int e = 0; e < 4; ++e) pm = fmaxf(pm, stt[t][e]);
            pm = fmaxf(pm, __shfl_xor(pm, 16));
            pm = fmaxf(pm, __shfl_xor(pm, 32));
            if (__any(pm > mA)) {
                float mn = fmaxf(mA, pm);
                float corr = __builtin_amdgcn_exp2f(mA - mn);
                lA *= corr;
                float corrq[4];
#pragma unroll
                for (int e = 0; e < 4; ++e) corrq[e] = __shfl(corr, g * 4 + e);
#pragma unroll
                for (int dt = 0; dt < 4; ++dt)
#pragma unroll
                    for (int e = 0; e < 4; ++e) oA[dt][e] *= corrq[e];
                mA = mn;
            }
            float lsx = 0.f;
#pragma unroll
            for (int t = 0; t < 4; ++t) {
                ushort4 pk;
                float p0 = __builtin_amdgcn_exp2f(stt[t][0] - mA);
                float p1 = __builtin_amdgcn_exp2f(stt[t][1] - mA);
                float p2 = __builtin_amdgcn_exp2f(stt[t][2] - mA);
                float p3 = __builtin_amdgcn_exp2f(stt[t][3] - mA);
                lsx += (p0 + p1) + (p2 + p3);
                pk.x = f2bf(p0); pk.y = f2bf(p1); pk.z = f2bf(p2); pk.w = f2bf(p3);
                int lc = (2 * t + (g >> 1)) ^ rx;
                *(ushort4*)(&plds[w][0][r * 64 + lc * 8 + (g & 1) * 4]) = pk;
            }
            lsx += __shfl_xor(lsx, 16);
            lsx += __shfl_xor(lsx, 32);
            lA += lsx;
        }
        // ---- set B ----
        {
            f32x4 stt[4] = {};
#pragma unroll
            for (int t = 0; t < 4; ++t) {
                bf16x8 kf0 = *(const bf16x8*)(Kl + (16 * t + r) * 64 + ((0 + g) ^ rx) * 8);
                bf16x8 kf1 = *(const bf16x8*)(Kl + (16 * t + r) * 64 + ((4 + g) ^ rx) * 8);
                stt[t] = __builtin_amdgcn_mfma_f32_16x16x32_bf16(kf0, qfB0, stt[t], 0, 0, 0);
                stt[t] = __builtin_amdgcn_mfma_f32_16x16x32_bf16(kf1, qfB1, stt[t], 0, 0, 0);
            }
            float pm = stt[0][0];
#pragma unroll
            for (int t = 0; t < 4; ++t)
#pragma unroll
                for (int e = 0; e < 4; ++e) pm = fmaxf(pm, stt[t][e]);
            pm = fmaxf(pm, __shfl_xor(pm, 16));
            pm = fmaxf(pm, __shfl_xor(pm, 32));
            if (__any(pm > mB)) {
                float mn = fmaxf(mB, pm);
                float corr = __builtin_amdgcn_exp2f(mB - mn);
                lB *= corr;
                float corrq[4];
#pragma unroll
                for (int e = 0; e < 4; ++e) corrq[e] = __shfl(corr, g * 4 + e);
#pragma unroll
                for (int dt = 0; dt < 4; ++dt)
#pragma unroll
                    for (int e = 0; e < 4; ++e) oB[dt][e] *= corrq[e];
                mB = mn;
            }
            float lsx = 0.f;
#pragma unroll
            for (int t = 0; t < 4; ++t) {
                ushort4 pk;
                float p0 = __builtin_amdgcn_exp2f(stt[t][0] - mB);
                float p1 = __builtin_amdgcn_exp2f(stt[t][1] - mB);
                float p2 = __builtin_amdgcn_exp2f(stt[t][2] - mB);
                float p3 = __builtin_amdgcn_exp2f(stt[t][3] - mB);
                lsx += (p0 + p1) + (p2 + p3);
                pk.x = f2bf(p0); pk.y = f2bf(p1); pk.z = f2bf(p2); pk.w = f2bf(p3);
                int lc = (2 * t + (g >> 1)) ^ rx;
                *(ushort4*)(&plds[w][1][r * 64 + lc * 8 + (g & 1) * 4]) = pk;
            }
            lsx += __shfl_xor(lsx, 16);
            lsx += __shfl_xor(lsx, 32);
            lB += lsx;
        }
        // ---- PV: vf reads shared across both sets ----
        bf16x8 paA0 = *(const bf16x8*)(&plds[w][0][r * 64 + (g ^ rx) * 8]);
        bf16x8 paA1 = *(const bf16x8*)(&plds[w][0][r * 64 + ((4 + g) ^ rx) * 8]);
        bf16x8 paB0 = *(const bf16x8*)(&plds[w][1][r * 64 + (g ^ rx) * 8]);
        bf16x8 paB1 = *(const bf16x8*)(&plds[w][1][r * 64 + ((4 + g) ^ rx) * 8]);
#pragma unroll
        for (int dt = 0; dt < 4; ++dt) {
            bf16x8 vf0 = *(const bf16x8*)(Vl + (dt * 16 + r) * 64 + ((0 + g) ^ rx) * 8);
            bf16x8 vf1 = *(const bf16x8*)(Vl + (dt * 16 + r) * 64 + ((4 + g) ^ rx) * 8);
            oA[dt] = __builtin_amdgcn_mfma_f32_16x16x32_bf16(paA0, vf0, oA[dt], 0, 0, 0);
            oA[dt] = __builtin_amdgcn_mfma_f32_16x16x32_bf16(paA1, vf1, oA[dt], 0, 0, 0);
            oB[dt] = __builtin_amdgcn_mfma_f32_16x16x32_bf16(paB0, vf0, oB[dt], 0, 0, 0);
            oB[dt] = __builtin_amdgcn_mfma_f32_16x16x32_bf16(paB1, vf1, oB[dt], 0, 0, 0);
        }
        __syncthreads();
    }

    // store unnormalized partials: 128 rows per block (A: 0-63, B: 64-127)
    size_t slot = (size_t)(head * 32 + qt) * NSPLIT + sp;
    float* ob = opart + slot * 8192;
#pragma unroll
    for (int dt = 0; dt < 4; ++dt)
#pragma unroll
        for (int e = 0; e < 4; ++e) {
            ob[(w * 16 + g * 4 + e) * 64 + dt * 16 + r] = oA[dt][e];
            ob[(64 + w * 16 + g * 4 + e) * 64 + dt * 16 + r] = oB[dt][e];
        }
    float* mlb = mlpart + slot * 256;
    if (g == 0) {
        mlb[w * 16 + r] = mA;
        mlb[64 + w * 16 + r] = mB;
        mlb[128 + w * 16 + r] = lA;
        mlb[192 + w * 16 + r] = lB;
    }
}

// ---------------- merge split-K attention partials -> attnb (bf16) ----------------
// grid (kN/4, heads), block 256: wave w = one q row, lane = d (0..63)
__global__ __launch_bounds__(256) void mha_merge(
    const float* __restrict__ opart, const float* __restrict__ mlpart,
    u16* __restrict__ attnb) {
    int head = blockIdx.y;
    int q = blockIdx.x * 4 + (threadIdx.x >> 6);
    int d = threadIdx.x & 63;
    int qt = q >> 7, ql = q & 127;
    size_t sb = (size_t)(head * 32 + qt) * NSPLIT;
    float ms[NSPLIT], lsv[NSPLIT];
    float mstar = -3.0e38f;
#pragma unroll
    for (int s = 0; s < NSPLIT; ++s) {
        ms[s] = mlpart[(sb + s) * 256 + ql];
        lsv[s] = mlpart[(sb + s) * 256 + 128 + ql];
        mstar = fmaxf(mstar, ms[s]);
    }
    float acc = 0.f, lsum = 0.f;
#pragma unroll
    for (int s = 0; s < NSPLIT; ++s) {
        float wgt = __builtin_amdgcn_exp2f(ms[s] - mstar);
        lsum += lsv[s] * wgt;
        acc += opart[(sb + s) * 8192 + ql * 64 + d] * wgt;
    }
    attnb[(size_t)q * kC + head * 64 + d] = f2bf(acc / lsum);
}

// ---------------- final: out[4096,2] = t_bf @ out_w2^T + b2; wave per row ----------------
__global__ __launch_bounds__(256) void final_out(
    const u16* __restrict__ tbf, const float* __restrict__ w2,
    const float* __restrict__ b2, float* __restrict__ out) {
    int row = blockIdx.x * 4 + (threadIdx.x >> 6);
    int lane = threadIdx.x & 63;
    const ushort4 tv = *(const ushort4*)(tbf + (size_t)row * 256 + lane * 4);
    float t0 = bf2f(tv.x), t1 = bf2f(tv.y), t2 = bf2f(tv.z), t3 = bf2f(tv.w);
    const float4 w0 = *(const float4*)(w2 + lane * 4);
    const float4 w1 = *(const float4*)(w2 + 256 + lane * 4);
    float d0 = t0 * w0.x + t1 * w0.y + t2 * w0.z + t3 * w0.w;
    float d1 = t0 * w1.x + t1 * w1.y + t2 * w1.z + t3 * w1.w;
    for (int d = 1; d < 64; d <<= 1) { d0 += __shfl_xor(d0, d); d1 += __shfl_xor(d1, d); }
    if (lane == 0) {
        out[(size_t)row * 2 + 0] = d0 + b2[0];
        out[(size_t)row * 2 + 1] = d1 + b2[1];
    }
}

extern "C" void kernel_launch(void* const* d_in, const int* in_sizes, int n_in,
                              void* d_out, int out_size, void* d_ws, size_t ws_size,
                              hipStream_t stream) {
    (void)in_sizes; (void)n_in; (void)out_size;
    const float* x        = (const float*)d_in[0];
    const int*   ei       = (const int*)d_in[1];
    const float* in_w     = (const float*)d_in[2];
    const float* in_b     = (const float*)d_in[3];
    const float* gat_wl   = (const float*)d_in[4];
    const float* gat_wr   = (const float*)d_in[5];
    const float* gat_att  = (const float*)d_in[6];
    const float* gat_b    = (const float*)d_in[7];
    const float* mha_in_w = (const float*)d_in[8];
    const float* mha_in_b = (const float*)d_in[9];
    const float* mha_out_w= (const float*)d_in[10];
    const float* mha_out_b= (const float*)d_in[11];
    const float* ln1_g = (const float*)d_in[12];
    const float* ln1_b = (const float*)d_in[13];
    const float* ln2_g = (const float*)d_in[14];
    const float* ln2_b = (const float*)d_in[15];
    const float* ln3_g = (const float*)d_in[16];
    const float* ln3_b = (const float*)d_in[17];
    const float* ffn_w1 = (const float*)d_in[18];
    const float* ffn_b1 = (const float*)d_in[19];
    const float* ffn_w2 = (const float*)d_in[20];
    const float* ffn_b2 = (const float*)d_in[21];
    const float* out_w1 = (const float*)d_in[22];
    const float* out_b1 = (const float*)d_in[23];
    const float* out_w2 = (const float*)d_in[24];
    const float* out_b2 = (const float*)d_in[25];
    float* out = (float*)d_out;

    char* ws = (char*)d_ws;
    size_t off = 0;
    auto alloc = [&](size_t bytes) -> void* {
        void* p = (void*)(ws + off);
        off += (bytes + 255) & ~(size_t)255;
        return p;
    };
    float* h     = (float*)alloc((size_t)kN * kC * 4);
    u16*   hbf   = (u16*)  alloc((size_t)kN * kC * 2);
    float* xlb   = (float*)alloc((size_t)kN * 1024 * 4);   // slot reused: xgbf / Qb+Kb+VTb
    float* xrb   = (float*)alloc((size_t)kN * 1024 * 4);   // slot reused: opart
    float* locb  = (float*)alloc((size_t)kN * kC * 4);     // slot reused: mlpart
    u16*   attnb = (u16*)  alloc((size_t)kN * kC * 2);
    u16*   midb  = (u16*)  alloc((size_t)kN * 512 * 2);
    u16*   tbf   = (u16*)  alloc((size_t)kN * kC * 2);
    u16*   xbf   = (u16*)  alloc((size_t)kN * kIn * 2);
    u16*   wbf   = (u16*)  alloc((size_t)3342336 * 2);
    int*   coff  = (int*)  alloc((size_t)4097 * 4);
    int*   ccur  = (int*)  alloc((size_t)4096 * 4);
    int*   csrc  = (int*)  alloc((size_t)kET * 4);
    if (ws_size < off) return;  // not enough scratch: bail loudly (output stays poisoned)

    u16* xgbf = (u16*)xlb;                      // [4096][2048] bf16 (xl|xr fused)
    u16* Qb  = (u16*)xlb;                       // [4][4096][64]
    u16* Kb  = Qb + (size_t)4 * kN * 64;        // [4][4096][64]
    u16* VTb = Kb + (size_t)4 * kN * 64;        // [4][64][4096]
    float* opart  = xrb;                        // 512 slots x 8192 f32 = 16 MB exact
    float* mlpart = locb;                       // 512 x 256 f32 = 512 KB

    // bf16 weight buffer offsets (elements); gat wl/wr interleaved per layer [2048][256]
    const size_t OFF_INW  = 0;
    const size_t OFF_GAT  = 131072;
    const size_t OFF_MIN  = 1703936;
    const size_t OFF_MOUT = 2293760;
    const size_t OFF_F1   = 2490368;
    const size_t OFF_F2   = 2883584;
    const size_t OFF_O1   = 3276800;

    // one fused cast of x + all weights (region table inside the kernel)
    cast_all<<<dim3((1359872 + 255) / 256), dim3(256), 0, stream>>>(
        x, in_w, gat_wl, gat_wr, mha_in_w, mha_out_w, ffn_w1, ffn_w2, out_w1,
        xbf, wbf);

    // CSR build (once per launch; same graph for all layers)
    hipMemsetAsync(ccur, 0, 4096 * 4, stream);
    csr_count<<<dim3((kET + 255) / 256), dim3(256), 0, stream>>>(ei, ccur);
    csr_scan<<<dim3(1), dim3(1024), 0, stream>>>(ccur, coff);
    csr_scatter<<<dim3((kET + 255) / 256), dim3(256), 0, stream>>>(ei, ccur, csrc);

    // input projection: h = x @ in_w^T + in_b  (fp32 + bf16 outputs)
    gemm_st<64, 512, 0, 1, 1><<<dim3(kC / 64, kN / 64), dim3(256), 0, stream>>>(
        xbf, wbf + OFF_INW, in_b, h, hbf, kC);

    for (int l = 0; l < kL; ++l) {
        // GATv2 transforms: fused wl|wr 128x128-tile GEMM -> xgbf [4096][2048]
        gemm_128<256><<<dim3(2048 / 128, kN / 128), dim3(256), 0, stream>>>(
            hbf, wbf + OFF_GAT + (size_t)l * 524288, xgbf, 2048);
        // gat_agg with fused residual + ln1 (writes h, hbf directly)
        gat_agg<<<dim3(kN), dim3(256), 0, stream>>>(
            xgbf, gat_att + (size_t)l * 1024, gat_b + (size_t)l * kC, coff, csrc,
            ln1_g + (size_t)l * kC, ln1_b + (size_t)l * kC, h, hbf);

        // MHA: fused qkv GEMM writes Qb/Kb/VTb directly
        gemm_qkv<<<dim3(768 / 64, kN / 128), dim3(256), 0, stream>>>(
            hbf, wbf + OFF_MIN + (size_t)l * 768 * kC, mha_in_b + (size_t)l * 768,
            Qb, Kb, VTb);
        mha_mfma3<<<dim3(kN / 128, 4, NSPLIT), dim3(256), 0, stream>>>(Qb, Kb, VTb, opart, mlpart);
        mha_merge<<<dim3(kN / 4, 4), dim3(256), 0, stream>>>(opart, mlpart, attnb);
        // mout GEMM + fused residual + ln2
        gemm_ln<16, 256><<<dim3(kN / 16), dim3(256), 0, stream>>>(
            attnb, wbf + OFF_MOUT + (size_t)l * kC * kC, mha_out_b + (size_t)l * kC,
            ln2_g + (size_t)l * kC, ln2_b + (size_t)l * kC, h, hbf);

        // FFN
        gemm_st<64, 256, 1, 0, 1><<<dim3(512 / 64, kN / 64), dim3(256), 0, stream>>>(
            hbf, wbf + OFF_F1 + (size_t)l * 512 * kC, ffn_b1 + (size_t)l * 512, nullptr, midb, 512);
        // ffn2 GEMM + fused residual + ln3
        gemm_ln<16, 512><<<dim3(kN / 16), dim3(256), 0, stream>>>(
            midb, wbf + OFF_F2 + (size_t)l * kC * 512, ffn_b2 + (size_t)l * kC,
            ln3_g + (size_t)l * kC, ln3_b + (size_t)l * kC, h, hbf);
    }

    // output head
    gemm_st<64, 256, 1, 0, 1><<<dim3(kC / 64, kN / 64), dim3(256), 0, stream>>>(
        hbf, wbf + OFF_O1, out_b1, nullptr, tbf, kC);
    final_out<<<dim3(kN / 4), dim3(256), 0, stream>>>(tbf, out_w2, out_b2, out);
}